// Round 2
// baseline (2058.255 us; speedup 1.0000x reference)
//
#include <hip/hip_runtime.h>
#include <math.h>

// ---------------------------------------------------------------------------
// VQ-VAE forward, fp32, batch-chunked to fit unknown ws_size.
//  x (32,1,256,256) -> h (32,128,128,128) -> z (32,64,64,64)
//  VQ: N=131072 x D=64 vs K=512   (q aliases z in-place)
//  q -> g (aliases h) -> x_recon (32,1,256,256)
// d_out: [0]=vq_loss, [1..131072]=idx (as float), [131073..]=x_recon
// ws layout: wT2 131072 | wTd 131072 | csq 512 | h CB*2097152 | zq CB*262144
// ---------------------------------------------------------------------------

#define REC_OFF 131073

__global__ __launch_bounds__(64) void zero_loss_k(float* __restrict__ out) {
  if (threadIdx.x == 0) out[0] = 0.f;
}

// ---------------- weight repack (makes scalar-load index contiguous) --------
__global__ __launch_bounds__(256) void repack_k(
    const float* __restrict__ ew2,   // enc_w2 (d=64, c=128, ky, kx)
    const float* __restrict__ dw2,   // dec_w2 (ci=64, co=128, ky, kx)
    float* __restrict__ wT2,         // [(c*4+ky)*4+kx][d 0..63]
    float* __restrict__ wTd) {       // [(ky*4+kx)*64+ci][co 0..127]
  int i = blockIdx.x * 256 + threadIdx.x;          // 131072 total
  int kx = i & 3, ky = (i >> 2) & 3, mid = (i >> 4) & 127, top = i >> 11;
  wT2[(((mid * 4 + ky) * 4 + kx) << 6) + top] = ew2[i];
  wTd[((((ky * 4 + kx) << 6) + top) << 7) + mid] = dw2[i];
}

__global__ __launch_bounds__(256) void csq_k(
    const float* __restrict__ cb, float* __restrict__ csq) {
  int k = blockIdx.x * 256 + threadIdx.x;          // 512 total
  const float* cp = cb + (k << 6);
  float s = 0.f;
#pragma unroll
  for (int d = 0; d < 64; ++d) s = fmaf(cp[d], cp[d], s);
  csq[k] = s;
}

// ---------------- conv1 (1->128, 4x4, s2, p1) + relu ------------------------
// x pre-offset to chunk base. b is chunk-local.
__global__ __launch_bounds__(128) void conv1_k(
    const float* __restrict__ x, const float* __restrict__ w1,
    const float* __restrict__ b1, float* __restrict__ h) {
  int oy = blockIdx.x, b = blockIdx.y, ox = threadIdx.x;
  float xv[16];
#pragma unroll
  for (int ky = 0; ky < 4; ++ky) {
    int iy = 2 * oy - 1 + ky;
#pragma unroll
    for (int kx = 0; kx < 4; ++kx) {
      int ix = 2 * ox - 1 + kx;
      float v = 0.f;
      if (iy >= 0 && iy < 256 && ix >= 0 && ix < 256)
        v = x[(b * 256 + iy) * 256 + ix];
      xv[ky * 4 + kx] = v;
    }
  }
  for (int c = 0; c < 128; ++c) {
    const float* wp = w1 + c * 16;                 // wave-uniform -> s_load
    float acc = b1[c];
#pragma unroll
    for (int k = 0; k < 16; ++k) acc = fmaf(xv[k], wp[k], acc);
    h[((b * 128 + c) * 128 + oy) * 128 + ox] = fmaxf(acc, 0.f);
  }
}

// ---------------- conv2 (128->64, 4x4, s2, p1) + relu -----------------------
// block=(y,b): 64 x-positions (lanes) x 64 d (4 waves x 16 d). acc[16]/thread.
__global__ __launch_bounds__(256) void conv2_k(
    const float* __restrict__ h, const float* __restrict__ wT2,
    const float* __restrict__ b2, float* __restrict__ z) {
  __shared__ float in4[4][136];
  int y = blockIdx.x, b = blockIdx.y;
  int t = threadIdx.x, l = t & 63;
  int d0 = __builtin_amdgcn_readfirstlane((t >> 6) << 4);
  float acc[16];
#pragma unroll
  for (int i = 0; i < 16; ++i) acc[i] = 0.f;

  for (int c = 0; c < 128; ++c) {
    __syncthreads();
    for (int s = t; s < 544; s += 256) {
      int ky = s / 136, i = s - ky * 136;
      int iy = 2 * y - 1 + ky, ix = i - 1;
      float v = 0.f;
      if (i < 132 && iy >= 0 && iy < 128 && ix >= 0 && ix < 128)
        v = h[((b * 128 + c) * 128 + iy) * 128 + ix];
      in4[ky][i] = v;
    }
    __syncthreads();
#pragma unroll
    for (int ky = 0; ky < 4; ++ky) {
      const float2 xa = *reinterpret_cast<const float2*>(&in4[ky][2 * l]);
      const float2 xb = *reinterpret_cast<const float2*>(&in4[ky][2 * l + 2]);
      float xk[4] = {xa.x, xa.y, xb.x, xb.y};
      const float* wp = wT2 + (((c * 4 + ky) * 4) << 6) + d0;
#pragma unroll
      for (int kx = 0; kx < 4; ++kx) {
        const float* wq = wp + (kx << 6);          // wave-uniform -> s_load_dwordx16
        float xs = xk[kx];
#pragma unroll
        for (int dd = 0; dd < 16; ++dd) acc[dd] = fmaf(wq[dd], xs, acc[dd]);
      }
    }
  }
#pragma unroll
  for (int dd = 0; dd < 16; ++dd) {
    float v = fmaxf(acc[dd] + b2[d0 + dd], 0.f);
    z[((b * 64 + d0 + dd) * 64 + y) * 64 + l] = v;
  }
}

// ---------------- VQ: argmin + quantize (in-place ok) + loss ----------------
// Each thread owns one spatial position: reads its full z column into regs
// BEFORE writing q column, so q may alias z.
__global__ __launch_bounds__(256) void vq_k(
    const float* __restrict__ z, const float* __restrict__ cb,
    const float* __restrict__ csq, float* __restrict__ q,
    float* __restrict__ out, int n0) {
  int n = blockIdx.x * 256 + threadIdx.x;          // chunk-local
  int b = n >> 12, rem = n & 4095, y = rem >> 6, x = rem & 63;
  const float* zp = z + ((b * 64) * 64 + y) * 64 + x;
  float zr[64];
#pragma unroll
  for (int d = 0; d < 64; ++d) zr[d] = zp[d * 4096];

  float bestd = 1e30f;
  int bestk = 0;
  for (int k = 0; k < 512; ++k) {
    const float* cp = cb + (k << 6);               // wave-uniform -> s_load
    float dot = 0.f;
#pragma unroll
    for (int d = 0; d < 64; ++d) dot = fmaf(cp[d], zr[d], dot);
    float dist = csq[k] - 2.f * dot;               // monotonic in true distance
    if (dist < bestd) { bestd = dist; bestk = k; } // strict '<' keeps first min
  }
  out[1 + n0 + n] = (float)bestk;

  const float* cbest = cb + (bestk << 6);
  float* qp = q + ((b * 64) * 64 + y) * 64 + x;
  float ls = 0.f;
#pragma unroll
  for (int d = 0; d < 64; ++d) {
    float c = cbest[d];
    qp[d * 4096] = c;
    float df = c - zr[d];
    ls = fmaf(df, df, ls);
  }
#pragma unroll
  for (int m = 32; m; m >>= 1) ls += __shfl_xor(ls, m);
  __shared__ float red[4];
  if ((threadIdx.x & 63) == 0) red[threadIdx.x >> 6] = ls;
  __syncthreads();
  if (threadIdx.x == 0)
    atomicAdd(out, (red[0] + red[1] + red[2] + red[3]) * (1.25f / 8388608.f));
}

// ---------------- convT2 (64->128, 4x4, s2, p1) + relu ----------------------
// block=(coh, Y, b): 128 thr = 2 waves (X parity). Each thread: 64 co accs.
__global__ __launch_bounds__(128) void dconv2_k(
    const float* __restrict__ q, const float* __restrict__ wTd,
    const float* __restrict__ db2, float* __restrict__ g) {
  __shared__ float rows[2][68];
  int coh = blockIdx.x, Y = blockIdx.y, b = blockIdx.z;
  int t = threadIdx.x;
  int pX = __builtin_amdgcn_readfirstlane(t >> 6);
  int l = t & 63;
  int co0 = coh << 6;
  int kyA = (Y + 1) & 1, kyB = kyA + 2;
  int yA = (Y + 1) >> 1, yB = yA - 1;
  int kxA = pX ? 0 : 1, kxB = kxA + 2;

  float acc[64];
#pragma unroll
  for (int i = 0; i < 64; ++i) acc[i] = 0.f;

  for (int ci = 0; ci < 64; ++ci) {
    __syncthreads();
    for (int s = t; s < 136; s += 128) {
      int r = s / 68, i = s - r * 68;
      int yy = r ? yB : yA;
      int ix = i - 1;
      float v = 0.f;
      if (i < 66 && yy >= 0 && yy < 64 && ix >= 0 && ix < 64)
        v = q[((b * 64 + ci) * 64 + yy) * 64 + ix];
      rows[r][i] = v;
    }
    __syncthreads();
    float vAhi = rows[0][l + pX + 1], vAlo = rows[0][l + pX];
    float vBhi = rows[1][l + pX + 1], vBlo = rows[1][l + pX];
    const float* wpA = wTd + ((kyA * 4 + kxA) << 13) + (ci << 7) + co0;
    const float* wpB = wTd + ((kyA * 4 + kxB) << 13) + (ci << 7) + co0;
    const float* wpC = wTd + ((kyB * 4 + kxA) << 13) + (ci << 7) + co0;
    const float* wpD = wTd + ((kyB * 4 + kxB) << 13) + (ci << 7) + co0;
#pragma unroll
    for (int cc = 0; cc < 64; ++cc) {
      float a = acc[cc];
      a = fmaf(wpA[cc], vAhi, a);
      a = fmaf(wpB[cc], vAlo, a);
      a = fmaf(wpC[cc], vBhi, a);
      a = fmaf(wpD[cc], vBlo, a);
      acc[cc] = a;
    }
  }
  int X = 2 * l + pX;
#pragma unroll
  for (int cc = 0; cc < 64; ++cc) {
    float v = fmaxf(acc[cc] + db2[co0 + cc], 0.f);
    g[((b * 128 + co0 + cc) * 128 + Y) * 128 + X] = v;
  }
}

// ---------------- convT1 (128->1, 4x4, s2, p1) + sigmoid --------------------
// rec pre-offset to chunk base. block=(a, b): rows Y=8a..8a+7, 256 wide.
__global__ __launch_bounds__(256) void dconv1_k(
    const float* __restrict__ g, const float* __restrict__ wd1,
    const float* __restrict__ db1, float* __restrict__ rec) {
  __shared__ float rows[6][132];
  int a = blockIdx.x, b = blockIdx.y;
  int t = threadIdx.x;
  int w = __builtin_amdgcn_readfirstlane(t >> 6);
  int l = t & 63;
  int xh = w >> 1, pX = w & 1;
  int L = xh * 64 + l;                       // X = 2L + pX
  int kxA = pX ? 0 : 1, kxB = kxA + 2;
  float acc[8];
#pragma unroll
  for (int i = 0; i < 8; ++i) acc[i] = 0.f;

  for (int ci = 0; ci < 128; ++ci) {
    __syncthreads();
    for (int s = t; s < 792; s += 256) {
      int r = s / 132, i = s - r * 132;
      int yy = 4 * a - 1 + r, ix = i - 1;
      float v = 0.f;
      if (i < 130 && yy >= 0 && yy < 128 && ix >= 0 && ix < 128)
        v = g[((b * 128 + ci) * 128 + yy) * 128 + ix];
      rows[r][i] = v;
    }
    __syncthreads();
    const float* wp = wd1 + ci * 16;         // contiguous taps -> s_load_dwordx16
    float rhi[6], rlo[6];
#pragma unroll
    for (int r = 0; r < 6; ++r) {
      rhi[r] = rows[r][L + pX + 1];
      rlo[r] = rows[r][L + pX];
    }
#pragma unroll
    for (int j = 0; j < 8; ++j) {
      int kyA = (j + 1) & 1, kyB = kyA + 2;
      int rA = ((j + 1) >> 1) + 1;
      float v = acc[j];
      v = fmaf(wp[kyA * 4 + kxA], rhi[rA], v);
      v = fmaf(wp[kyA * 4 + kxB], rlo[rA], v);
      v = fmaf(wp[kyB * 4 + kxA], rhi[rA - 1], v);
      v = fmaf(wp[kyB * 4 + kxB], rlo[rA - 1], v);
      acc[j] = v;
    }
  }
  float bb = db1[0];
#pragma unroll
  for (int j = 0; j < 8; ++j) {
    float v = acc[j] + bb;
    v = 1.f / (1.f + __expf(-v));
    rec[((b * 256 + 8 * a + j) * 256) + 2 * L + pX] = v;
  }
}

// ---------------------------------------------------------------------------
extern "C" void kernel_launch(void* const* d_in, const int* in_sizes, int n_in,
                              void* d_out, int out_size, void* d_ws, size_t ws_size,
                              hipStream_t stream) {
  const float* x      = (const float*)d_in[0];
  const float* enc_w1 = (const float*)d_in[1];
  const float* enc_b1 = (const float*)d_in[2];
  const float* enc_w2 = (const float*)d_in[3];
  const float* enc_b2 = (const float*)d_in[4];
  const float* cb     = (const float*)d_in[5];
  const float* dec_w2 = (const float*)d_in[6];
  const float* dec_b2 = (const float*)d_in[7];
  const float* dec_w1 = (const float*)d_in[8];
  const float* dec_b1 = (const float*)d_in[9];

  float* out = (float*)d_out;
  float* ws  = (float*)d_ws;
  float* wT2 = ws;                        // 131072
  float* wTd = wT2 + 131072;              // 131072
  float* csq = wTd + 131072;              // 512
  float* dyn = csq + 512;                 // chunk buffers

  // Per-image: h = 2,097,152 floats (aliased as g), z/q (aliased) = 262,144.
  const size_t PER_IMG = 2097152 + 262144;                   // 2,359,296 floats
  size_t avail = (ws_size / 4 > 262656 + 64) ? ws_size / 4 - 262656 - 64 : 0;
  int CB = 32;
  while (CB > 1 && (size_t)CB * PER_IMG > avail) CB >>= 1;

  zero_loss_k<<<dim3(1), 64, 0, stream>>>(out);
  repack_k<<<dim3(512), 256, 0, stream>>>(enc_w2, dec_w2, wT2, wTd);
  csq_k<<<dim3(2), 256, 0, stream>>>(cb, csq);

  for (int b0 = 0; b0 < 32; b0 += CB) {
    float* h  = dyn;                                  // CB*2097152 (g aliases)
    float* zq = dyn + (size_t)CB * 2097152;           // CB*262144 (q aliases z)
    conv1_k<<<dim3(128, CB), 128, 0, stream>>>(
        x + (size_t)b0 * 65536, enc_w1, enc_b1, h);
    conv2_k<<<dim3(64, CB), 256, 0, stream>>>(h, wT2, enc_b2, zq);
    vq_k<<<dim3(CB * 16), 256, 0, stream>>>(zq, cb, csq, zq, out, b0 * 4096);
    dconv2_k<<<dim3(2, 128, CB), 128, 0, stream>>>(zq, wTd, dec_b2, h /*g*/);
    dconv1_k<<<dim3(32, CB), 256, 0, stream>>>(
        h /*g*/, dec_w1, dec_b1, out + REC_OFF + (size_t)b0 * 65536);
  }
}

// Round 3
// 1947.782 us; speedup vs baseline: 1.0567x; 1.0567x over previous
//
#include <hip/hip_runtime.h>
#include <math.h>

// ---------------------------------------------------------------------------
// VQ-VAE forward, fp32, batch-chunked to fit unknown ws_size.
//  x (32,1,256,256) -> h (32,128,128,128) -> z (32,64,64,64)
//  VQ: N=131072 x D=64 vs K=512   (q aliases z in-place)
//  q -> g (aliases h) -> x_recon (32,1,256,256)
// d_out: [0]=vq_loss, [1..131072]=idx (as float), [131073..]=x_recon
// ws layout: wT2 131072 | wTd 131072 | csq 512 | h CB*2097152 | zq CB*262144
// Round 3: channel-group LDS staging (CSTEP) to amortize barriers; dconv2
// rewritten at 256 thr/block so both co-halves share one staging.
// ---------------------------------------------------------------------------

#define REC_OFF 131073

__global__ __launch_bounds__(64) void zero_loss_k(float* __restrict__ out) {
  if (threadIdx.x == 0) out[0] = 0.f;
}

// ---------------- weight repack (makes scalar-load index contiguous) --------
__global__ __launch_bounds__(256) void repack_k(
    const float* __restrict__ ew2,   // enc_w2 (d=64, c=128, ky, kx)
    const float* __restrict__ dw2,   // dec_w2 (ci=64, co=128, ky, kx)
    float* __restrict__ wT2,         // [(c*4+ky)*4+kx][d 0..63]
    float* __restrict__ wTd) {       // [(ky*4+kx)*64+ci][co 0..127]
  int i = blockIdx.x * 256 + threadIdx.x;          // 131072 total
  int kx = i & 3, ky = (i >> 2) & 3, mid = (i >> 4) & 127, top = i >> 11;
  wT2[(((mid * 4 + ky) * 4 + kx) << 6) + top] = ew2[i];
  wTd[((((ky * 4 + kx) << 6) + top) << 7) + mid] = dw2[i];
}

__global__ __launch_bounds__(256) void csq_k(
    const float* __restrict__ cb, float* __restrict__ csq) {
  int k = blockIdx.x * 256 + threadIdx.x;          // 512 total
  const float* cp = cb + (k << 6);
  float s = 0.f;
#pragma unroll
  for (int d = 0; d < 64; ++d) s = fmaf(cp[d], cp[d], s);
  csq[k] = s;
}

// ---------------- conv1 (1->128, 4x4, s2, p1) + relu ------------------------
__global__ __launch_bounds__(128) void conv1_k(
    const float* __restrict__ x, const float* __restrict__ w1,
    const float* __restrict__ b1, float* __restrict__ h) {
  int oy = blockIdx.x, b = blockIdx.y, ox = threadIdx.x;
  float xv[16];
#pragma unroll
  for (int ky = 0; ky < 4; ++ky) {
    int iy = 2 * oy - 1 + ky;
#pragma unroll
    for (int kx = 0; kx < 4; ++kx) {
      int ix = 2 * ox - 1 + kx;
      float v = 0.f;
      if (iy >= 0 && iy < 256 && ix >= 0 && ix < 256)
        v = x[(b * 256 + iy) * 256 + ix];
      xv[ky * 4 + kx] = v;
    }
  }
  for (int c = 0; c < 128; ++c) {
    const float* wp = w1 + c * 16;                 // wave-uniform -> s_load
    float acc = b1[c];
#pragma unroll
    for (int k = 0; k < 16; ++k) acc = fmaf(xv[k], wp[k], acc);
    h[((b * 128 + c) * 128 + oy) * 128 + ox] = fmaxf(acc, 0.f);
  }
}

// ---------------- conv2 (128->64, 4x4, s2, p1) + relu -----------------------
// block=(y,b): 64 x (lanes) x 64 d (4 waves x 16 d). acc[16]/thread.
// CSTEP=4 channels staged per barrier round: 1024 FMA/thread per round.
#define C2_STEP 4
__global__ __launch_bounds__(256) void conv2_k(
    const float* __restrict__ h, const float* __restrict__ wT2,
    const float* __restrict__ b2, float* __restrict__ z) {
  __shared__ float in4[C2_STEP][4][136];
  int y = blockIdx.x, b = blockIdx.y;
  int t = threadIdx.x, l = t & 63;
  int d0 = __builtin_amdgcn_readfirstlane((t >> 6) << 4);
  float acc[16];
#pragma unroll
  for (int i = 0; i < 16; ++i) acc[i] = 0.f;

  for (int c0 = 0; c0 < 128; c0 += C2_STEP) {
    __syncthreads();
    for (int s = t; s < C2_STEP * 544; s += 256) {
      int cc = s / 544, r = s - cc * 544;
      int ky = r / 136, i = r - ky * 136;
      int iy = 2 * y - 1 + ky, ix = i - 1;
      float v = 0.f;
      if (i < 132 && iy >= 0 && iy < 128 && ix >= 0 && ix < 128)
        v = h[((b * 128 + c0 + cc) * 128 + iy) * 128 + ix];
      in4[cc][ky][i] = v;
    }
    __syncthreads();
#pragma unroll
    for (int cc = 0; cc < C2_STEP; ++cc) {
      int c = c0 + cc;
#pragma unroll
      for (int ky = 0; ky < 4; ++ky) {
        const float2 xa = *reinterpret_cast<const float2*>(&in4[cc][ky][2 * l]);
        const float2 xb = *reinterpret_cast<const float2*>(&in4[cc][ky][2 * l + 2]);
        float xk[4] = {xa.x, xa.y, xb.x, xb.y};
        const float* wp = wT2 + (((c * 4 + ky) * 4) << 6) + d0;
#pragma unroll
        for (int kx = 0; kx < 4; ++kx) {
          const float* wq = wp + (kx << 6);        // wave-uniform -> s_load_dwordx16
          float xs = xk[kx];
#pragma unroll
          for (int dd = 0; dd < 16; ++dd) acc[dd] = fmaf(wq[dd], xs, acc[dd]);
        }
      }
    }
  }
#pragma unroll
  for (int dd = 0; dd < 16; ++dd) {
    float v = fmaxf(acc[dd] + b2[d0 + dd], 0.f);
    z[((b * 64 + d0 + dd) * 64 + y) * 64 + l] = v;
  }
}

// ---------------- VQ: argmin + quantize (in-place ok) + loss ----------------
__global__ __launch_bounds__(256) void vq_k(
    const float* __restrict__ z, const float* __restrict__ cb,
    const float* __restrict__ csq, float* __restrict__ q,
    float* __restrict__ out, int n0) {
  int n = blockIdx.x * 256 + threadIdx.x;          // chunk-local
  int b = n >> 12, rem = n & 4095, y = rem >> 6, x = rem & 63;
  const float* zp = z + ((b * 64) * 64 + y) * 64 + x;
  float zr[64];
#pragma unroll
  for (int d = 0; d < 64; ++d) zr[d] = zp[d * 4096];

  float bestd = 1e30f;
  int bestk = 0;
  for (int k = 0; k < 512; ++k) {
    const float* cp = cb + (k << 6);               // wave-uniform -> s_load
    float d0a = 0.f, d1a = 0.f;
#pragma unroll
    for (int d = 0; d < 64; d += 2) {
      d0a = fmaf(cp[d], zr[d], d0a);
      d1a = fmaf(cp[d + 1], zr[d + 1], d1a);
    }
    float dist = csq[k] - 2.f * (d0a + d1a);       // monotonic in true distance
    if (dist < bestd) { bestd = dist; bestk = k; } // strict '<' keeps first min
  }
  out[1 + n0 + n] = (float)bestk;

  const float* cbest = cb + (bestk << 6);
  float* qp = q + ((b * 64) * 64 + y) * 64 + x;
  float ls = 0.f;
#pragma unroll
  for (int d = 0; d < 64; ++d) {
    float c = cbest[d];
    qp[d * 4096] = c;
    float df = c - zr[d];
    ls = fmaf(df, df, ls);
  }
#pragma unroll
  for (int m = 32; m; m >>= 1) ls += __shfl_xor(ls, m);
  __shared__ float red[4];
  if ((threadIdx.x & 63) == 0) red[threadIdx.x >> 6] = ls;
  __syncthreads();
  if (threadIdx.x == 0)
    atomicAdd(out, (red[0] + red[1] + red[2] + red[3]) * (1.25f / 8388608.f));
}

// ---------------- convT2 (64->128, 4x4, s2, p1) + relu ----------------------
// block=(Y, b): 256 thr = 4 waves (coh = w>>1, pX = w&1). 64 co accs/thread.
// CSTEP=8 ci staged per barrier round, shared by both co-halves.
#define DC2_STEP 8
__global__ __launch_bounds__(256) void dconv2_k(
    const float* __restrict__ q, const float* __restrict__ wTd,
    const float* __restrict__ db2, float* __restrict__ g) {
  __shared__ float rows[DC2_STEP][2][68];
  int Y = blockIdx.x, b = blockIdx.y;
  int t = threadIdx.x;
  int w = __builtin_amdgcn_readfirstlane(t >> 6);
  int pX = w & 1, coh = w >> 1;
  int l = t & 63;
  int co0 = coh << 6;
  int kyA = (Y + 1) & 1, kyB = kyA + 2;
  int yA = (Y + 1) >> 1, yB = yA - 1;
  int kxA = pX ? 0 : 1, kxB = kxA + 2;

  float acc[64];
#pragma unroll
  for (int i = 0; i < 64; ++i) acc[i] = 0.f;

  for (int c0 = 0; c0 < 64; c0 += DC2_STEP) {
    __syncthreads();
    for (int s = t; s < DC2_STEP * 136; s += 256) {
      int cc = s / 136, r2 = s - cc * 136;
      int r = r2 / 68, i = r2 - r * 68;
      int yy = r ? yB : yA;
      int ix = i - 1;
      float v = 0.f;
      if (i < 66 && yy >= 0 && yy < 64 && ix >= 0 && ix < 64)
        v = q[((b * 64 + c0 + cc) * 64 + yy) * 64 + ix];
      rows[cc][r][i] = v;
    }
    __syncthreads();
#pragma unroll
    for (int cc = 0; cc < DC2_STEP; ++cc) {
      int ci = c0 + cc;
      float vAhi = rows[cc][0][l + pX + 1], vAlo = rows[cc][0][l + pX];
      float vBhi = rows[cc][1][l + pX + 1], vBlo = rows[cc][1][l + pX];
      const float* wpA = wTd + ((kyA * 4 + kxA) << 13) + (ci << 7) + co0;
      const float* wpB = wTd + ((kyA * 4 + kxB) << 13) + (ci << 7) + co0;
      const float* wpC = wTd + ((kyB * 4 + kxA) << 13) + (ci << 7) + co0;
      const float* wpD = wTd + ((kyB * 4 + kxB) << 13) + (ci << 7) + co0;
#pragma unroll
      for (int co = 0; co < 64; ++co) {
        float a = acc[co];
        a = fmaf(wpA[co], vAhi, a);
        a = fmaf(wpB[co], vAlo, a);
        a = fmaf(wpC[co], vBhi, a);
        a = fmaf(wpD[co], vBlo, a);
        acc[co] = a;
      }
    }
  }
  int X = 2 * l + pX;
#pragma unroll
  for (int co = 0; co < 64; ++co) {
    float v = fmaxf(acc[co] + db2[co0 + co], 0.f);
    g[((b * 128 + co0 + co) * 128 + Y) * 128 + X] = v;
  }
}

// ---------------- convT1 (128->1, 4x4, s2, p1) + sigmoid --------------------
// rec pre-offset to chunk base. block=(a, b): rows Y=8a..8a+7, 256 wide.
// CSTEP=2 ci staged per barrier round.
#define DC1_STEP 2
__global__ __launch_bounds__(256) void dconv1_k(
    const float* __restrict__ g, const float* __restrict__ wd1,
    const float* __restrict__ db1, float* __restrict__ rec) {
  __shared__ float rows[DC1_STEP][6][132];
  int a = blockIdx.x, b = blockIdx.y;
  int t = threadIdx.x;
  int w = __builtin_amdgcn_readfirstlane(t >> 6);
  int l = t & 63;
  int xh = w >> 1, pX = w & 1;
  int L = xh * 64 + l;                       // X = 2L + pX
  int kxA = pX ? 0 : 1, kxB = kxA + 2;
  float acc[8];
#pragma unroll
  for (int i = 0; i < 8; ++i) acc[i] = 0.f;

  for (int c0 = 0; c0 < 128; c0 += DC1_STEP) {
    __syncthreads();
    for (int s = t; s < DC1_STEP * 792; s += 256) {
      int cc = s / 792, r2 = s - cc * 792;
      int r = r2 / 132, i = r2 - r * 132;
      int yy = 4 * a - 1 + r, ix = i - 1;
      float v = 0.f;
      if (i < 130 && yy >= 0 && yy < 128 && ix >= 0 && ix < 128)
        v = g[((b * 128 + c0 + cc) * 128 + yy) * 128 + ix];
      rows[cc][r][i] = v;
    }
    __syncthreads();
#pragma unroll
    for (int cc = 0; cc < DC1_STEP; ++cc) {
      const float* wp = wd1 + (c0 + cc) * 16;  // contiguous taps -> s_load
      float rhi[6], rlo[6];
#pragma unroll
      for (int r = 0; r < 6; ++r) {
        rhi[r] = rows[cc][r][L + pX + 1];
        rlo[r] = rows[cc][r][L + pX];
      }
#pragma unroll
      for (int j = 0; j < 8; ++j) {
        int kyA = (j + 1) & 1, kyB = kyA + 2;
        int rA = ((j + 1) >> 1) + 1;
        float v = acc[j];
        v = fmaf(wp[kyA * 4 + kxA], rhi[rA], v);
        v = fmaf(wp[kyA * 4 + kxB], rlo[rA], v);
        v = fmaf(wp[kyB * 4 + kxA], rhi[rA - 1], v);
        v = fmaf(wp[kyB * 4 + kxB], rlo[rA - 1], v);
        acc[j] = v;
      }
    }
  }
  float bb = db1[0];
#pragma unroll
  for (int j = 0; j < 8; ++j) {
    float v = acc[j] + bb;
    v = 1.f / (1.f + __expf(-v));
    rec[((b * 256 + 8 * a + j) * 256) + 2 * L + pX] = v;
  }
}

// ---------------------------------------------------------------------------
extern "C" void kernel_launch(void* const* d_in, const int* in_sizes, int n_in,
                              void* d_out, int out_size, void* d_ws, size_t ws_size,
                              hipStream_t stream) {
  const float* x      = (const float*)d_in[0];
  const float* enc_w1 = (const float*)d_in[1];
  const float* enc_b1 = (const float*)d_in[2];
  const float* enc_w2 = (const float*)d_in[3];
  const float* enc_b2 = (const float*)d_in[4];
  const float* cb     = (const float*)d_in[5];
  const float* dec_w2 = (const float*)d_in[6];
  const float* dec_b2 = (const float*)d_in[7];
  const float* dec_w1 = (const float*)d_in[8];
  const float* dec_b1 = (const float*)d_in[9];

  float* out = (float*)d_out;
  float* ws  = (float*)d_ws;
  float* wT2 = ws;                        // 131072
  float* wTd = wT2 + 131072;              // 131072
  float* csq = wTd + 131072;              // 512
  float* dyn = csq + 512;                 // chunk buffers

  // Per-image: h = 2,097,152 floats (aliased as g), z/q (aliased) = 262,144.
  const size_t PER_IMG = 2097152 + 262144;                   // 2,359,296 floats
  size_t avail = (ws_size / 4 > 262656 + 64) ? ws_size / 4 - 262656 - 64 : 0;
  int CB = 32;
  while (CB > 1 && (size_t)CB * PER_IMG > avail) CB >>= 1;

  zero_loss_k<<<dim3(1), 64, 0, stream>>>(out);
  repack_k<<<dim3(512), 256, 0, stream>>>(enc_w2, dec_w2, wT2, wTd);
  csq_k<<<dim3(2), 256, 0, stream>>>(cb, csq);

  for (int b0 = 0; b0 < 32; b0 += CB) {
    float* h  = dyn;                                  // CB*2097152 (g aliases)
    float* zq = dyn + (size_t)CB * 2097152;           // CB*262144 (q aliases z)
    conv1_k<<<dim3(128, CB), 128, 0, stream>>>(
        x + (size_t)b0 * 65536, enc_w1, enc_b1, h);
    conv2_k<<<dim3(64, CB), 256, 0, stream>>>(h, wT2, enc_b2, zq);
    vq_k<<<dim3(CB * 16), 256, 0, stream>>>(zq, cb, csq, zq, out, b0 * 4096);
    dconv2_k<<<dim3(128, CB), 256, 0, stream>>>(zq, wTd, dec_b2, h /*g*/);
    dconv1_k<<<dim3(32, CB), 256, 0, stream>>>(
        h /*g*/, dec_w1, dec_b1, out + REC_OFF + (size_t)b0 * 65536);
  }
}

// Round 4
// 1601.880 us; speedup vs baseline: 1.2849x; 1.2159x over previous
//
#include <hip/hip_runtime.h>
#include <math.h>

// ---------------------------------------------------------------------------
// VQ-VAE forward, fp32 (decoder convT2 via bf16x3 MFMA), batch-chunked.
//  x (32,1,256,256) -> h (32,128,128,128) -> z (32,64,64,64)
//  VQ: N=131072 x D=64 vs K=512   (q packed bf16 hi/lo, aliases z in-place)
//  q -> g (aliases h) -> x_recon (32,1,256,256)
// d_out: [0]=vq_loss, [1..131072]=idx (as float), [131073..]=x_recon
// ws: wT2 131072 f | wAf_hi 65536 f | wAf_lo 65536 f | csq 512 | chunk bufs
// ---------------------------------------------------------------------------

#define REC_OFF 131073

typedef unsigned short ushort_t;
typedef __attribute__((ext_vector_type(8))) short bf16x8;
typedef __attribute__((ext_vector_type(4))) float f32x4;
typedef __attribute__((ext_vector_type(4))) unsigned int u32x4;
union FragU { u32x4 u; bf16x8 h; };

__global__ __launch_bounds__(64) void zero_loss_k(float* __restrict__ out) {
  if (threadIdx.x == 0) out[0] = 0.f;
}

// ---------------- weight repacks ------------------------------------------
__global__ __launch_bounds__(256) void repack_k(
    const float* __restrict__ ew2,   // enc_w2 (d=64, c=128, ky, kx)
    float* __restrict__ wT2) {       // [(c*4+ky)*4+kx][d 0..63]
  int i = blockIdx.x * 256 + threadIdx.x;          // 131072 total
  int kx = i & 3, ky = (i >> 2) & 3, mid = (i >> 4) & 127, top = i >> 11;
  wT2[(((mid * 4 + ky) * 4 + kx) << 6) + top] = ew2[i];
}

// A-fragment table for dconv2 MFMA: [v][s][mtg][lane][j] bf16 hi/lo.
// v = (Y&1)*2 + pX.  k_local = 8*(lane>>4)+j -> ci = 8s+2g+(j>>2), tap = j&3.
// tap0=(kyA,kxB) tap1=(kyA,kxA) tap2=(kyB,kxB) tap3=(kyB,kxA).
__global__ __launch_bounds__(256) void repackA_k(
    const float* __restrict__ dw2,   // dec_w2 (ci=64, co=128, ky, kx)
    ushort_t* __restrict__ hi, ushort_t* __restrict__ lo) {
  int idx = blockIdx.x * 256 + threadIdx.x;        // 131072 total
  int j = idx & 7, l = (idx >> 3) & 63, mt = (idx >> 9) & 7;
  int s = (idx >> 12) & 7, v = idx >> 15;
  int co = (mt << 4) + (l & 15);
  int ci = (s << 3) + ((l >> 4) << 1) + (j >> 2);
  int tap = j & 3;
  int Yp = v >> 1, pX = v & 1;
  int kyA = 1 - Yp, kyB = kyA + 2;
  int kxA = pX ? 0 : 1, kxB = kxA + 2;
  int ky = (tap & 2) ? kyB : kyA;
  int kx = (tap & 1) ? kxA : kxB;
  float val = dw2[(((ci << 7) + co) << 4) + (ky << 2) + kx];
  unsigned u = __float_as_uint(val);
  float rf = val - __uint_as_float(u & 0xFFFF0000u);
  hi[idx] = (ushort_t)(u >> 16);
  lo[idx] = (ushort_t)(__float_as_uint(rf) >> 16);
}

__global__ __launch_bounds__(256) void csq_k(
    const float* __restrict__ cb, float* __restrict__ csq) {
  int k = blockIdx.x * 256 + threadIdx.x;          // 512 total
  const float* cp = cb + (k << 6);
  float s = 0.f;
#pragma unroll
  for (int d = 0; d < 64; ++d) s = fmaf(cp[d], cp[d], s);
  csq[k] = s;
}

// ---------------- conv1 (1->128, 4x4, s2, p1) + relu ------------------------
__global__ __launch_bounds__(128) void conv1_k(
    const float* __restrict__ x, const float* __restrict__ w1,
    const float* __restrict__ b1, float* __restrict__ h) {
  int oy = blockIdx.x, b = blockIdx.y, ox = threadIdx.x;
  float xv[16];
#pragma unroll
  for (int ky = 0; ky < 4; ++ky) {
    int iy = 2 * oy - 1 + ky;
#pragma unroll
    for (int kx = 0; kx < 4; ++kx) {
      int ix = 2 * ox - 1 + kx;
      float v = 0.f;
      if (iy >= 0 && iy < 256 && ix >= 0 && ix < 256)
        v = x[(b * 256 + iy) * 256 + ix];
      xv[ky * 4 + kx] = v;
    }
  }
  for (int c = 0; c < 128; ++c) {
    const float* wp = w1 + c * 16;                 // wave-uniform -> s_load
    float acc = b1[c];
#pragma unroll
    for (int k = 0; k < 16; ++k) acc = fmaf(xv[k], wp[k], acc);
    h[((b * 128 + c) * 128 + oy) * 128 + ox] = fmaxf(acc, 0.f);
  }
}

// ---------------- conv2 (128->64, 4x4, s2, p1) + relu -----------------------
// 512 thr = 8 waves: H = w>>2 channel-half (0:c<64, 1:c>=64), d0 = (w&3)*16.
// 16 rounds of 4 channels per half; LDS reduce of the two halves at the end.
#define C2_STEP 4
__global__ __launch_bounds__(512) void conv2_k(
    const float* __restrict__ h, const float* __restrict__ wT2,
    const float* __restrict__ b2, float* __restrict__ z) {
  __shared__ float in4[2][C2_STEP][4][136];        // 17.4 KB
  __shared__ float red[64][64];                    // 16 KB
  int y = blockIdx.x, b = blockIdx.y;
  int t = threadIdx.x, l = t & 63;
  int w = __builtin_amdgcn_readfirstlane(t >> 6);
  int H = w >> 2;
  int d0 = (w & 3) << 4;
  float acc[16];
#pragma unroll
  for (int i = 0; i < 16; ++i) acc[i] = 0.f;

  for (int k0 = 0; k0 < 16; ++k0) {
    __syncthreads();
    for (int s = t; s < 2 * C2_STEP * 544; s += 512) {
      int half = s / 2176, r = s - half * 2176;
      int cc = r / 544, r2 = r - cc * 544;
      int ky = r2 / 136, i = r2 - ky * 136;
      int c = (half << 6) + (k0 << 2) + cc;
      int iy = 2 * y - 1 + ky, ix = i - 1;
      float v = 0.f;
      if (i < 132 && iy >= 0 && iy < 128 && ix >= 0 && ix < 128)
        v = h[((b * 128 + c) * 128 + iy) * 128 + ix];
      in4[half][cc][ky][i] = v;
    }
    __syncthreads();
#pragma unroll
    for (int cc = 0; cc < C2_STEP; ++cc) {
      int c = (H << 6) + (k0 << 2) + cc;
#pragma unroll
      for (int ky = 0; ky < 4; ++ky) {
        const float2 xa = *reinterpret_cast<const float2*>(&in4[H][cc][ky][2 * l]);
        const float2 xb = *reinterpret_cast<const float2*>(&in4[H][cc][ky][2 * l + 2]);
        float xk[4] = {xa.x, xa.y, xb.x, xb.y};
        const float* wp = wT2 + (((c * 4 + ky) * 4) << 6) + d0;
#pragma unroll
        for (int kx = 0; kx < 4; ++kx) {
          const float* wq = wp + (kx << 6);        // wave-uniform -> s_load
          float xs = xk[kx];
#pragma unroll
          for (int dd = 0; dd < 16; ++dd) acc[dd] = fmaf(wq[dd], xs, acc[dd]);
        }
      }
    }
  }
  __syncthreads();
  if (H == 1) {
#pragma unroll
    for (int dd = 0; dd < 16; ++dd) red[d0 + dd][l] = acc[dd];
  }
  __syncthreads();
  if (H == 0) {
#pragma unroll
    for (int dd = 0; dd < 16; ++dd) {
      float v = fmaxf(acc[dd] + red[d0 + dd][l] + b2[d0 + dd], 0.f);
      z[((b * 64 + d0 + dd) * 64 + y) * 64 + l] = v;
    }
  }
}

// ---------------- VQ: argmin + quantize (packed bf16 hi/lo) + loss ----------
// Reads full z column to regs first, then writes packed q over z (alias ok).
__global__ __launch_bounds__(256) void vq_k(
    const float* __restrict__ z, const float* __restrict__ cb,
    const float* __restrict__ csq, unsigned int* __restrict__ q_pk,
    float* __restrict__ out, int n0) {
  int n = blockIdx.x * 256 + threadIdx.x;          // chunk-local
  int b = n >> 12, rem = n & 4095, y = rem >> 6, x = rem & 63;
  const float* zp = z + ((b * 64) * 64 + y) * 64 + x;
  float zr[64];
#pragma unroll
  for (int d = 0; d < 64; ++d) zr[d] = zp[d * 4096];

  float bestd = 1e30f;
  int bestk = 0;
  for (int k = 0; k < 512; ++k) {
    const float* cp = cb + (k << 6);               // wave-uniform -> s_load
    float d0a = 0.f, d1a = 0.f;
#pragma unroll
    for (int d = 0; d < 64; d += 2) {
      d0a = fmaf(cp[d], zr[d], d0a);
      d1a = fmaf(cp[d + 1], zr[d + 1], d1a);
    }
    float dist = csq[k] - 2.f * (d0a + d1a);       // monotonic in true distance
    if (dist < bestd) { bestd = dist; bestk = k; } // strict '<' keeps first min
  }
  out[1 + n0 + n] = (float)bestk;

  const float* cbest = cb + (bestk << 6);
  unsigned int* qp = q_pk + ((b * 64) * 64 + y) * 64 + x;
  float ls = 0.f;
#pragma unroll
  for (int d = 0; d < 64; ++d) {
    float c = cbest[d];
    unsigned u = __float_as_uint(c);
    unsigned htop = u & 0xFFFF0000u;
    float rf = c - __uint_as_float(htop);
    qp[d * 4096] = htop | (__float_as_uint(rf) >> 16);
    float df = c - zr[d];
    ls = fmaf(df, df, ls);
  }
#pragma unroll
  for (int m = 32; m; m >>= 1) ls += __shfl_xor(ls, m);
  __shared__ float red[4];
  if ((threadIdx.x & 63) == 0) red[threadIdx.x >> 6] = ls;
  __syncthreads();
  if (threadIdx.x == 0)
    atomicAdd(out, (red[0] + red[1] + red[2] + red[3]) * (1.25f / 8388608.f));
}

// ---------------- convT2 (64->128, 4x4, s2, p1) + relu: bf16x3 MFMA ---------
// block=(Y,b): 4 waves (pX = w&1, coh = w>>1). Per parity a GEMM
// M=128(co) x N=64(l_pos) x K=256(ci*4taps); wave does M'=64 x N=64.
__global__ __launch_bounds__(256) void dconv2_k(
    const unsigned int* __restrict__ q_pk, const ushort_t* __restrict__ wAh,
    const ushort_t* __restrict__ wAl, const float* __restrict__ db2,
    float* __restrict__ g) {
  __shared__ unsigned int rows[64][2][68];         // 34.8 KB packed hi|lo
  int Y = blockIdx.x, b = blockIdx.y;
  int t = threadIdx.x, l = t & 63;
  int w = __builtin_amdgcn_readfirstlane(t >> 6);
  int pX = w & 1, coh = w >> 1;
  int yA = (Y + 1) >> 1, yB = yA - 1;
  int v = ((Y & 1) << 1) | pX;

  for (int s = t; s < 64 * 2 * 68; s += 256) {
    int ci = s / 136, r2 = s - ci * 136;
    int r = r2 / 68, i = r2 - r * 68;
    int yy = r ? yB : yA, ix = i - 1;
    unsigned val = 0u;
    if (i < 66 && yy >= 0 && yy < 64 && ix >= 0 && ix < 64)
      val = q_pk[((b * 64 + ci) * 64 + yy) * 64 + ix];
    rows[ci][r][i] = val;
  }
  __syncthreads();

  f32x4 acc[4][4];
#pragma unroll
  for (int mt = 0; mt < 4; ++mt)
#pragma unroll
    for (int nt = 0; nt < 4; ++nt) acc[mt][nt] = (f32x4)0.f;

  for (int s8 = 0; s8 < 8; ++s8) {
    FragU ah[4], al[4];
#pragma unroll
    for (int mt = 0; mt < 4; ++mt) {
      long off = ((((long)(v * 8 + s8) * 8 + (coh * 4 + mt)) * 64 + l) * 8);
      ah[mt].u = *reinterpret_cast<const u32x4*>(wAh + off);
      al[mt].u = *reinterpret_cast<const u32x4*>(wAl + off);
    }
#pragma unroll
    for (int nt = 0; nt < 4; ++nt) {
      int p = nt * 16 + (l & 15) + pX;
      int cc0 = (s8 << 3) + ((l >> 4) << 1);
      unsigned u0 = rows[cc0][0][p], u1 = rows[cc0][0][p + 1];
      unsigned u2 = rows[cc0][1][p], u3 = rows[cc0][1][p + 1];
      unsigned u4 = rows[cc0 + 1][0][p], u5 = rows[cc0 + 1][0][p + 1];
      unsigned u6 = rows[cc0 + 1][1][p], u7 = rows[cc0 + 1][1][p + 1];
      FragU bh, bl;
      bh.u[0] = (u0 >> 16) | (u1 & 0xFFFF0000u);
      bl.u[0] = (u0 & 0xFFFFu) | (u1 << 16);
      bh.u[1] = (u2 >> 16) | (u3 & 0xFFFF0000u);
      bl.u[1] = (u2 & 0xFFFFu) | (u3 << 16);
      bh.u[2] = (u4 >> 16) | (u5 & 0xFFFF0000u);
      bl.u[2] = (u4 & 0xFFFFu) | (u5 << 16);
      bh.u[3] = (u6 >> 16) | (u7 & 0xFFFF0000u);
      bl.u[3] = (u6 & 0xFFFFu) | (u7 << 16);
#pragma unroll
      for (int mt = 0; mt < 4; ++mt) {
        acc[mt][nt] = __builtin_amdgcn_mfma_f32_16x16x32_bf16(
            ah[mt].h, bh.h, acc[mt][nt], 0, 0, 0);
        acc[mt][nt] = __builtin_amdgcn_mfma_f32_16x16x32_bf16(
            ah[mt].h, bl.h, acc[mt][nt], 0, 0, 0);
        acc[mt][nt] = __builtin_amdgcn_mfma_f32_16x16x32_bf16(
            al[mt].h, bh.h, acc[mt][nt], 0, 0, 0);
      }
    }
  }

#pragma unroll
  for (int mt = 0; mt < 4; ++mt) {
#pragma unroll
    for (int r = 0; r < 4; ++r) {
      int co = ((coh * 4 + mt) << 4) + ((l >> 4) << 2) + r;
      float bias = db2[co];
#pragma unroll
      for (int nt = 0; nt < 4; ++nt) {
        int X = ((nt << 4) + (l & 15)) * 2 + pX;
        float val = fmaxf(acc[mt][nt][r] + bias, 0.f);
        g[((b * 128 + co) * 128 + Y) * 128 + X] = val;
      }
    }
  }
}

// ---------------- convT1 (128->1, 4x4, s2, p1) + sigmoid --------------------
#define DC1_STEP 2
__global__ __launch_bounds__(256) void dconv1_k(
    const float* __restrict__ g, const float* __restrict__ wd1,
    const float* __restrict__ db1, float* __restrict__ rec) {
  __shared__ float rows[DC1_STEP][6][132];
  int a = blockIdx.x, b = blockIdx.y;
  int t = threadIdx.x;
  int w = __builtin_amdgcn_readfirstlane(t >> 6);
  int l = t & 63;
  int xh = w >> 1, pX = w & 1;
  int L = xh * 64 + l;                       // X = 2L + pX
  int kxA = pX ? 0 : 1, kxB = kxA + 2;
  float acc[8];
#pragma unroll
  for (int i = 0; i < 8; ++i) acc[i] = 0.f;

  for (int c0 = 0; c0 < 128; c0 += DC1_STEP) {
    __syncthreads();
    for (int s = t; s < DC1_STEP * 792; s += 256) {
      int cc = s / 792, r2 = s - cc * 792;
      int r = r2 / 132, i = r2 - r * 132;
      int yy = 4 * a - 1 + r, ix = i - 1;
      float v = 0.f;
      if (i < 130 && yy >= 0 && yy < 128 && ix >= 0 && ix < 128)
        v = g[((b * 128 + c0 + cc) * 128 + yy) * 128 + ix];
      rows[cc][r][i] = v;
    }
    __syncthreads();
#pragma unroll
    for (int cc = 0; cc < DC1_STEP; ++cc) {
      const float* wp = wd1 + (c0 + cc) * 16;  // contiguous taps -> s_load
      float rhi[6], rlo[6];
#pragma unroll
      for (int r = 0; r < 6; ++r) {
        rhi[r] = rows[cc][r][L + pX + 1];
        rlo[r] = rows[cc][r][L + pX];
      }
#pragma unroll
      for (int j = 0; j < 8; ++j) {
        int kyA = (j + 1) & 1, kyB = kyA + 2;
        int rA = ((j + 1) >> 1) + 1;
        float v = acc[j];
        v = fmaf(wp[kyA * 4 + kxA], rhi[rA], v);
        v = fmaf(wp[kyA * 4 + kxB], rlo[rA], v);
        v = fmaf(wp[kyB * 4 + kxA], rhi[rA - 1], v);
        v = fmaf(wp[kyB * 4 + kxB], rlo[rA - 1], v);
        acc[j] = v;
      }
    }
  }
  float bb = db1[0];
#pragma unroll
  for (int j = 0; j < 8; ++j) {
    float v = acc[j] + bb;
    v = 1.f / (1.f + __expf(-v));
    rec[((b * 256 + 8 * a + j) * 256) + 2 * L + pX] = v;
  }
}

// ---------------------------------------------------------------------------
extern "C" void kernel_launch(void* const* d_in, const int* in_sizes, int n_in,
                              void* d_out, int out_size, void* d_ws, size_t ws_size,
                              hipStream_t stream) {
  const float* x      = (const float*)d_in[0];
  const float* enc_w1 = (const float*)d_in[1];
  const float* enc_b1 = (const float*)d_in[2];
  const float* enc_w2 = (const float*)d_in[3];
  const float* enc_b2 = (const float*)d_in[4];
  const float* cb     = (const float*)d_in[5];
  const float* dec_w2 = (const float*)d_in[6];
  const float* dec_b2 = (const float*)d_in[7];
  const float* dec_w1 = (const float*)d_in[8];
  const float* dec_b1 = (const float*)d_in[9];

  float* out = (float*)d_out;
  float* ws  = (float*)d_ws;
  float* wT2 = ws;                              // 131072 f
  ushort_t* wAh = (ushort_t*)(ws + 131072);     // 131072 ushort = 65536 f
  ushort_t* wAl = (ushort_t*)(ws + 131072 + 65536);
  float* csq = ws + 262144;                     // 512
  float* dyn = ws + 262656;                     // chunk buffers

  // Per-image: h = 2,097,152 floats (aliased as g), z/q_pk (aliased) = 262,144.
  const size_t PER_IMG = 2097152 + 262144;                   // 2,359,296 floats
  size_t avail = (ws_size / 4 > 262656 + 64) ? ws_size / 4 - 262656 - 64 : 0;
  int CB = 32;
  while (CB > 1 && (size_t)CB * PER_IMG > avail) CB >>= 1;

  zero_loss_k<<<dim3(1), 64, 0, stream>>>(out);
  repack_k<<<dim3(512), 256, 0, stream>>>(enc_w2, wT2);
  repackA_k<<<dim3(512), 256, 0, stream>>>(dec_w2, wAh, wAl);
  csq_k<<<dim3(2), 256, 0, stream>>>(cb, csq);

  for (int b0 = 0; b0 < 32; b0 += CB) {
    float* h  = dyn;                                  // CB*2097152 (g aliases)
    float* zq = dyn + (size_t)CB * 2097152;           // CB*262144 (q_pk aliases)
    conv1_k<<<dim3(128, CB), 128, 0, stream>>>(
        x + (size_t)b0 * 65536, enc_w1, enc_b1, h);
    conv2_k<<<dim3(64, CB), 512, 0, stream>>>(h, wT2, enc_b2, zq);
    vq_k<<<dim3(CB * 16), 256, 0, stream>>>(
        zq, cb, csq, (unsigned int*)zq, out, b0 * 4096);
    dconv2_k<<<dim3(128, CB), 256, 0, stream>>>(
        (const unsigned int*)zq, wAh, wAl, dec_b2, h /*g*/);
    dconv1_k<<<dim3(32, CB), 256, 0, stream>>>(
        h /*g*/, dec_w1, dec_b1, out + REC_OFF + (size_t)b0 * 65536);
  }
}

// Round 5
// 1312.108 us; speedup vs baseline: 1.5687x; 1.2208x over previous
//
#include <hip/hip_runtime.h>
#include <math.h>

// ---------------------------------------------------------------------------
// VQ-VAE forward, bf16x3-MFMA for conv2 & convT2, batch-chunked.
//  x (32,1,256,256) -> h_pk (32,128,128,128 u32 hi|lo) -> z (32,64,64,64 f32)
//  VQ: N=131072 x D=64 vs K=512   (q packed bf16 hi/lo, aliases z in-place)
//  q -> g (f32, aliases h_pk) -> x_recon (32,1,256,256)
// d_out: [0]=vq_loss, [1..131072]=idx (as float), [131073..]=x_recon
// ws: wCh 64Kf | wCl 64Kf | wAh 64Kf | wAl 64Kf | csq 512 | chunk bufs
// Fragment conventions (HW-verified in round 4 dconv2, absmax 0.0):
//   A/B: lane l holds k_local = 8*(l>>4)+j, m/n = l&15
//   C/D: row = (l>>4)*4 + reg, col = l&15
// ---------------------------------------------------------------------------

#define REC_OFF 131073

typedef unsigned short ushort_t;
typedef __attribute__((ext_vector_type(8))) short bf16x8;
typedef __attribute__((ext_vector_type(4))) float f32x4;
typedef __attribute__((ext_vector_type(4))) unsigned int u32x4;
union FragU { u32x4 u; bf16x8 h; };

__device__ __forceinline__ unsigned pack_hilo(float v) {
  unsigned u = __float_as_uint(v);
  unsigned htop = u & 0xFFFF0000u;
  float rf = v - __uint_as_float(htop);
  return htop | (__float_as_uint(rf) >> 16);
}

__global__ __launch_bounds__(64) void zero_loss_k(float* __restrict__ out) {
  if (threadIdx.x == 0) out[0] = 0.f;
}

// ---- conv2 A-table: [ks=ci0*4+ky][mt][lane][j] bf16 hi/lo -----------------
// k_local j: ci = (ks>>2)*8 + (l>>4)*2 + (j>>2), ky = ks&3, kx = j&3,
// d = mt*16 + (l&15).  src enc_w2 (d=64, ci=128, ky, kx).
__global__ __launch_bounds__(256) void repackA2_k(
    const float* __restrict__ ew2,
    ushort_t* __restrict__ hi, ushort_t* __restrict__ lo) {
  int idx = blockIdx.x * 256 + threadIdx.x;        // 131072 total
  int j = idx & 7, l = (idx >> 3) & 63, mt = (idx >> 9) & 3, ks = idx >> 11;
  int ci = ((ks >> 2) << 3) + ((l >> 4) << 1) + (j >> 2);
  int ky = ks & 3, kx = j & 3, d = (mt << 4) + (l & 15);
  float val = ew2[((d << 7) + ci) * 16 + (ky << 2) + kx];
  unsigned u = __float_as_uint(val);
  float rf = val - __uint_as_float(u & 0xFFFF0000u);
  hi[idx] = (ushort_t)(u >> 16);
  lo[idx] = (ushort_t)(__float_as_uint(rf) >> 16);
}

// ---- dconv2 A-table (unchanged from round 4, proven) ----------------------
__global__ __launch_bounds__(256) void repackA_k(
    const float* __restrict__ dw2,   // dec_w2 (ci=64, co=128, ky, kx)
    ushort_t* __restrict__ hi, ushort_t* __restrict__ lo) {
  int idx = blockIdx.x * 256 + threadIdx.x;        // 131072 total
  int j = idx & 7, l = (idx >> 3) & 63, mt = (idx >> 9) & 7;
  int s = (idx >> 12) & 7, v = idx >> 15;
  int co = (mt << 4) + (l & 15);
  int ci = (s << 3) + ((l >> 4) << 1) + (j >> 2);
  int tap = j & 3;
  int Yp = v >> 1, pX = v & 1;
  int kyA = 1 - Yp, kyB = kyA + 2;
  int kxA = pX ? 0 : 1, kxB = kxA + 2;
  int ky = (tap & 2) ? kyB : kyA;
  int kx = (tap & 1) ? kxA : kxB;
  float val = dw2[(((ci << 7) + co) << 4) + (ky << 2) + kx];
  unsigned u = __float_as_uint(val);
  float rf = val - __uint_as_float(u & 0xFFFF0000u);
  hi[idx] = (ushort_t)(u >> 16);
  lo[idx] = (ushort_t)(__float_as_uint(rf) >> 16);
}

__global__ __launch_bounds__(256) void csq_k(
    const float* __restrict__ cb, float* __restrict__ csq) {
  int k = blockIdx.x * 256 + threadIdx.x;          // 512 total
  const float* cp = cb + (k << 6);
  float s = 0.f;
#pragma unroll
  for (int d = 0; d < 64; ++d) s = fmaf(cp[d], cp[d], s);
  csq[k] = s;
}

// ---------------- conv1 (1->128, 4x4, s2, p1) + relu -> packed u32 ----------
__global__ __launch_bounds__(128) void conv1_k(
    const float* __restrict__ x, const float* __restrict__ w1,
    const float* __restrict__ b1, unsigned* __restrict__ hp) {
  int oy = blockIdx.x, b = blockIdx.y, ox = threadIdx.x;
  float xv[16];
#pragma unroll
  for (int ky = 0; ky < 4; ++ky) {
    int iy = 2 * oy - 1 + ky;
#pragma unroll
    for (int kx = 0; kx < 4; ++kx) {
      int ix = 2 * ox - 1 + kx;
      float v = 0.f;
      if (iy >= 0 && iy < 256 && ix >= 0 && ix < 256)
        v = x[(b * 256 + iy) * 256 + ix];
      xv[ky * 4 + kx] = v;
    }
  }
  for (int c = 0; c < 128; ++c) {
    const float* wp = w1 + c * 16;                 // wave-uniform -> s_load
    float acc = b1[c];
#pragma unroll
    for (int k = 0; k < 16; ++k) acc = fmaf(xv[k], wp[k], acc);
    hp[((b * 128 + c) * 128 + oy) * 128 + ox] = pack_hilo(fmaxf(acc, 0.f));
  }
}

// ---------------- conv2 (128->64, 4x4, s2, p1) + relu: bf16x3 MFMA ----------
// block=(y,b), 4 waves = nt (x-quarter). GEMM M=64(d) N=64(x) K=2048.
// 16 rounds of 8 ci; per round 4 ky-ksteps; per (wave,kstep): 12 MFMA.
__global__ __launch_bounds__(256) void conv2_k(
    const unsigned* __restrict__ hp, const ushort_t* __restrict__ wCh,
    const ushort_t* __restrict__ wCl, const float* __restrict__ b2,
    float* __restrict__ z) {
  __shared__ unsigned hs[8][4][134];               // 17.2 KB (134: bank stagger)
  int y = blockIdx.x, b = blockIdx.y;
  int t = threadIdx.x, l = t & 63;
  int nt = __builtin_amdgcn_readfirstlane(t >> 6);
  int g = l >> 4;
  int x = (nt << 4) + (l & 15);

  f32x4 acc[4];
#pragma unroll
  for (int mt = 0; mt < 4; ++mt) acc[mt] = (f32x4)0.f;

  for (int rnd = 0; rnd < 16; ++rnd) {
    __syncthreads();
    for (int s = t; s < 8 * 4 * 130; s += 256) {
      int ci_l = s / 520, r2 = s - ci_l * 520;
      int r = r2 / 130, i = r2 - r * 130;
      int ci = (rnd << 3) + ci_l;
      int iy = 2 * y - 1 + r, ix = i - 1;
      unsigned v = 0u;
      if (iy >= 0 && iy < 128 && ix >= 0 && ix < 128)
        v = hp[((b * 128 + ci) * 128 + iy) * 128 + ix];
      hs[ci_l][r][i] = v;
    }
    __syncthreads();
#pragma unroll
    for (int ky = 0; ky < 4; ++ky) {
      int ks = (rnd << 2) + ky;
      FragU ah[4], al_[4];
#pragma unroll
      for (int mt = 0; mt < 4; ++mt) {
        long aoff = ((((long)ks * 4 + mt) * 64 + l) * 8);
        ah[mt].u = *reinterpret_cast<const u32x4*>(wCh + aoff);
        al_[mt].u = *reinterpret_cast<const u32x4*>(wCl + aoff);
      }
      const unsigned* pa = &hs[g * 2][ky][2 * x];
      const unsigned* pb = &hs[g * 2 + 1][ky][2 * x];
      unsigned a0 = pa[0], a1 = pa[1], a2 = pa[2], a3 = pa[3];
      unsigned b0 = pb[0], b1 = pb[1], b2_ = pb[2], b3 = pb[3];
      FragU bh, bl;
      bh.u[0] = __builtin_amdgcn_perm(a1, a0, 0x07060302u);
      bl.u[0] = __builtin_amdgcn_perm(a1, a0, 0x05040100u);
      bh.u[1] = __builtin_amdgcn_perm(a3, a2, 0x07060302u);
      bl.u[1] = __builtin_amdgcn_perm(a3, a2, 0x05040100u);
      bh.u[2] = __builtin_amdgcn_perm(b1, b0, 0x07060302u);
      bl.u[2] = __builtin_amdgcn_perm(b1, b0, 0x05040100u);
      bh.u[3] = __builtin_amdgcn_perm(b3, b2_, 0x07060302u);
      bl.u[3] = __builtin_amdgcn_perm(b3, b2_, 0x05040100u);
#pragma unroll
      for (int mt = 0; mt < 4; ++mt) {
        acc[mt] = __builtin_amdgcn_mfma_f32_16x16x32_bf16(
            ah[mt].h, bh.h, acc[mt], 0, 0, 0);
        acc[mt] = __builtin_amdgcn_mfma_f32_16x16x32_bf16(
            ah[mt].h, bl.h, acc[mt], 0, 0, 0);
        acc[mt] = __builtin_amdgcn_mfma_f32_16x16x32_bf16(
            al_[mt].h, bh.h, acc[mt], 0, 0, 0);
      }
    }
  }
#pragma unroll
  for (int mt = 0; mt < 4; ++mt) {
#pragma unroll
    for (int r = 0; r < 4; ++r) {
      int d = (mt << 4) + ((l >> 4) << 2) + r;
      float v = fmaxf(acc[mt][r] + b2[d], 0.f);
      z[((b * 64 + d) * 64 + y) * 64 + x] = v;
    }
  }
}

// ---------------- VQ: argmin + quantize (packed bf16 hi/lo) + loss ----------
__global__ __launch_bounds__(256) void vq_k(
    const float* __restrict__ z, const float* __restrict__ cb,
    const float* __restrict__ csq, unsigned int* __restrict__ q_pk,
    float* __restrict__ out, int n0) {
  int n = blockIdx.x * 256 + threadIdx.x;          // chunk-local
  int b = n >> 12, rem = n & 4095, y = rem >> 6, x = rem & 63;
  const float* zp = z + ((b * 64) * 64 + y) * 64 + x;
  float zr[64];
#pragma unroll
  for (int d = 0; d < 64; ++d) zr[d] = zp[d * 4096];

  float bestd = 1e30f;
  int bestk = 0;
  for (int k = 0; k < 512; ++k) {
    const float* cp = cb + (k << 6);               // wave-uniform -> s_load
    float d0a = 0.f, d1a = 0.f;
#pragma unroll
    for (int d = 0; d < 64; d += 2) {
      d0a = fmaf(cp[d], zr[d], d0a);
      d1a = fmaf(cp[d + 1], zr[d + 1], d1a);
    }
    float dist = csq[k] - 2.f * (d0a + d1a);       // monotonic in true distance
    if (dist < bestd) { bestd = dist; bestk = k; } // strict '<' keeps first min
  }
  out[1 + n0 + n] = (float)bestk;

  const float* cbest = cb + (bestk << 6);
  unsigned int* qp = q_pk + ((b * 64) * 64 + y) * 64 + x;
  float ls = 0.f;
#pragma unroll
  for (int d = 0; d < 64; ++d) {
    float c = cbest[d];
    qp[d * 4096] = pack_hilo(c);
    float df = c - zr[d];
    ls = fmaf(df, df, ls);
  }
#pragma unroll
  for (int m = 32; m; m >>= 1) ls += __shfl_xor(ls, m);
  __shared__ float red[4];
  if ((threadIdx.x & 63) == 0) red[threadIdx.x >> 6] = ls;
  __syncthreads();
  if (threadIdx.x == 0)
    atomicAdd(out, (red[0] + red[1] + red[2] + red[3]) * (1.25f / 8388608.f));
}

// ---------------- convT2 (64->128, 4x4, s2, p1) + relu: bf16x3 MFMA ---------
__global__ __launch_bounds__(256) void dconv2_k(
    const unsigned int* __restrict__ q_pk, const ushort_t* __restrict__ wAh,
    const ushort_t* __restrict__ wAl, const float* __restrict__ db2,
    float* __restrict__ g) {
  __shared__ unsigned int rows[64][2][68];         // 34.8 KB packed hi|lo
  int Y = blockIdx.x, b = blockIdx.y;
  int t = threadIdx.x, l = t & 63;
  int w = __builtin_amdgcn_readfirstlane(t >> 6);
  int pX = w & 1, coh = w >> 1;
  int yA = (Y + 1) >> 1, yB = yA - 1;
  int v = ((Y & 1) << 1) | pX;

  for (int s = t; s < 64 * 2 * 68; s += 256) {
    int ci = s / 136, r2 = s - ci * 136;
    int r = r2 / 68, i = r2 - r * 68;
    int yy = r ? yB : yA, ix = i - 1;
    unsigned val = 0u;
    if (i < 66 && yy >= 0 && yy < 64 && ix >= 0 && ix < 64)
      val = q_pk[((b * 64 + ci) * 64 + yy) * 64 + ix];
    rows[ci][r][i] = val;
  }
  __syncthreads();

  f32x4 acc[4][4];
#pragma unroll
  for (int mt = 0; mt < 4; ++mt)
#pragma unroll
    for (int nt = 0; nt < 4; ++nt) acc[mt][nt] = (f32x4)0.f;

  for (int s8 = 0; s8 < 8; ++s8) {
    FragU ah[4], al[4];
#pragma unroll
    for (int mt = 0; mt < 4; ++mt) {
      long off = ((((long)(v * 8 + s8) * 8 + (coh * 4 + mt)) * 64 + l) * 8);
      ah[mt].u = *reinterpret_cast<const u32x4*>(wAh + off);
      al[mt].u = *reinterpret_cast<const u32x4*>(wAl + off);
    }
#pragma unroll
    for (int nt = 0; nt < 4; ++nt) {
      int p = nt * 16 + (l & 15) + pX;
      int cc0 = (s8 << 3) + ((l >> 4) << 1);
      unsigned u0 = rows[cc0][0][p], u1 = rows[cc0][0][p + 1];
      unsigned u2 = rows[cc0][1][p], u3 = rows[cc0][1][p + 1];
      unsigned u4 = rows[cc0 + 1][0][p], u5 = rows[cc0 + 1][0][p + 1];
      unsigned u6 = rows[cc0 + 1][1][p], u7 = rows[cc0 + 1][1][p + 1];
      FragU bh, bl;
      bh.u[0] = (u0 >> 16) | (u1 & 0xFFFF0000u);
      bl.u[0] = (u0 & 0xFFFFu) | (u1 << 16);
      bh.u[1] = (u2 >> 16) | (u3 & 0xFFFF0000u);
      bl.u[1] = (u2 & 0xFFFFu) | (u3 << 16);
      bh.u[2] = (u4 >> 16) | (u5 & 0xFFFF0000u);
      bl.u[2] = (u4 & 0xFFFFu) | (u5 << 16);
      bh.u[3] = (u6 >> 16) | (u7 & 0xFFFF0000u);
      bl.u[3] = (u6 & 0xFFFFu) | (u7 << 16);
#pragma unroll
      for (int mt = 0; mt < 4; ++mt) {
        acc[mt][nt] = __builtin_amdgcn_mfma_f32_16x16x32_bf16(
            ah[mt].h, bh.h, acc[mt][nt], 0, 0, 0);
        acc[mt][nt] = __builtin_amdgcn_mfma_f32_16x16x32_bf16(
            ah[mt].h, bl.h, acc[mt][nt], 0, 0, 0);
        acc[mt][nt] = __builtin_amdgcn_mfma_f32_16x16x32_bf16(
            al[mt].h, bh.h, acc[mt][nt], 0, 0, 0);
      }
    }
  }

#pragma unroll
  for (int mt = 0; mt < 4; ++mt) {
#pragma unroll
    for (int r = 0; r < 4; ++r) {
      int co = ((coh * 4 + mt) << 4) + ((l >> 4) << 2) + r;
      float bias = db2[co];
#pragma unroll
      for (int nt = 0; nt < 4; ++nt) {
        int X = ((nt << 4) + (l & 15)) * 2 + pX;
        float val = fmaxf(acc[mt][nt][r] + bias, 0.f);
        g[((b * 128 + co) * 128 + Y) * 128 + X] = val;
      }
    }
  }
}

// ---------------- convT1 (128->1, 4x4, s2, p1) + sigmoid --------------------
#define DC1_STEP 2
__global__ __launch_bounds__(256) void dconv1_k(
    const float* __restrict__ g, const float* __restrict__ wd1,
    const float* __restrict__ db1, float* __restrict__ rec) {
  __shared__ float rows[DC1_STEP][6][132];
  int a = blockIdx.x, b = blockIdx.y;
  int t = threadIdx.x;
  int w = __builtin_amdgcn_readfirstlane(t >> 6);
  int l = t & 63;
  int xh = w >> 1, pX = w & 1;
  int L = xh * 64 + l;                       // X = 2L + pX
  int kxA = pX ? 0 : 1, kxB = kxA + 2;
  float acc[8];
#pragma unroll
  for (int i = 0; i < 8; ++i) acc[i] = 0.f;

  for (int c0 = 0; c0 < 128; c0 += DC1_STEP) {
    __syncthreads();
    for (int s = t; s < DC1_STEP * 792; s += 256) {
      int cc = s / 792, r2 = s - cc * 792;
      int r = r2 / 132, i = r2 - r * 132;
      int yy = 4 * a - 1 + r, ix = i - 1;
      float v = 0.f;
      if (i < 130 && yy >= 0 && yy < 128 && ix >= 0 && ix < 128)
        v = g[((b * 128 + c0 + cc) * 128 + yy) * 128 + ix];
      rows[cc][r][i] = v;
    }
    __syncthreads();
#pragma unroll
    for (int cc = 0; cc < DC1_STEP; ++cc) {
      const float* wp = wd1 + (c0 + cc) * 16;  // contiguous taps -> s_load
      float rhi[6], rlo[6];
#pragma unroll
      for (int r = 0; r < 6; ++r) {
        rhi[r] = rows[cc][r][L + pX + 1];
        rlo[r] = rows[cc][r][L + pX];
      }
#pragma unroll
      for (int j = 0; j < 8; ++j) {
        int kyA = (j + 1) & 1, kyB = kyA + 2;
        int rA = ((j + 1) >> 1) + 1;
        float v = acc[j];
        v = fmaf(wp[kyA * 4 + kxA], rhi[rA], v);
        v = fmaf(wp[kyA * 4 + kxB], rlo[rA], v);
        v = fmaf(wp[kyB * 4 + kxA], rhi[rA - 1], v);
        v = fmaf(wp[kyB * 4 + kxB], rlo[rA - 1], v);
        acc[j] = v;
      }
    }
  }
  float bb = db1[0];
#pragma unroll
  for (int j = 0; j < 8; ++j) {
    float v = acc[j] + bb;
    v = 1.f / (1.f + __expf(-v));
    rec[((b * 256 + 8 * a + j) * 256) + 2 * L + pX] = v;
  }
}

// ---------------------------------------------------------------------------
extern "C" void kernel_launch(void* const* d_in, const int* in_sizes, int n_in,
                              void* d_out, int out_size, void* d_ws, size_t ws_size,
                              hipStream_t stream) {
  const float* x      = (const float*)d_in[0];
  const float* enc_w1 = (const float*)d_in[1];
  const float* enc_b1 = (const float*)d_in[2];
  const float* enc_w2 = (const float*)d_in[3];
  const float* enc_b2 = (const float*)d_in[4];
  const float* cb     = (const float*)d_in[5];
  const float* dec_w2 = (const float*)d_in[6];
  const float* dec_b2 = (const float*)d_in[7];
  const float* dec_w1 = (const float*)d_in[8];
  const float* dec_b1 = (const float*)d_in[9];

  float* out = (float*)d_out;
  float* ws  = (float*)d_ws;
  ushort_t* wCh = (ushort_t*)ws;                    // 131072 ushort = 65536 f
  ushort_t* wCl = (ushort_t*)(ws + 65536);
  ushort_t* wAh = (ushort_t*)(ws + 131072);
  ushort_t* wAl = (ushort_t*)(ws + 196608);
  float* csq = ws + 262144;                         // 512
  float* dyn = ws + 262656;                         // chunk buffers

  // Per-image: h_pk = 2,097,152 u32 (g f32 aliases), z/q_pk = 262,144.
  const size_t PER_IMG = 2097152 + 262144;                   // 2,359,296 elems
  size_t avail = (ws_size / 4 > 262656 + 64) ? ws_size / 4 - 262656 - 64 : 0;
  int CB = 32;
  while (CB > 1 && (size_t)CB * PER_IMG > avail) CB >>= 1;

  zero_loss_k<<<dim3(1), 64, 0, stream>>>(out);
  repackA2_k<<<dim3(512), 256, 0, stream>>>(enc_w2, wCh, wCl);
  repackA_k<<<dim3(512), 256, 0, stream>>>(dec_w2, wAh, wAl);
  csq_k<<<dim3(2), 256, 0, stream>>>(cb, csq);

  for (int b0 = 0; b0 < 32; b0 += CB) {
    unsigned* hp = (unsigned*)dyn;                    // CB*2097152 (g aliases)
    float* zq = dyn + (size_t)CB * 2097152;           // CB*262144 (q_pk aliases)
    conv1_k<<<dim3(128, CB), 128, 0, stream>>>(
        x + (size_t)b0 * 65536, enc_w1, enc_b1, hp);
    conv2_k<<<dim3(64, CB), 256, 0, stream>>>(hp, wCh, wCl, enc_b2, zq);
    vq_k<<<dim3(CB * 16), 256, 0, stream>>>(
        zq, cb, csq, (unsigned int*)zq, out, b0 * 4096);
    dconv2_k<<<dim3(128, CB), 256, 0, stream>>>(
        (const unsigned int*)zq, wAh, wAl, dec_b2, (float*)dyn /*g*/);
    dconv1_k<<<dim3(32, CB), 256, 0, stream>>>(
        (float*)dyn /*g*/, dec_w1, dec_b1, out + REC_OFF + (size_t)b0 * 65536);
  }
}

// Round 6
// 1198.401 us; speedup vs baseline: 1.7175x; 1.0949x over previous
//
#include <hip/hip_runtime.h>
#include <math.h>

// ---------------------------------------------------------------------------
// VQ-VAE forward, bf16x3-MFMA for conv2 & convT2, batch-chunked.
//  x (32,1,256,256) -> h_pk (32,128,128,128 u32 hi|lo) -> z (32,64,64,64 f32)
//  VQ: N=131072 x D=64 vs K=512   (q packed bf16 hi/lo, aliases z in-place)
//  q -> g (f32, aliases h_pk) -> x_recon (32,1,256,256)
// d_out: [0]=vq_loss, [1..131072]=idx (as float), [131073..]=x_recon
// ws: wCh 64Kf | wCl 64Kf | wAh 64Kf | wAl 64Kf | csq 512 | chunk bufs
// Fragment conventions (HW-verified, absmax 0.0 in rounds 4-5):
//   A/B: lane l holds k_local = 8*(l>>4)+j, m/n = l&15
//   C/D: row = (l>>4)*4 + reg, col = l&15
// Round 6: vq_k rebuilt — wave-split-K (4 waves x 128 codes), LDS-broadcast
// codebook tiles, 4-chain ILP, 4x-parallel quantize epilogue.
// ---------------------------------------------------------------------------

#define REC_OFF 131073

typedef unsigned short ushort_t;
typedef __attribute__((ext_vector_type(8))) short bf16x8;
typedef __attribute__((ext_vector_type(4))) float f32x4;
typedef __attribute__((ext_vector_type(4))) unsigned int u32x4;
union FragU { u32x4 u; bf16x8 h; };

__device__ __forceinline__ unsigned pack_hilo(float v) {
  unsigned u = __float_as_uint(v);
  unsigned htop = u & 0xFFFF0000u;
  float rf = v - __uint_as_float(htop);
  return htop | (__float_as_uint(rf) >> 16);
}

__global__ __launch_bounds__(64) void zero_loss_k(float* __restrict__ out) {
  if (threadIdx.x == 0) out[0] = 0.f;
}

// ---- conv2 A-table: [ks=ci0*4+ky][mt][lane][j] bf16 hi/lo -----------------
__global__ __launch_bounds__(256) void repackA2_k(
    const float* __restrict__ ew2,
    ushort_t* __restrict__ hi, ushort_t* __restrict__ lo) {
  int idx = blockIdx.x * 256 + threadIdx.x;        // 131072 total
  int j = idx & 7, l = (idx >> 3) & 63, mt = (idx >> 9) & 3, ks = idx >> 11;
  int ci = ((ks >> 2) << 3) + ((l >> 4) << 1) + (j >> 2);
  int ky = ks & 3, kx = j & 3, d = (mt << 4) + (l & 15);
  float val = ew2[((d << 7) + ci) * 16 + (ky << 2) + kx];
  unsigned u = __float_as_uint(val);
  float rf = val - __uint_as_float(u & 0xFFFF0000u);
  hi[idx] = (ushort_t)(u >> 16);
  lo[idx] = (ushort_t)(__float_as_uint(rf) >> 16);
}

// ---- dconv2 A-table (proven) ----------------------------------------------
__global__ __launch_bounds__(256) void repackA_k(
    const float* __restrict__ dw2,   // dec_w2 (ci=64, co=128, ky, kx)
    ushort_t* __restrict__ hi, ushort_t* __restrict__ lo) {
  int idx = blockIdx.x * 256 + threadIdx.x;        // 131072 total
  int j = idx & 7, l = (idx >> 3) & 63, mt = (idx >> 9) & 7;
  int s = (idx >> 12) & 7, v = idx >> 15;
  int co = (mt << 4) + (l & 15);
  int ci = (s << 3) + ((l >> 4) << 1) + (j >> 2);
  int tap = j & 3;
  int Yp = v >> 1, pX = v & 1;
  int kyA = 1 - Yp, kyB = kyA + 2;
  int kxA = pX ? 0 : 1, kxB = kxA + 2;
  int ky = (tap & 2) ? kyB : kyA;
  int kx = (tap & 1) ? kxA : kxB;
  float val = dw2[(((ci << 7) + co) << 4) + (ky << 2) + kx];
  unsigned u = __float_as_uint(val);
  float rf = val - __uint_as_float(u & 0xFFFF0000u);
  hi[idx] = (ushort_t)(u >> 16);
  lo[idx] = (ushort_t)(__float_as_uint(rf) >> 16);
}

__global__ __launch_bounds__(256) void csq_k(
    const float* __restrict__ cb, float* __restrict__ csq) {
  int k = blockIdx.x * 256 + threadIdx.x;          // 512 total
  const float* cp = cb + (k << 6);
  float s = 0.f;
#pragma unroll
  for (int d = 0; d < 64; ++d) s = fmaf(cp[d], cp[d], s);
  csq[k] = s;
}

// ---------------- conv1 (1->128, 4x4, s2, p1) + relu -> packed u32 ----------
__global__ __launch_bounds__(128) void conv1_k(
    const float* __restrict__ x, const float* __restrict__ w1,
    const float* __restrict__ b1, unsigned* __restrict__ hp) {
  int oy = blockIdx.x, b = blockIdx.y, ox = threadIdx.x;
  float xv[16];
#pragma unroll
  for (int ky = 0; ky < 4; ++ky) {
    int iy = 2 * oy - 1 + ky;
#pragma unroll
    for (int kx = 0; kx < 4; ++kx) {
      int ix = 2 * ox - 1 + kx;
      float v = 0.f;
      if (iy >= 0 && iy < 256 && ix >= 0 && ix < 256)
        v = x[(b * 256 + iy) * 256 + ix];
      xv[ky * 4 + kx] = v;
    }
  }
  for (int c = 0; c < 128; ++c) {
    const float* wp = w1 + c * 16;                 // wave-uniform -> s_load
    float acc = b1[c];
#pragma unroll
    for (int k = 0; k < 16; ++k) acc = fmaf(xv[k], wp[k], acc);
    hp[((b * 128 + c) * 128 + oy) * 128 + ox] = pack_hilo(fmaxf(acc, 0.f));
  }
}

// ---------------- conv2 (128->64, 4x4, s2, p1) + relu: bf16x3 MFMA ----------
__global__ __launch_bounds__(256) void conv2_k(
    const unsigned* __restrict__ hp, const ushort_t* __restrict__ wCh,
    const ushort_t* __restrict__ wCl, const float* __restrict__ b2,
    float* __restrict__ z) {
  __shared__ unsigned hs[8][4][134];               // 17.2 KB
  int y = blockIdx.x, b = blockIdx.y;
  int t = threadIdx.x, l = t & 63;
  int nt = __builtin_amdgcn_readfirstlane(t >> 6);
  int g = l >> 4;
  int x = (nt << 4) + (l & 15);

  f32x4 acc[4];
#pragma unroll
  for (int mt = 0; mt < 4; ++mt) acc[mt] = (f32x4)0.f;

  for (int rnd = 0; rnd < 16; ++rnd) {
    __syncthreads();
    for (int s = t; s < 8 * 4 * 130; s += 256) {
      int ci_l = s / 520, r2 = s - ci_l * 520;
      int r = r2 / 130, i = r2 - r * 130;
      int ci = (rnd << 3) + ci_l;
      int iy = 2 * y - 1 + r, ix = i - 1;
      unsigned v = 0u;
      if (iy >= 0 && iy < 128 && ix >= 0 && ix < 128)
        v = hp[((b * 128 + ci) * 128 + iy) * 128 + ix];
      hs[ci_l][r][i] = v;
    }
    __syncthreads();
#pragma unroll
    for (int ky = 0; ky < 4; ++ky) {
      int ks = (rnd << 2) + ky;
      FragU ah[4], al_[4];
#pragma unroll
      for (int mt = 0; mt < 4; ++mt) {
        long aoff = ((((long)ks * 4 + mt) * 64 + l) * 8);
        ah[mt].u = *reinterpret_cast<const u32x4*>(wCh + aoff);
        al_[mt].u = *reinterpret_cast<const u32x4*>(wCl + aoff);
      }
      const unsigned* pa = &hs[g * 2][ky][2 * x];
      const unsigned* pb = &hs[g * 2 + 1][ky][2 * x];
      unsigned a0 = pa[0], a1 = pa[1], a2 = pa[2], a3 = pa[3];
      unsigned b0 = pb[0], b1 = pb[1], b2_ = pb[2], b3 = pb[3];
      FragU bh, bl;
      bh.u[0] = __builtin_amdgcn_perm(a1, a0, 0x07060302u);
      bl.u[0] = __builtin_amdgcn_perm(a1, a0, 0x05040100u);
      bh.u[1] = __builtin_amdgcn_perm(a3, a2, 0x07060302u);
      bl.u[1] = __builtin_amdgcn_perm(a3, a2, 0x05040100u);
      bh.u[2] = __builtin_amdgcn_perm(b1, b0, 0x07060302u);
      bl.u[2] = __builtin_amdgcn_perm(b1, b0, 0x05040100u);
      bh.u[3] = __builtin_amdgcn_perm(b3, b2_, 0x07060302u);
      bl.u[3] = __builtin_amdgcn_perm(b3, b2_, 0x05040100u);
#pragma unroll
      for (int mt = 0; mt < 4; ++mt) {
        acc[mt] = __builtin_amdgcn_mfma_f32_16x16x32_bf16(
            ah[mt].h, bh.h, acc[mt], 0, 0, 0);
        acc[mt] = __builtin_amdgcn_mfma_f32_16x16x32_bf16(
            ah[mt].h, bl.h, acc[mt], 0, 0, 0);
        acc[mt] = __builtin_amdgcn_mfma_f32_16x16x32_bf16(
            al_[mt].h, bh.h, acc[mt], 0, 0, 0);
      }
    }
  }
#pragma unroll
  for (int mt = 0; mt < 4; ++mt) {
#pragma unroll
    for (int r = 0; r < 4; ++r) {
      int d = (mt << 4) + ((l >> 4) << 2) + r;
      float v = fmaxf(acc[mt][r] + b2[d], 0.f);
      z[((b * 64 + d) * 64 + y) * 64 + x] = v;
    }
  }
}

// ---------------- VQ: wave-split-K argmin + quantize + loss -----------------
// block = 256 thr = 4 waves, 64 points (lane l = point). Wave w scans codes
// [w*128,(w+1)*128) in 4 LDS tiles of 32 codes (broadcast reads). Merge via
// LDS ascending-wave strict '<' (preserves np.argmin first-min ties). Thread
// (w,l) quantizes dims [16w,16w+16) of point l from its resident zr regs.
__global__ __launch_bounds__(256) void vq_k(
    const float* __restrict__ z, const float* __restrict__ cb,
    const float* __restrict__ csq, unsigned int* __restrict__ q_pk,
    float* __restrict__ out, int n0) {
  __shared__ float cbs[4][2048];                   // 32 KB code tiles
  __shared__ float csqs[4][32];
  __shared__ float bdm[4][64];
  __shared__ int   bkm[4][64];
  __shared__ float redl[4];
  int t = threadIdx.x, l = t & 63;
  int w = __builtin_amdgcn_readfirstlane(t >> 6);
  int n = blockIdx.x * 64 + l;                     // chunk-local point
  int b = n >> 12, rem = n & 4095, y = rem >> 6, x = rem & 63;
  const float* zp = z + ((b * 64) * 64 + y) * 64 + x;
  float zr[64];
#pragma unroll
  for (int d = 0; d < 64; ++d) zr[d] = zp[d * 4096];  // coalesced across lanes

  float bestd = 1e30f;
  int bestk = 0;
  for (int r = 0; r < 4; ++r) {
    int k0 = w * 128 + r * 32;
    const float4* src = reinterpret_cast<const float4*>(cb + k0 * 64);
    float4* dst = reinterpret_cast<float4*>(&cbs[w][0]);
    __syncthreads();                               // tile r-1 fully consumed
#pragma unroll
    for (int i = 0; i < 8; ++i) dst[i * 64 + l] = src[i * 64 + l];
    if (l < 32) csqs[w][l] = csq[k0 + l];
    __syncthreads();                               // tile r visible
    for (int j = 0; j < 32; ++j) {
      const float* cp = &cbs[w][j * 64];
      float a0 = 0.f, a1 = 0.f, a2 = 0.f, a3 = 0.f;
#pragma unroll
      for (int d = 0; d < 16; ++d) {
        a0 = fmaf(cp[d], zr[d], a0);
        a1 = fmaf(cp[16 + d], zr[16 + d], a1);
        a2 = fmaf(cp[32 + d], zr[32 + d], a2);
        a3 = fmaf(cp[48 + d], zr[48 + d], a3);
      }
      float dist = csqs[w][j] - 2.f * ((a0 + a1) + (a2 + a3));
      if (dist < bestd) { bestd = dist; bestk = k0 + j; }  // first-min ties
    }
  }
  bdm[w][l] = bestd;
  bkm[w][l] = bestk;
  __syncthreads();
  float bd = bdm[0][l];
  int bk = bkm[0][l];
#pragma unroll
  for (int w2 = 1; w2 < 4; ++w2) {                 // ascending k, strict '<'
    float d2 = bdm[w2][l];
    int k2 = bkm[w2][l];
    if (d2 < bd) { bd = d2; bk = k2; }
  }
  if (w == 0) out[1 + n0 + n] = (float)bk;

  const float* cbest = cb + (bk << 6) + (w << 4);  // dims [16w,16w+16)
  unsigned int* qp = q_pk + ((b * 64 + (w << 4)) * 64 + y) * 64 + x;
  float ls = 0.f;
#pragma unroll
  for (int d = 0; d < 16; ++d) {
    float c = cbest[d];
    qp[d * 4096] = pack_hilo(c);
    float df = c - zr[(w << 4) + d];
    ls = fmaf(df, df, ls);
  }
#pragma unroll
  for (int m = 32; m; m >>= 1) ls += __shfl_xor(ls, m);
  if (l == 0) redl[w] = ls;
  __syncthreads();
  if (t == 0)
    atomicAdd(out, (redl[0] + redl[1] + redl[2] + redl[3]) * (1.25f / 8388608.f));
}

// ---------------- convT2 (64->128, 4x4, s2, p1) + relu: bf16x3 MFMA ---------
__global__ __launch_bounds__(256) void dconv2_k(
    const unsigned int* __restrict__ q_pk, const ushort_t* __restrict__ wAh,
    const ushort_t* __restrict__ wAl, const float* __restrict__ db2,
    float* __restrict__ g) {
  __shared__ unsigned int rows[64][2][68];         // 34.8 KB packed hi|lo
  int Y = blockIdx.x, b = blockIdx.y;
  int t = threadIdx.x, l = t & 63;
  int w = __builtin_amdgcn_readfirstlane(t >> 6);
  int pX = w & 1, coh = w >> 1;
  int yA = (Y + 1) >> 1, yB = yA - 1;
  int v = ((Y & 1) << 1) | pX;

  for (int s = t; s < 64 * 2 * 68; s += 256) {
    int ci = s / 136, r2 = s - ci * 136;
    int r = r2 / 68, i = r2 - r * 68;
    int yy = r ? yB : yA, ix = i - 1;
    unsigned val = 0u;
    if (i < 66 && yy >= 0 && yy < 64 && ix >= 0 && ix < 64)
      val = q_pk[((b * 64 + ci) * 64 + yy) * 64 + ix];
    rows[ci][r][i] = val;
  }
  __syncthreads();

  f32x4 acc[4][4];
#pragma unroll
  for (int mt = 0; mt < 4; ++mt)
#pragma unroll
    for (int nt = 0; nt < 4; ++nt) acc[mt][nt] = (f32x4)0.f;

  for (int s8 = 0; s8 < 8; ++s8) {
    FragU ah[4], al[4];
#pragma unroll
    for (int mt = 0; mt < 4; ++mt) {
      long off = ((((long)(v * 8 + s8) * 8 + (coh * 4 + mt)) * 64 + l) * 8);
      ah[mt].u = *reinterpret_cast<const u32x4*>(wAh + off);
      al[mt].u = *reinterpret_cast<const u32x4*>(wAl + off);
    }
#pragma unroll
    for (int nt = 0; nt < 4; ++nt) {
      int p = nt * 16 + (l & 15) + pX;
      int cc0 = (s8 << 3) + ((l >> 4) << 1);
      unsigned u0 = rows[cc0][0][p], u1 = rows[cc0][0][p + 1];
      unsigned u2 = rows[cc0][1][p], u3 = rows[cc0][1][p + 1];
      unsigned u4 = rows[cc0 + 1][0][p], u5 = rows[cc0 + 1][0][p + 1];
      unsigned u6 = rows[cc0 + 1][1][p], u7 = rows[cc0 + 1][1][p + 1];
      FragU bh, bl;
      bh.u[0] = (u0 >> 16) | (u1 & 0xFFFF0000u);
      bl.u[0] = (u0 & 0xFFFFu) | (u1 << 16);
      bh.u[1] = (u2 >> 16) | (u3 & 0xFFFF0000u);
      bl.u[1] = (u2 & 0xFFFFu) | (u3 << 16);
      bh.u[2] = (u4 >> 16) | (u5 & 0xFFFF0000u);
      bl.u[2] = (u4 & 0xFFFFu) | (u5 << 16);
      bh.u[3] = (u6 >> 16) | (u7 & 0xFFFF0000u);
      bl.u[3] = (u6 & 0xFFFFu) | (u7 << 16);
#pragma unroll
      for (int mt = 0; mt < 4; ++mt) {
        acc[mt][nt] = __builtin_amdgcn_mfma_f32_16x16x32_bf16(
            ah[mt].h, bh.h, acc[mt][nt], 0, 0, 0);
        acc[mt][nt] = __builtin_amdgcn_mfma_f32_16x16x32_bf16(
            ah[mt].h, bl.h, acc[mt][nt], 0, 0, 0);
        acc[mt][nt] = __builtin_amdgcn_mfma_f32_16x16x32_bf16(
            al[mt].h, bh.h, acc[mt][nt], 0, 0, 0);
      }
    }
  }

#pragma unroll
  for (int mt = 0; mt < 4; ++mt) {
#pragma unroll
    for (int r = 0; r < 4; ++r) {
      int co = ((coh * 4 + mt) << 4) + ((l >> 4) << 2) + r;
      float bias = db2[co];
#pragma unroll
      for (int nt = 0; nt < 4; ++nt) {
        int X = ((nt << 4) + (l & 15)) * 2 + pX;
        float val = fmaxf(acc[mt][nt][r] + bias, 0.f);
        g[((b * 128 + co) * 128 + Y) * 128 + X] = val;
      }
    }
  }
}

// ---------------- convT1 (128->1, 4x4, s2, p1) + sigmoid --------------------
#define DC1_STEP 2
__global__ __launch_bounds__(256) void dconv1_k(
    const float* __restrict__ g, const float* __restrict__ wd1,
    const float* __restrict__ db1, float* __restrict__ rec) {
  __shared__ float rows[DC1_STEP][6][132];
  int a = blockIdx.x, b = blockIdx.y;
  int t = threadIdx.x;
  int w = __builtin_amdgcn_readfirstlane(t >> 6);
  int l = t & 63;
  int xh = w >> 1, pX = w & 1;
  int L = xh * 64 + l;                       // X = 2L + pX
  int kxA = pX ? 0 : 1, kxB = kxA + 2;
  float acc[8];
#pragma unroll
  for (int i = 0; i < 8; ++i) acc[i] = 0.f;

  for (int c0 = 0; c0 < 128; c0 += DC1_STEP) {
    __syncthreads();
    for (int s = t; s < DC1_STEP * 792; s += 256) {
      int cc = s / 792, r2 = s - cc * 792;
      int r = r2 / 132, i = r2 - r * 132;
      int yy = 4 * a - 1 + r, ix = i - 1;
      float v = 0.f;
      if (i < 130 && yy >= 0 && yy < 128 && ix >= 0 && ix < 128)
        v = g[((b * 128 + c0 + cc) * 128 + yy) * 128 + ix];
      rows[cc][r][i] = v;
    }
    __syncthreads();
#pragma unroll
    for (int cc = 0; cc < DC1_STEP; ++cc) {
      const float* wp = wd1 + (c0 + cc) * 16;  // contiguous taps -> s_load
      float rhi[6], rlo[6];
#pragma unroll
      for (int r = 0; r < 6; ++r) {
        rhi[r] = rows[cc][r][L + pX + 1];
        rlo[r] = rows[cc][r][L + pX];
      }
#pragma unroll
      for (int j = 0; j < 8; ++j) {
        int kyA = (j + 1) & 1, kyB = kyA + 2;
        int rA = ((j + 1) >> 1) + 1;
        float v = acc[j];
        v = fmaf(wp[kyA * 4 + kxA], rhi[rA], v);
        v = fmaf(wp[kyA * 4 + kxB], rlo[rA], v);
        v = fmaf(wp[kyB * 4 + kxA], rhi[rA - 1], v);
        v = fmaf(wp[kyB * 4 + kxB], rlo[rA - 1], v);
        acc[j] = v;
      }
    }
  }
  float bb = db1[0];
#pragma unroll
  for (int j = 0; j < 8; ++j) {
    float v = acc[j] + bb;
    v = 1.f / (1.f + __expf(-v));
    rec[((b * 256 + 8 * a + j) * 256) + 2 * L + pX] = v;
  }
}

// ---------------------------------------------------------------------------
extern "C" void kernel_launch(void* const* d_in, const int* in_sizes, int n_in,
                              void* d_out, int out_size, void* d_ws, size_t ws_size,
                              hipStream_t stream) {
  const float* x      = (const float*)d_in[0];
  const float* enc_w1 = (const float*)d_in[1];
  const float* enc_b1 = (const float*)d_in[2];
  const float* enc_w2 = (const float*)d_in[3];
  const float* enc_b2 = (const float*)d_in[4];
  const float* cb     = (const float*)d_in[5];
  const float* dec_w2 = (const float*)d_in[6];
  const float* dec_b2 = (const float*)d_in[7];
  const float* dec_w1 = (const float*)d_in[8];
  const float* dec_b1 = (const float*)d_in[9];

  float* out = (float*)d_out;
  float* ws  = (float*)d_ws;
  ushort_t* wCh = (ushort_t*)ws;                    // 131072 ushort = 65536 f
  ushort_t* wCl = (ushort_t*)(ws + 65536);
  ushort_t* wAh = (ushort_t*)(ws + 131072);
  ushort_t* wAl = (ushort_t*)(ws + 196608);
  float* csq = ws + 262144;                         // 512
  float* dyn = ws + 262656;                         // chunk buffers

  // Per-image: h_pk = 2,097,152 u32 (g f32 aliases), z/q_pk = 262,144.
  const size_t PER_IMG = 2097152 + 262144;                   // 2,359,296 elems
  size_t avail = (ws_size / 4 > 262656 + 64) ? ws_size / 4 - 262656 - 64 : 0;
  int CB = 32;
  while (CB > 1 && (size_t)CB * PER_IMG > avail) CB >>= 1;

  zero_loss_k<<<dim3(1), 64, 0, stream>>>(out);
  repackA2_k<<<dim3(512), 256, 0, stream>>>(enc_w2, wCh, wCl);
  repackA_k<<<dim3(512), 256, 0, stream>>>(dec_w2, wAh, wAl);
  csq_k<<<dim3(2), 256, 0, stream>>>(cb, csq);

  for (int b0 = 0; b0 < 32; b0 += CB) {
    unsigned* hp = (unsigned*)dyn;                    // CB*2097152 (g aliases)
    float* zq = dyn + (size_t)CB * 2097152;           // CB*262144 (q_pk aliases)
    conv1_k<<<dim3(128, CB), 128, 0, stream>>>(
        x + (size_t)b0 * 65536, enc_w1, enc_b1, hp);
    conv2_k<<<dim3(64, CB), 256, 0, stream>>>(hp, wCh, wCl, enc_b2, zq);
    vq_k<<<dim3(CB * 64), 256, 0, stream>>>(
        zq, cb, csq, (unsigned int*)zq, out, b0 * 4096);
    dconv2_k<<<dim3(128, CB), 256, 0, stream>>>(
        (const unsigned int*)zq, wAh, wAl, dec_b2, (float*)dyn /*g*/);
    dconv1_k<<<dim3(32, CB), 256, 0, stream>>>(
        (float*)dyn /*g*/, dec_w1, dec_b1, out + REC_OFF + (size_t)b0 * 65536);
  }
}

// Round 7
// 965.097 us; speedup vs baseline: 2.1327x; 1.2417x over previous
//
#include <hip/hip_runtime.h>
#include <math.h>

// ---------------------------------------------------------------------------
// VQ-VAE forward, bf16x3-MFMA for conv2 & convT2, batch-chunked.
//  x (32,1,256,256) -> h_pk (32,128,128,128 u32 hi|lo) -> z (32,64,64,64 f32)
//  VQ: N=131072 x D=64 vs K=512   (q packed bf16 hi/lo, aliases z in-place)
//  q -> g (f32, aliases h_pk) -> x_recon (32,1,256,256)
// d_out: [0]=vq_loss, [1..131072]=idx (as float), [131073..]=x_recon
// ws: wCh 64Kf | wCl 64Kf | wAh 64Kf | wAl 64Kf | csq 512 | chunk bufs
// Fragment conventions (HW-verified, absmax 0.0 in rounds 4-6):
//   A/B: lane l holds k_local = 8*(l>>4)+j, m/n = l&15
//   C/D: row = (l>>4)*4 + reg, col = l&15
// Round 7: dconv1_k rebuilt — direct global loads (no LDS, no barriers),
// 4 output rows/block (grid 64xCB -> 2 waves/SIMD), ci unrolled x2.
// ---------------------------------------------------------------------------

#define REC_OFF 131073

typedef unsigned short ushort_t;
typedef __attribute__((ext_vector_type(8))) short bf16x8;
typedef __attribute__((ext_vector_type(4))) float f32x4;
typedef __attribute__((ext_vector_type(4))) unsigned int u32x4;
union FragU { u32x4 u; bf16x8 h; };

__device__ __forceinline__ unsigned pack_hilo(float v) {
  unsigned u = __float_as_uint(v);
  unsigned htop = u & 0xFFFF0000u;
  float rf = v - __uint_as_float(htop);
  return htop | (__float_as_uint(rf) >> 16);
}

__global__ __launch_bounds__(64) void zero_loss_k(float* __restrict__ out) {
  if (threadIdx.x == 0) out[0] = 0.f;
}

// ---- conv2 A-table: [ks=ci0*4+ky][mt][lane][j] bf16 hi/lo -----------------
__global__ __launch_bounds__(256) void repackA2_k(
    const float* __restrict__ ew2,
    ushort_t* __restrict__ hi, ushort_t* __restrict__ lo) {
  int idx = blockIdx.x * 256 + threadIdx.x;        // 131072 total
  int j = idx & 7, l = (idx >> 3) & 63, mt = (idx >> 9) & 3, ks = idx >> 11;
  int ci = ((ks >> 2) << 3) + ((l >> 4) << 1) + (j >> 2);
  int ky = ks & 3, kx = j & 3, d = (mt << 4) + (l & 15);
  float val = ew2[((d << 7) + ci) * 16 + (ky << 2) + kx];
  unsigned u = __float_as_uint(val);
  float rf = val - __uint_as_float(u & 0xFFFF0000u);
  hi[idx] = (ushort_t)(u >> 16);
  lo[idx] = (ushort_t)(__float_as_uint(rf) >> 16);
}

// ---- dconv2 A-table (proven) ----------------------------------------------
__global__ __launch_bounds__(256) void repackA_k(
    const float* __restrict__ dw2,   // dec_w2 (ci=64, co=128, ky, kx)
    ushort_t* __restrict__ hi, ushort_t* __restrict__ lo) {
  int idx = blockIdx.x * 256 + threadIdx.x;        // 131072 total
  int j = idx & 7, l = (idx >> 3) & 63, mt = (idx >> 9) & 7;
  int s = (idx >> 12) & 7, v = idx >> 15;
  int co = (mt << 4) + (l & 15);
  int ci = (s << 3) + ((l >> 4) << 1) + (j >> 2);
  int tap = j & 3;
  int Yp = v >> 1, pX = v & 1;
  int kyA = 1 - Yp, kyB = kyA + 2;
  int kxA = pX ? 0 : 1, kxB = kxA + 2;
  int ky = (tap & 2) ? kyB : kyA;
  int kx = (tap & 1) ? kxA : kxB;
  float val = dw2[(((ci << 7) + co) << 4) + (ky << 2) + kx];
  unsigned u = __float_as_uint(val);
  float rf = val - __uint_as_float(u & 0xFFFF0000u);
  hi[idx] = (ushort_t)(u >> 16);
  lo[idx] = (ushort_t)(__float_as_uint(rf) >> 16);
}

__global__ __launch_bounds__(256) void csq_k(
    const float* __restrict__ cb, float* __restrict__ csq) {
  int k = blockIdx.x * 256 + threadIdx.x;          // 512 total
  const float* cp = cb + (k << 6);
  float s = 0.f;
#pragma unroll
  for (int d = 0; d < 64; ++d) s = fmaf(cp[d], cp[d], s);
  csq[k] = s;
}

// ---------------- conv1 (1->128, 4x4, s2, p1) + relu -> packed u32 ----------
__global__ __launch_bounds__(128) void conv1_k(
    const float* __restrict__ x, const float* __restrict__ w1,
    const float* __restrict__ b1, unsigned* __restrict__ hp) {
  int oy = blockIdx.x, b = blockIdx.y, ox = threadIdx.x;
  float xv[16];
#pragma unroll
  for (int ky = 0; ky < 4; ++ky) {
    int iy = 2 * oy - 1 + ky;
#pragma unroll
    for (int kx = 0; kx < 4; ++kx) {
      int ix = 2 * ox - 1 + kx;
      float v = 0.f;
      if (iy >= 0 && iy < 256 && ix >= 0 && ix < 256)
        v = x[(b * 256 + iy) * 256 + ix];
      xv[ky * 4 + kx] = v;
    }
  }
  for (int c = 0; c < 128; ++c) {
    const float* wp = w1 + c * 16;                 // wave-uniform -> s_load
    float acc = b1[c];
#pragma unroll
    for (int k = 0; k < 16; ++k) acc = fmaf(xv[k], wp[k], acc);
    hp[((b * 128 + c) * 128 + oy) * 128 + ox] = pack_hilo(fmaxf(acc, 0.f));
  }
}

// ---------------- conv2 (128->64, 4x4, s2, p1) + relu: bf16x3 MFMA ----------
__global__ __launch_bounds__(256) void conv2_k(
    const unsigned* __restrict__ hp, const ushort_t* __restrict__ wCh,
    const ushort_t* __restrict__ wCl, const float* __restrict__ b2,
    float* __restrict__ z) {
  __shared__ unsigned hs[8][4][134];               // 17.2 KB
  int y = blockIdx.x, b = blockIdx.y;
  int t = threadIdx.x, l = t & 63;
  int nt = __builtin_amdgcn_readfirstlane(t >> 6);
  int g = l >> 4;
  int x = (nt << 4) + (l & 15);

  f32x4 acc[4];
#pragma unroll
  for (int mt = 0; mt < 4; ++mt) acc[mt] = (f32x4)0.f;

  for (int rnd = 0; rnd < 16; ++rnd) {
    __syncthreads();
    for (int s = t; s < 8 * 4 * 130; s += 256) {
      int ci_l = s / 520, r2 = s - ci_l * 520;
      int r = r2 / 130, i = r2 - r * 130;
      int ci = (rnd << 3) + ci_l;
      int iy = 2 * y - 1 + r, ix = i - 1;
      unsigned v = 0u;
      if (iy >= 0 && iy < 128 && ix >= 0 && ix < 128)
        v = hp[((b * 128 + ci) * 128 + iy) * 128 + ix];
      hs[ci_l][r][i] = v;
    }
    __syncthreads();
#pragma unroll
    for (int ky = 0; ky < 4; ++ky) {
      int ks = (rnd << 2) + ky;
      FragU ah[4], al_[4];
#pragma unroll
      for (int mt = 0; mt < 4; ++mt) {
        long aoff = ((((long)ks * 4 + mt) * 64 + l) * 8);
        ah[mt].u = *reinterpret_cast<const u32x4*>(wCh + aoff);
        al_[mt].u = *reinterpret_cast<const u32x4*>(wCl + aoff);
      }
      const unsigned* pa = &hs[g * 2][ky][2 * x];
      const unsigned* pb = &hs[g * 2 + 1][ky][2 * x];
      unsigned a0 = pa[0], a1 = pa[1], a2 = pa[2], a3 = pa[3];
      unsigned b0 = pb[0], b1 = pb[1], b2_ = pb[2], b3 = pb[3];
      FragU bh, bl;
      bh.u[0] = __builtin_amdgcn_perm(a1, a0, 0x07060302u);
      bl.u[0] = __builtin_amdgcn_perm(a1, a0, 0x05040100u);
      bh.u[1] = __builtin_amdgcn_perm(a3, a2, 0x07060302u);
      bl.u[1] = __builtin_amdgcn_perm(a3, a2, 0x05040100u);
      bh.u[2] = __builtin_amdgcn_perm(b1, b0, 0x07060302u);
      bl.u[2] = __builtin_amdgcn_perm(b1, b0, 0x05040100u);
      bh.u[3] = __builtin_amdgcn_perm(b3, b2_, 0x07060302u);
      bl.u[3] = __builtin_amdgcn_perm(b3, b2_, 0x05040100u);
#pragma unroll
      for (int mt = 0; mt < 4; ++mt) {
        acc[mt] = __builtin_amdgcn_mfma_f32_16x16x32_bf16(
            ah[mt].h, bh.h, acc[mt], 0, 0, 0);
        acc[mt] = __builtin_amdgcn_mfma_f32_16x16x32_bf16(
            ah[mt].h, bl.h, acc[mt], 0, 0, 0);
        acc[mt] = __builtin_amdgcn_mfma_f32_16x16x32_bf16(
            al_[mt].h, bh.h, acc[mt], 0, 0, 0);
      }
    }
  }
#pragma unroll
  for (int mt = 0; mt < 4; ++mt) {
#pragma unroll
    for (int r = 0; r < 4; ++r) {
      int d = (mt << 4) + ((l >> 4) << 2) + r;
      float v = fmaxf(acc[mt][r] + b2[d], 0.f);
      z[((b * 64 + d) * 64 + y) * 64 + x] = v;
    }
  }
}

// ---------------- VQ: wave-split-K argmin + quantize + loss -----------------
__global__ __launch_bounds__(256) void vq_k(
    const float* __restrict__ z, const float* __restrict__ cb,
    const float* __restrict__ csq, unsigned int* __restrict__ q_pk,
    float* __restrict__ out, int n0) {
  __shared__ float cbs[4][2048];                   // 32 KB code tiles
  __shared__ float csqs[4][32];
  __shared__ float bdm[4][64];
  __shared__ int   bkm[4][64];
  __shared__ float redl[4];
  int t = threadIdx.x, l = t & 63;
  int w = __builtin_amdgcn_readfirstlane(t >> 6);
  int n = blockIdx.x * 64 + l;                     // chunk-local point
  int b = n >> 12, rem = n & 4095, y = rem >> 6, x = rem & 63;
  const float* zp = z + ((b * 64) * 64 + y) * 64 + x;
  float zr[64];
#pragma unroll
  for (int d = 0; d < 64; ++d) zr[d] = zp[d * 4096];  // coalesced across lanes

  float bestd = 1e30f;
  int bestk = 0;
  for (int r = 0; r < 4; ++r) {
    int k0 = w * 128 + r * 32;
    const float4* src = reinterpret_cast<const float4*>(cb + k0 * 64);
    float4* dst = reinterpret_cast<float4*>(&cbs[w][0]);
    __syncthreads();                               // tile r-1 fully consumed
#pragma unroll
    for (int i = 0; i < 8; ++i) dst[i * 64 + l] = src[i * 64 + l];
    if (l < 32) csqs[w][l] = csq[k0 + l];
    __syncthreads();                               // tile r visible
    for (int j = 0; j < 32; ++j) {
      const float* cp = &cbs[w][j * 64];
      float a0 = 0.f, a1 = 0.f, a2 = 0.f, a3 = 0.f;
#pragma unroll
      for (int d = 0; d < 16; ++d) {
        a0 = fmaf(cp[d], zr[d], a0);
        a1 = fmaf(cp[16 + d], zr[16 + d], a1);
        a2 = fmaf(cp[32 + d], zr[32 + d], a2);
        a3 = fmaf(cp[48 + d], zr[48 + d], a3);
      }
      float dist = csqs[w][j] - 2.f * ((a0 + a1) + (a2 + a3));
      if (dist < bestd) { bestd = dist; bestk = k0 + j; }  // first-min ties
    }
  }
  bdm[w][l] = bestd;
  bkm[w][l] = bestk;
  __syncthreads();
  float bd = bdm[0][l];
  int bk = bkm[0][l];
#pragma unroll
  for (int w2 = 1; w2 < 4; ++w2) {                 // ascending k, strict '<'
    float d2 = bdm[w2][l];
    int k2 = bkm[w2][l];
    if (d2 < bd) { bd = d2; bk = k2; }
  }
  if (w == 0) out[1 + n0 + n] = (float)bk;

  const float* cbest = cb + (bk << 6) + (w << 4);  // dims [16w,16w+16)
  unsigned int* qp = q_pk + ((b * 64 + (w << 4)) * 64 + y) * 64 + x;
  float ls = 0.f;
#pragma unroll
  for (int d = 0; d < 16; ++d) {
    float c = cbest[d];
    qp[d * 4096] = pack_hilo(c);
    float df = c - zr[(w << 4) + d];
    ls = fmaf(df, df, ls);
  }
#pragma unroll
  for (int m = 32; m; m >>= 1) ls += __shfl_xor(ls, m);
  if (l == 0) redl[w] = ls;
  __syncthreads();
  if (t == 0)
    atomicAdd(out, (redl[0] + redl[1] + redl[2] + redl[3]) * (1.25f / 8388608.f));
}

// ---------------- convT2 (64->128, 4x4, s2, p1) + relu: bf16x3 MFMA ---------
__global__ __launch_bounds__(256) void dconv2_k(
    const unsigned int* __restrict__ q_pk, const ushort_t* __restrict__ wAh,
    const ushort_t* __restrict__ wAl, const float* __restrict__ db2,
    float* __restrict__ g) {
  __shared__ unsigned int rows[64][2][68];         // 34.8 KB packed hi|lo
  int Y = blockIdx.x, b = blockIdx.y;
  int t = threadIdx.x, l = t & 63;
  int w = __builtin_amdgcn_readfirstlane(t >> 6);
  int pX = w & 1, coh = w >> 1;
  int yA = (Y + 1) >> 1, yB = yA - 1;
  int v = ((Y & 1) << 1) | pX;

  for (int s = t; s < 64 * 2 * 68; s += 256) {
    int ci = s / 136, r2 = s - ci * 136;
    int r = r2 / 68, i = r2 - r * 68;
    int yy = r ? yB : yA, ix = i - 1;
    unsigned val = 0u;
    if (i < 66 && yy >= 0 && yy < 64 && ix >= 0 && ix < 64)
      val = q_pk[((b * 64 + ci) * 64 + yy) * 64 + ix];
    rows[ci][r][i] = val;
  }
  __syncthreads();

  f32x4 acc[4][4];
#pragma unroll
  for (int mt = 0; mt < 4; ++mt)
#pragma unroll
    for (int nt = 0; nt < 4; ++nt) acc[mt][nt] = (f32x4)0.f;

  for (int s8 = 0; s8 < 8; ++s8) {
    FragU ah[4], al[4];
#pragma unroll
    for (int mt = 0; mt < 4; ++mt) {
      long off = ((((long)(v * 8 + s8) * 8 + (coh * 4 + mt)) * 64 + l) * 8);
      ah[mt].u = *reinterpret_cast<const u32x4*>(wAh + off);
      al[mt].u = *reinterpret_cast<const u32x4*>(wAl + off);
    }
#pragma unroll
    for (int nt = 0; nt < 4; ++nt) {
      int p = nt * 16 + (l & 15) + pX;
      int cc0 = (s8 << 3) + ((l >> 4) << 1);
      unsigned u0 = rows[cc0][0][p], u1 = rows[cc0][0][p + 1];
      unsigned u2 = rows[cc0][1][p], u3 = rows[cc0][1][p + 1];
      unsigned u4 = rows[cc0 + 1][0][p], u5 = rows[cc0 + 1][0][p + 1];
      unsigned u6 = rows[cc0 + 1][1][p], u7 = rows[cc0 + 1][1][p + 1];
      FragU bh, bl;
      bh.u[0] = (u0 >> 16) | (u1 & 0xFFFF0000u);
      bl.u[0] = (u0 & 0xFFFFu) | (u1 << 16);
      bh.u[1] = (u2 >> 16) | (u3 & 0xFFFF0000u);
      bl.u[1] = (u2 & 0xFFFFu) | (u3 << 16);
      bh.u[2] = (u4 >> 16) | (u5 & 0xFFFF0000u);
      bl.u[2] = (u4 & 0xFFFFu) | (u5 << 16);
      bh.u[3] = (u6 >> 16) | (u7 & 0xFFFF0000u);
      bl.u[3] = (u6 & 0xFFFFu) | (u7 << 16);
#pragma unroll
      for (int mt = 0; mt < 4; ++mt) {
        acc[mt][nt] = __builtin_amdgcn_mfma_f32_16x16x32_bf16(
            ah[mt].h, bh.h, acc[mt][nt], 0, 0, 0);
        acc[mt][nt] = __builtin_amdgcn_mfma_f32_16x16x32_bf16(
            ah[mt].h, bl.h, acc[mt][nt], 0, 0, 0);
        acc[mt][nt] = __builtin_amdgcn_mfma_f32_16x16x32_bf16(
            al[mt].h, bh.h, acc[mt][nt], 0, 0, 0);
      }
    }
  }

#pragma unroll
  for (int mt = 0; mt < 4; ++mt) {
#pragma unroll
    for (int r = 0; r < 4; ++r) {
      int co = ((coh * 4 + mt) << 4) + ((l >> 4) << 2) + r;
      float bias = db2[co];
#pragma unroll
      for (int nt = 0; nt < 4; ++nt) {
        int X = ((nt << 4) + (l & 15)) * 2 + pX;
        float val = fmaxf(acc[mt][nt][r] + bias, 0.f);
        g[((b * 128 + co) * 128 + Y) * 128 + X] = val;
      }
    }
  }
}

// ---------------- convT1 (128->1, 4x4, s2, p1) + sigmoid --------------------
// Direct-load, no LDS, no barriers. block=(a2,b): output rows Y=4*a2..4*a2+3,
// 256 cols. 256 thr = 4 waves (xh=w>>1, pX=w&1); thread: col X=2L+pX, 4 rows.
// Input rows yy0..yy0+3 (yy0=2*a2-1); per ci loads 8 values (4 rows x hi/lo).
__global__ __launch_bounds__(256) void dconv1_k(
    const float* __restrict__ g, const float* __restrict__ wd1,
    const float* __restrict__ db1, float* __restrict__ rec) {
  int a2 = blockIdx.x, b = blockIdx.y;
  int t = threadIdx.x;
  int w = __builtin_amdgcn_readfirstlane(t >> 6);
  int l = t & 63;
  int xh = w >> 1, pX = w & 1;
  int L = xh * 64 + l;                       // X = 2L + pX
  int kxA = pX ? 0 : 1, kxB = kxA + 2;
  int ixH = L + pX, ixL = L + pX - 1;
  bool okH = ixH < 128, okL = ixL >= 0;
  int yy0 = 2 * a2 - 1;
  bool vy[4];
#pragma unroll
  for (int r = 0; r < 4; ++r) vy[r] = (yy0 + r) >= 0 && (yy0 + r) < 128;

  const float* gb = g + ((long)b * 128) * 16384 + (long)yy0 * 128;
  float acc[4] = {0.f, 0.f, 0.f, 0.f};

  for (int ci = 0; ci < 128; ci += 2) {
    const float* p0 = gb + (long)ci * 16384;
    const float* p1 = p0 + 16384;
    float hi0[4], lo0[4], hi1[4], lo1[4];
#pragma unroll
    for (int r = 0; r < 4; ++r) {
      const float* q0 = p0 + r * 128;
      const float* q1 = p1 + r * 128;
      hi0[r] = (vy[r] && okH) ? q0[ixH] : 0.f;
      lo0[r] = (vy[r] && okL) ? q0[ixL] : 0.f;
      hi1[r] = (vy[r] && okH) ? q1[ixH] : 0.f;
      lo1[r] = (vy[r] && okL) ? q1[ixL] : 0.f;
    }
    const float* wp0 = wd1 + ci * 16;        // wave-uniform -> s_load
    const float* wp1 = wp0 + 16;
#pragma unroll
    for (int j = 0; j < 4; ++j) {
      int kyA = (j + 1) & 1, kyB = kyA + 2;
      int rA = ((j + 1) >> 1) + 1;           // in [1,3]
      float v = acc[j];
      v = fmaf(wp0[kyA * 4 + kxA], hi0[rA], v);
      v = fmaf(wp0[kyA * 4 + kxB], lo0[rA], v);
      v = fmaf(wp0[kyB * 4 + kxA], hi0[rA - 1], v);
      v = fmaf(wp0[kyB * 4 + kxB], lo0[rA - 1], v);
      v = fmaf(wp1[kyA * 4 + kxA], hi1[rA], v);
      v = fmaf(wp1[kyA * 4 + kxB], lo1[rA], v);
      v = fmaf(wp1[kyB * 4 + kxA], hi1[rA - 1], v);
      v = fmaf(wp1[kyB * 4 + kxB], lo1[rA - 1], v);
      acc[j] = v;
    }
  }
  float bb = db1[0];
#pragma unroll
  for (int j = 0; j < 4; ++j) {
    float v = acc[j] + bb;
    v = 1.f / (1.f + __expf(-v));
    rec[((b * 256 + 4 * a2 + j) * 256) + 2 * L + pX] = v;
  }
}

// ---------------------------------------------------------------------------
extern "C" void kernel_launch(void* const* d_in, const int* in_sizes, int n_in,
                              void* d_out, int out_size, void* d_ws, size_t ws_size,
                              hipStream_t stream) {
  const float* x      = (const float*)d_in[0];
  const float* enc_w1 = (const float*)d_in[1];
  const float* enc_b1 = (const float*)d_in[2];
  const float* enc_w2 = (const float*)d_in[3];
  const float* enc_b2 = (const float*)d_in[4];
  const float* cb     = (const float*)d_in[5];
  const float* dec_w2 = (const float*)d_in[6];
  const float* dec_b2 = (const float*)d_in[7];
  const float* dec_w1 = (const float*)d_in[8];
  const float* dec_b1 = (const float*)d_in[9];

  float* out = (float*)d_out;
  float* ws  = (float*)d_ws;
  ushort_t* wCh = (ushort_t*)ws;                    // 131072 ushort = 65536 f
  ushort_t* wCl = (ushort_t*)(ws + 65536);
  ushort_t* wAh = (ushort_t*)(ws + 131072);
  ushort_t* wAl = (ushort_t*)(ws + 196608);
  float* csq = ws + 262144;                         // 512
  float* dyn = ws + 262656;                         // chunk buffers

  // Per-image: h_pk = 2,097,152 u32 (g f32 aliases), z/q_pk = 262,144.
  const size_t PER_IMG = 2097152 + 262144;                   // 2,359,296 elems
  size_t avail = (ws_size / 4 > 262656 + 64) ? ws_size / 4 - 262656 - 64 : 0;
  int CB = 32;
  while (CB > 1 && (size_t)CB * PER_IMG > avail) CB >>= 1;

  zero_loss_k<<<dim3(1), 64, 0, stream>>>(out);
  repackA2_k<<<dim3(512), 256, 0, stream>>>(enc_w2, wCh, wCl);
  repackA_k<<<dim3(512), 256, 0, stream>>>(dec_w2, wAh, wAl);
  csq_k<<<dim3(2), 256, 0, stream>>>(cb, csq);

  for (int b0 = 0; b0 < 32; b0 += CB) {
    unsigned* hp = (unsigned*)dyn;                    // CB*2097152 (g aliases)
    float* zq = dyn + (size_t)CB * 2097152;           // CB*262144 (q_pk aliases)
    conv1_k<<<dim3(128, CB), 128, 0, stream>>>(
        x + (size_t)b0 * 65536, enc_w1, enc_b1, hp);
    conv2_k<<<dim3(64, CB), 256, 0, stream>>>(hp, wCh, wCl, enc_b2, zq);
    vq_k<<<dim3(CB * 64), 256, 0, stream>>>(
        zq, cb, csq, (unsigned int*)zq, out, b0 * 4096);
    dconv2_k<<<dim3(128, CB), 256, 0, stream>>>(
        (const unsigned int*)zq, wAh, wAl, dec_b2, (float*)dyn /*g*/);
    dconv1_k<<<dim3(64, CB), 256, 0, stream>>>(
        (float*)dyn /*g*/, dec_w1, dec_b1, out + REC_OFF + (size_t)b0 * 65536);
  }
}

// Round 8
// 788.901 us; speedup vs baseline: 2.6090x; 1.2233x over previous
//
#include <hip/hip_runtime.h>
#include <math.h>

// ---------------------------------------------------------------------------
// VQ-VAE forward, bf16x3-MFMA for conv2 & convT2, batch-chunked.
//  x (32,1,256,256) -> h_pk (32,128,128,128 u32 hi|lo) -> z (32,64,64,64 f32)
//  VQ: N=131072 x D=64 vs K=512   (q packed bf16 hi/lo, aliases z in-place)
//  q -> g (f32, aliases h_pk) -> x_recon (32,1,256,256)
// d_out: [0]=vq_loss, [1..131072]=idx (as float), [131073..]=x_recon
// ws: wCh 64Kf | wCl 64Kf | wAh 64Kf | wAl 64Kf | csq 512 | chunk bufs
// Fragment conventions (HW-verified, absmax 0.0 in rounds 4-7):
//   A/B: lane l holds k_local = 8*(l>>4)+j, m/n = l&15
//   C/D: row = (l>>4)*4 + reg, col = l&15
// Round 8: conv2_k restructured — waves = mt (M-split) with nt-loop A-reuse
// (A traffic 2MB -> 512KB/block), pow2 vectorized staging + reg double-buffer,
// LDS row 133 (bank-conflict-free B reads), halo pre-zeroed.
// ---------------------------------------------------------------------------

#define REC_OFF 131073

typedef unsigned short ushort_t;
typedef __attribute__((ext_vector_type(8))) short bf16x8;
typedef __attribute__((ext_vector_type(4))) float f32x4;
typedef __attribute__((ext_vector_type(4))) unsigned int u32x4;
union FragU { u32x4 u; bf16x8 h; };

__device__ __forceinline__ unsigned pack_hilo(float v) {
  unsigned u = __float_as_uint(v);
  unsigned htop = u & 0xFFFF0000u;
  float rf = v - __uint_as_float(htop);
  return htop | (__float_as_uint(rf) >> 16);
}

__global__ __launch_bounds__(64) void zero_loss_k(float* __restrict__ out) {
  if (threadIdx.x == 0) out[0] = 0.f;
}

// ---- conv2 A-table: [ks=ci0*4+ky][mt][lane][j] bf16 hi/lo -----------------
__global__ __launch_bounds__(256) void repackA2_k(
    const float* __restrict__ ew2,
    ushort_t* __restrict__ hi, ushort_t* __restrict__ lo) {
  int idx = blockIdx.x * 256 + threadIdx.x;        // 131072 total
  int j = idx & 7, l = (idx >> 3) & 63, mt = (idx >> 9) & 3, ks = idx >> 11;
  int ci = ((ks >> 2) << 3) + ((l >> 4) << 1) + (j >> 2);
  int ky = ks & 3, kx = j & 3, d = (mt << 4) + (l & 15);
  float val = ew2[((d << 7) + ci) * 16 + (ky << 2) + kx];
  unsigned u = __float_as_uint(val);
  float rf = val - __uint_as_float(u & 0xFFFF0000u);
  hi[idx] = (ushort_t)(u >> 16);
  lo[idx] = (ushort_t)(__float_as_uint(rf) >> 16);
}

// ---- dconv2 A-table (proven) ----------------------------------------------
__global__ __launch_bounds__(256) void repackA_k(
    const float* __restrict__ dw2,   // dec_w2 (ci=64, co=128, ky, kx)
    ushort_t* __restrict__ hi, ushort_t* __restrict__ lo) {
  int idx = blockIdx.x * 256 + threadIdx.x;        // 131072 total
  int j = idx & 7, l = (idx >> 3) & 63, mt = (idx >> 9) & 7;
  int s = (idx >> 12) & 7, v = idx >> 15;
  int co = (mt << 4) + (l & 15);
  int ci = (s << 3) + ((l >> 4) << 1) + (j >> 2);
  int tap = j & 3;
  int Yp = v >> 1, pX = v & 1;
  int kyA = 1 - Yp, kyB = kyA + 2;
  int kxA = pX ? 0 : 1, kxB = kxA + 2;
  int ky = (tap & 2) ? kyB : kyA;
  int kx = (tap & 1) ? kxA : kxB;
  float val = dw2[(((ci << 7) + co) << 4) + (ky << 2) + kx];
  unsigned u = __float_as_uint(val);
  float rf = val - __uint_as_float(u & 0xFFFF0000u);
  hi[idx] = (ushort_t)(u >> 16);
  lo[idx] = (ushort_t)(__float_as_uint(rf) >> 16);
}

__global__ __launch_bounds__(256) void csq_k(
    const float* __restrict__ cb, float* __restrict__ csq) {
  int k = blockIdx.x * 256 + threadIdx.x;          // 512 total
  const float* cp = cb + (k << 6);
  float s = 0.f;
#pragma unroll
  for (int d = 0; d < 64; ++d) s = fmaf(cp[d], cp[d], s);
  csq[k] = s;
}

// ---------------- conv1 (1->128, 4x4, s2, p1) + relu -> packed u32 ----------
__global__ __launch_bounds__(128) void conv1_k(
    const float* __restrict__ x, const float* __restrict__ w1,
    const float* __restrict__ b1, unsigned* __restrict__ hp) {
  int oy = blockIdx.x, b = blockIdx.y, ox = threadIdx.x;
  float xv[16];
#pragma unroll
  for (int ky = 0; ky < 4; ++ky) {
    int iy = 2 * oy - 1 + ky;
#pragma unroll
    for (int kx = 0; kx < 4; ++kx) {
      int ix = 2 * ox - 1 + kx;
      float v = 0.f;
      if (iy >= 0 && iy < 256 && ix >= 0 && ix < 256)
        v = x[(b * 256 + iy) * 256 + ix];
      xv[ky * 4 + kx] = v;
    }
  }
  for (int c = 0; c < 128; ++c) {
    const float* wp = w1 + c * 16;                 // wave-uniform -> s_load
    float acc = b1[c];
#pragma unroll
    for (int k = 0; k < 16; ++k) acc = fmaf(xv[k], wp[k], acc);
    hp[((b * 128 + c) * 128 + oy) * 128 + ox] = pack_hilo(fmaxf(acc, 0.f));
  }
}

// ---------------- conv2 (128->64, 4x4, s2, p1) + relu: bf16x3 MFMA ----------
// block=(y,b), 4 waves = mt (M-split). GEMM M=64(d) N=64(x) K=2048.
// Wave loads its own A slice (2xb128/kstep) and reuses over nt=0..3.
// Staging: thread (ci_l=t>>5, l32=t&31) loads 4 rows x u32x4, pow2 addrs,
// reg double-buffered. LDS row 133 words: slot j holds ix=j-1; j=0,129
// are always-zero x-halo (pre-zeroed once).
#define C2RL 133
__global__ __launch_bounds__(256) void conv2_k(
    const unsigned* __restrict__ hp, const ushort_t* __restrict__ wCh,
    const ushort_t* __restrict__ wCl, const float* __restrict__ b2,
    float* __restrict__ z) {
  __shared__ unsigned hs[8][4][C2RL];              // 17 KB
  int y = blockIdx.x, b = blockIdx.y;
  int t = threadIdx.x, l = t & 63;
  int w = __builtin_amdgcn_readfirstlane(t >> 6);  // = mt
  int g = l >> 4;

  if (t < 64) hs[t >> 3][(t >> 1) & 3][(t & 1) ? 129 : 0] = 0u;

  int ci_l = t >> 5, l32 = t & 31;
  int iy[4];
  bool rowok[4];
#pragma unroll
  for (int r = 0; r < 4; ++r) {
    iy[r] = 2 * y - 1 + r;
    rowok[r] = iy[r] >= 0 && iy[r] < 128;
  }
  const unsigned* hbase = hp + (((long)b * 128) << 14);

  u32x4 pre[4];
#pragma unroll
  for (int r = 0; r < 4; ++r)
    pre[r] = rowok[r]
        ? *reinterpret_cast<const u32x4*>(
              hbase + (((long)ci_l << 14) + (iy[r] << 7)) + 4 * l32)
        : (u32x4)0u;

  f32x4 acc[4];
#pragma unroll
  for (int nt = 0; nt < 4; ++nt) acc[nt] = (f32x4)0.f;

  for (int rnd = 0; rnd < 16; ++rnd) {
    __syncthreads();                               // buffer consumed / halo done
#pragma unroll
    for (int r = 0; r < 4; ++r) {
      unsigned* dst = &hs[ci_l][r][1 + 4 * l32];
      dst[0] = pre[r][0]; dst[1] = pre[r][1];
      dst[2] = pre[r][2]; dst[3] = pre[r][3];
    }
    __syncthreads();                               // tile visible
    if (rnd < 15) {
      long cb8 = ((long)((rnd + 1) * 8 + ci_l)) << 14;
#pragma unroll
      for (int r = 0; r < 4; ++r)
        pre[r] = rowok[r]
            ? *reinterpret_cast<const u32x4*>(
                  hbase + cb8 + (iy[r] << 7) + 4 * l32)
            : (u32x4)0u;
    }
#pragma unroll
    for (int ky = 0; ky < 4; ++ky) {
      int ks = (rnd << 2) + ky;
      FragU ah, al_;
      long aoff = (((long)ks * 4 + w) * 64 + l) * 8;
      ah.u = *reinterpret_cast<const u32x4*>(wCh + aoff);
      al_.u = *reinterpret_cast<const u32x4*>(wCl + aoff);
#pragma unroll
      for (int nt = 0; nt < 4; ++nt) {
        const unsigned* pa = &hs[g * 2][ky][(nt << 5) + 2 * (l & 15)];
        const unsigned* pb = &hs[g * 2 + 1][ky][(nt << 5) + 2 * (l & 15)];
        unsigned a0 = pa[0], a1 = pa[1], a2 = pa[2], a3 = pa[3];
        unsigned b0 = pb[0], b1 = pb[1], b2_ = pb[2], b3 = pb[3];
        FragU bh, bl;
        bh.u[0] = __builtin_amdgcn_perm(a1, a0, 0x07060302u);
        bl.u[0] = __builtin_amdgcn_perm(a1, a0, 0x05040100u);
        bh.u[1] = __builtin_amdgcn_perm(a3, a2, 0x07060302u);
        bl.u[1] = __builtin_amdgcn_perm(a3, a2, 0x05040100u);
        bh.u[2] = __builtin_amdgcn_perm(b1, b0, 0x07060302u);
        bl.u[2] = __builtin_amdgcn_perm(b1, b0, 0x05040100u);
        bh.u[3] = __builtin_amdgcn_perm(b3, b2_, 0x07060302u);
        bl.u[3] = __builtin_amdgcn_perm(b3, b2_, 0x05040100u);
        acc[nt] = __builtin_amdgcn_mfma_f32_16x16x32_bf16(
            ah.h, bh.h, acc[nt], 0, 0, 0);
        acc[nt] = __builtin_amdgcn_mfma_f32_16x16x32_bf16(
            ah.h, bl.h, acc[nt], 0, 0, 0);
        acc[nt] = __builtin_amdgcn_mfma_f32_16x16x32_bf16(
            al_.h, bh.h, acc[nt], 0, 0, 0);
      }
    }
  }
#pragma unroll
  for (int nt = 0; nt < 4; ++nt) {
#pragma unroll
    for (int r = 0; r < 4; ++r) {
      int d = (w << 4) + (g << 2) + r;
      int x = (nt << 4) + (l & 15);
      float v = fmaxf(acc[nt][r] + b2[d], 0.f);
      z[((b * 64 + d) * 64 + y) * 64 + x] = v;
    }
  }
}

// ---------------- VQ: wave-split-K argmin + quantize + loss -----------------
__global__ __launch_bounds__(256) void vq_k(
    const float* __restrict__ z, const float* __restrict__ cb,
    const float* __restrict__ csq, unsigned int* __restrict__ q_pk,
    float* __restrict__ out, int n0) {
  __shared__ float cbs[4][2048];                   // 32 KB code tiles
  __shared__ float csqs[4][32];
  __shared__ float bdm[4][64];
  __shared__ int   bkm[4][64];
  __shared__ float redl[4];
  int t = threadIdx.x, l = t & 63;
  int w = __builtin_amdgcn_readfirstlane(t >> 6);
  int n = blockIdx.x * 64 + l;                     // chunk-local point
  int b = n >> 12, rem = n & 4095, y = rem >> 6, x = rem & 63;
  const float* zp = z + ((b * 64) * 64 + y) * 64 + x;
  float zr[64];
#pragma unroll
  for (int d = 0; d < 64; ++d) zr[d] = zp[d * 4096];  // coalesced across lanes

  float bestd = 1e30f;
  int bestk = 0;
  for (int r = 0; r < 4; ++r) {
    int k0 = w * 128 + r * 32;
    const float4* src = reinterpret_cast<const float4*>(cb + k0 * 64);
    float4* dst = reinterpret_cast<float4*>(&cbs[w][0]);
    __syncthreads();                               // tile r-1 fully consumed
#pragma unroll
    for (int i = 0; i < 8; ++i) dst[i * 64 + l] = src[i * 64 + l];
    if (l < 32) csqs[w][l] = csq[k0 + l];
    __syncthreads();                               // tile r visible
    for (int j = 0; j < 32; ++j) {
      const float* cp = &cbs[w][j * 64];
      float a0 = 0.f, a1 = 0.f, a2 = 0.f, a3 = 0.f;
#pragma unroll
      for (int d = 0; d < 16; ++d) {
        a0 = fmaf(cp[d], zr[d], a0);
        a1 = fmaf(cp[16 + d], zr[16 + d], a1);
        a2 = fmaf(cp[32 + d], zr[32 + d], a2);
        a3 = fmaf(cp[48 + d], zr[48 + d], a3);
      }
      float dist = csqs[w][j] - 2.f * ((a0 + a1) + (a2 + a3));
      if (dist < bestd) { bestd = dist; bestk = k0 + j; }  // first-min ties
    }
  }
  bdm[w][l] = bestd;
  bkm[w][l] = bestk;
  __syncthreads();
  float bd = bdm[0][l];
  int bk = bkm[0][l];
#pragma unroll
  for (int w2 = 1; w2 < 4; ++w2) {                 // ascending k, strict '<'
    float d2 = bdm[w2][l];
    int k2 = bkm[w2][l];
    if (d2 < bd) { bd = d2; bk = k2; }
  }
  if (w == 0) out[1 + n0 + n] = (float)bk;

  const float* cbest = cb + (bk << 6) + (w << 4);  // dims [16w,16w+16)
  unsigned int* qp = q_pk + ((b * 64 + (w << 4)) * 64 + y) * 64 + x;
  float ls = 0.f;
#pragma unroll
  for (int d = 0; d < 16; ++d) {
    float c = cbest[d];
    qp[d * 4096] = pack_hilo(c);
    float df = c - zr[(w << 4) + d];
    ls = fmaf(df, df, ls);
  }
#pragma unroll
  for (int m = 32; m; m >>= 1) ls += __shfl_xor(ls, m);
  if (l == 0) redl[w] = ls;
  __syncthreads();
  if (t == 0)
    atomicAdd(out, (redl[0] + redl[1] + redl[2] + redl[3]) * (1.25f / 8388608.f));
}

// ---------------- convT2 (64->128, 4x4, s2, p1) + relu: bf16x3 MFMA ---------
__global__ __launch_bounds__(256) void dconv2_k(
    const unsigned int* __restrict__ q_pk, const ushort_t* __restrict__ wAh,
    const ushort_t* __restrict__ wAl, const float* __restrict__ db2,
    float* __restrict__ g) {
  __shared__ unsigned int rows[64][2][68];         // 34.8 KB packed hi|lo
  int Y = blockIdx.x, b = blockIdx.y;
  int t = threadIdx.x, l = t & 63;
  int w = __builtin_amdgcn_readfirstlane(t >> 6);
  int pX = w & 1, coh = w >> 1;
  int yA = (Y + 1) >> 1, yB = yA - 1;
  int v = ((Y & 1) << 1) | pX;

  for (int s = t; s < 64 * 2 * 68; s += 256) {
    int ci = s / 136, r2 = s - ci * 136;
    int r = r2 / 68, i = r2 - r * 68;
    int yy = r ? yB : yA, ix = i - 1;
    unsigned val = 0u;
    if (i < 66 && yy >= 0 && yy < 64 && ix >= 0 && ix < 64)
      val = q_pk[((b * 64 + ci) * 64 + yy) * 64 + ix];
    rows[ci][r][i] = val;
  }
  __syncthreads();

  f32x4 acc[4][4];
#pragma unroll
  for (int mt = 0; mt < 4; ++mt)
#pragma unroll
    for (int nt = 0; nt < 4; ++nt) acc[mt][nt] = (f32x4)0.f;

  for (int s8 = 0; s8 < 8; ++s8) {
    FragU ah[4], al[4];
#pragma unroll
    for (int mt = 0; mt < 4; ++mt) {
      long off = ((((long)(v * 8 + s8) * 8 + (coh * 4 + mt)) * 64 + l) * 8);
      ah[mt].u = *reinterpret_cast<const u32x4*>(wAh + off);
      al[mt].u = *reinterpret_cast<const u32x4*>(wAl + off);
    }
#pragma unroll
    for (int nt = 0; nt < 4; ++nt) {
      int p = nt * 16 + (l & 15) + pX;
      int cc0 = (s8 << 3) + ((l >> 4) << 1);
      unsigned u0 = rows[cc0][0][p], u1 = rows[cc0][0][p + 1];
      unsigned u2 = rows[cc0][1][p], u3 = rows[cc0][1][p + 1];
      unsigned u4 = rows[cc0 + 1][0][p], u5 = rows[cc0 + 1][0][p + 1];
      unsigned u6 = rows[cc0 + 1][1][p], u7 = rows[cc0 + 1][1][p + 1];
      FragU bh, bl;
      bh.u[0] = (u0 >> 16) | (u1 & 0xFFFF0000u);
      bl.u[0] = (u0 & 0xFFFFu) | (u1 << 16);
      bh.u[1] = (u2 >> 16) | (u3 & 0xFFFF0000u);
      bl.u[1] = (u2 & 0xFFFFu) | (u3 << 16);
      bh.u[2] = (u4 >> 16) | (u5 & 0xFFFF0000u);
      bl.u[2] = (u4 & 0xFFFFu) | (u5 << 16);
      bh.u[3] = (u6 >> 16) | (u7 & 0xFFFF0000u);
      bl.u[3] = (u6 & 0xFFFFu) | (u7 << 16);
#pragma unroll
      for (int mt = 0; mt < 4; ++mt) {
        acc[mt][nt] = __builtin_amdgcn_mfma_f32_16x16x32_bf16(
            ah[mt].h, bh.h, acc[mt][nt], 0, 0, 0);
        acc[mt][nt] = __builtin_amdgcn_mfma_f32_16x16x32_bf16(
            ah[mt].h, bl.h, acc[mt][nt], 0, 0, 0);
        acc[mt][nt] = __builtin_amdgcn_mfma_f32_16x16x32_bf16(
            al[mt].h, bh.h, acc[mt][nt], 0, 0, 0);
      }
    }
  }

#pragma unroll
  for (int mt = 0; mt < 4; ++mt) {
#pragma unroll
    for (int r = 0; r < 4; ++r) {
      int co = ((coh * 4 + mt) << 4) + ((l >> 4) << 2) + r;
      float bias = db2[co];
#pragma unroll
      for (int nt = 0; nt < 4; ++nt) {
        int X = ((nt << 4) + (l & 15)) * 2 + pX;
        float val = fmaxf(acc[mt][nt][r] + bias, 0.f);
        g[((b * 128 + co) * 128 + Y) * 128 + X] = val;
      }
    }
  }
}

// ---------------- convT1 (128->1, 4x4, s2, p1) + sigmoid --------------------
// Direct-load, no LDS, no barriers (proven round 7).
__global__ __launch_bounds__(256) void dconv1_k(
    const float* __restrict__ g, const float* __restrict__ wd1,
    const float* __restrict__ db1, float* __restrict__ rec) {
  int a2 = blockIdx.x, b = blockIdx.y;
  int t = threadIdx.x;
  int w = __builtin_amdgcn_readfirstlane(t >> 6);
  int l = t & 63;
  int xh = w >> 1, pX = w & 1;
  int L = xh * 64 + l;                       // X = 2L + pX
  int kxA = pX ? 0 : 1, kxB = kxA + 2;
  int ixH = L + pX, ixL = L + pX - 1;
  bool okH = ixH < 128, okL = ixL >= 0;
  int yy0 = 2 * a2 - 1;
  bool vy[4];
#pragma unroll
  for (int r = 0; r < 4; ++r) vy[r] = (yy0 + r) >= 0 && (yy0 + r) < 128;

  const float* gb = g + ((long)b * 128) * 16384 + (long)yy0 * 128;
  float acc[4] = {0.f, 0.f, 0.f, 0.f};

  for (int ci = 0; ci < 128; ci += 2) {
    const float* p0 = gb + (long)ci * 16384;
    const float* p1 = p0 + 16384;
    float hi0[4], lo0[4], hi1[4], lo1[4];
#pragma unroll
    for (int r = 0; r < 4; ++r) {
      const float* q0 = p0 + r * 128;
      const float* q1 = p1 + r * 128;
      hi0[r] = (vy[r] && okH) ? q0[ixH] : 0.f;
      lo0[r] = (vy[r] && okL) ? q0[ixL] : 0.f;
      hi1[r] = (vy[r] && okH) ? q1[ixH] : 0.f;
      lo1[r] = (vy[r] && okL) ? q1[ixL] : 0.f;
    }
    const float* wp0 = wd1 + ci * 16;        // wave-uniform -> s_load
    const float* wp1 = wp0 + 16;
#pragma unroll
    for (int j = 0; j < 4; ++j) {
      int kyA = (j + 1) & 1, kyB = kyA + 2;
      int rA = ((j + 1) >> 1) + 1;           // in [1,3]
      float v = acc[j];
      v = fmaf(wp0[kyA * 4 + kxA], hi0[rA], v);
      v = fmaf(wp0[kyA * 4 + kxB], lo0[rA], v);
      v = fmaf(wp0[kyB * 4 + kxA], hi0[rA - 1], v);
      v = fmaf(wp0[kyB * 4 + kxB], lo0[rA - 1], v);
      v = fmaf(wp1[kyA * 4 + kxA], hi1[rA], v);
      v = fmaf(wp1[kyA * 4 + kxB], lo1[rA], v);
      v = fmaf(wp1[kyB * 4 + kxA], hi1[rA - 1], v);
      v = fmaf(wp1[kyB * 4 + kxB], lo1[rA - 1], v);
      acc[j] = v;
    }
  }
  float bb = db1[0];
#pragma unroll
  for (int j = 0; j < 4; ++j) {
    float v = acc[j] + bb;
    v = 1.f / (1.f + __expf(-v));
    rec[((b * 256 + 4 * a2 + j) * 256) + 2 * L + pX] = v;
  }
}

// ---------------------------------------------------------------------------
extern "C" void kernel_launch(void* const* d_in, const int* in_sizes, int n_in,
                              void* d_out, int out_size, void* d_ws, size_t ws_size,
                              hipStream_t stream) {
  const float* x      = (const float*)d_in[0];
  const float* enc_w1 = (const float*)d_in[1];
  const float* enc_b1 = (const float*)d_in[2];
  const float* enc_w2 = (const float*)d_in[3];
  const float* enc_b2 = (const float*)d_in[4];
  const float* cb     = (const float*)d_in[5];
  const float* dec_w2 = (const float*)d_in[6];
  const float* dec_b2 = (const float*)d_in[7];
  const float* dec_w1 = (const float*)d_in[8];
  const float* dec_b1 = (const float*)d_in[9];

  float* out = (float*)d_out;
  float* ws  = (float*)d_ws;
  ushort_t* wCh = (ushort_t*)ws;                    // 131072 ushort = 65536 f
  ushort_t* wCl = (ushort_t*)(ws + 65536);
  ushort_t* wAh = (ushort_t*)(ws + 131072);
  ushort_t* wAl = (ushort_t*)(ws + 196608);
  float* csq = ws + 262144;                         // 512
  float* dyn = ws + 262656;                         // chunk buffers

  // Per-image: h_pk = 2,097,152 u32 (g f32 aliases), z/q_pk = 262,144.
  const size_t PER_IMG = 2097152 + 262144;                   // 2,359,296 elems
  size_t avail = (ws_size / 4 > 262656 + 64) ? ws_size / 4 - 262656 - 64 : 0;
  int CB = 32;
  while (CB > 1 && (size_t)CB * PER_IMG > avail) CB >>= 1;

  zero_loss_k<<<dim3(1), 64, 0, stream>>>(out);
  repackA2_k<<<dim3(512), 256, 0, stream>>>(enc_w2, wCh, wCl);
  repackA_k<<<dim3(512), 256, 0, stream>>>(dec_w2, wAh, wAl);
  csq_k<<<dim3(2), 256, 0, stream>>>(cb, csq);

  for (int b0 = 0; b0 < 32; b0 += CB) {
    unsigned* hp = (unsigned*)dyn;                    // CB*2097152 (g aliases)
    float* zq = dyn + (size_t)CB * 2097152;           // CB*262144 (q_pk aliases)
    conv1_k<<<dim3(128, CB), 128, 0, stream>>>(
        x + (size_t)b0 * 65536, enc_w1, enc_b1, hp);
    conv2_k<<<dim3(64, CB), 256, 0, stream>>>(hp, wCh, wCl, enc_b2, zq);
    vq_k<<<dim3(CB * 64), 256, 0, stream>>>(
        zq, cb, csq, (unsigned int*)zq, out, b0 * 4096);
    dconv2_k<<<dim3(128, CB), 256, 0, stream>>>(
        (const unsigned int*)zq, wAh, wAl, dec_b2, (float*)dyn /*g*/);
    dconv1_k<<<dim3(64, CB), 256, 0, stream>>>(
        (float*)dyn /*g*/, dec_w1, dec_b1, out + REC_OFF + (size_t)b0 * 65536);
  }
}

// Round 9
// 695.208 us; speedup vs baseline: 2.9606x; 1.1348x over previous
//
#include <hip/hip_runtime.h>
#include <math.h>

// ---------------------------------------------------------------------------
// VQ-VAE forward, bf16x3-MFMA for conv2, convT2 AND VQ distances.
//  x (32,1,256,256) -> h_pk (32,128,128,128 u32 hi|lo) -> z (32,64,64,64 f32)
//  VQ: N=131072 x D=64 vs K=512 = M512/N64/K64 GEMM per 64-pt block
//  q packed bf16 hi/lo aliases z; g (f32, aliases h_pk) -> x_recon
// d_out: [0]=vq_loss, [1..131072]=idx (as float), [131073..]=x_recon
// ws: wCh|wCl|wAh|wAl 65536f ea | cbFh 16384f | cbFl 16384f | csqF 8192f | dyn
// Fragment conventions (HW-verified, absmax 0.0 rounds 4-8):
//   A/B: lane l holds k_local = 8*(l>>4)+j, m/n = l&15
//   C/D: row = (l>>4)*4 + reg, col = l&15
// Round 9: vq_k distances via bf16x3 MFMA; codebook in A-fragment table,
// csq pre-laid in C/D order; z staged packed in LDS (S=67); argmin fp32.
// ---------------------------------------------------------------------------

#define REC_OFF 131073

typedef unsigned short ushort_t;
typedef __attribute__((ext_vector_type(8))) short bf16x8;
typedef __attribute__((ext_vector_type(4))) float f32x4;
typedef __attribute__((ext_vector_type(4))) unsigned int u32x4;
union FragU { u32x4 u; bf16x8 h; };

__device__ __forceinline__ unsigned pack_hilo(float v) {
  unsigned u = __float_as_uint(v);
  unsigned htop = u & 0xFFFF0000u;
  float rf = v - __uint_as_float(htop);
  return htop | (__float_as_uint(rf) >> 16);
}

__global__ __launch_bounds__(64) void zero_loss_k(float* __restrict__ out) {
  if (threadIdx.x == 0) out[0] = 0.f;
}

// ---- conv2 A-table: [ks=ci0*4+ky][mt][lane][j] bf16 hi/lo -----------------
__global__ __launch_bounds__(256) void repackA2_k(
    const float* __restrict__ ew2,
    ushort_t* __restrict__ hi, ushort_t* __restrict__ lo) {
  int idx = blockIdx.x * 256 + threadIdx.x;        // 131072 total
  int j = idx & 7, l = (idx >> 3) & 63, mt = (idx >> 9) & 3, ks = idx >> 11;
  int ci = ((ks >> 2) << 3) + ((l >> 4) << 1) + (j >> 2);
  int ky = ks & 3, kx = j & 3, d = (mt << 4) + (l & 15);
  float val = ew2[((d << 7) + ci) * 16 + (ky << 2) + kx];
  unsigned u = __float_as_uint(val);
  float rf = val - __uint_as_float(u & 0xFFFF0000u);
  hi[idx] = (ushort_t)(u >> 16);
  lo[idx] = (ushort_t)(__float_as_uint(rf) >> 16);
}

// ---- dconv2 A-table (proven) ----------------------------------------------
__global__ __launch_bounds__(256) void repackA_k(
    const float* __restrict__ dw2,   // dec_w2 (ci=64, co=128, ky, kx)
    ushort_t* __restrict__ hi, ushort_t* __restrict__ lo) {
  int idx = blockIdx.x * 256 + threadIdx.x;        // 131072 total
  int j = idx & 7, l = (idx >> 3) & 63, mt = (idx >> 9) & 7;
  int s = (idx >> 12) & 7, v = idx >> 15;
  int co = (mt << 4) + (l & 15);
  int ci = (s << 3) + ((l >> 4) << 1) + (j >> 2);
  int tap = j & 3;
  int Yp = v >> 1, pX = v & 1;
  int kyA = 1 - Yp, kyB = kyA + 2;
  int kxA = pX ? 0 : 1, kxB = kxA + 2;
  int ky = (tap & 2) ? kyB : kyA;
  int kx = (tap & 1) ? kxA : kxB;
  float val = dw2[(((ci << 7) + co) << 4) + (ky << 2) + kx];
  unsigned u = __float_as_uint(val);
  float rf = val - __uint_as_float(u & 0xFFFF0000u);
  hi[idx] = (ushort_t)(u >> 16);
  lo[idx] = (ushort_t)(__float_as_uint(rf) >> 16);
}

// ---- VQ codebook A-table: [ks(2)][mt(32)][lane(64)][j(8)] bf16 hi/lo ------
__global__ __launch_bounds__(256) void repackCB_k(
    const float* __restrict__ cb,
    ushort_t* __restrict__ hi, ushort_t* __restrict__ lo) {
  int idx = blockIdx.x * 256 + threadIdx.x;        // 32768 total
  int j = idx & 7, l = (idx >> 3) & 63, mt = (idx >> 9) & 31, ks = idx >> 14;
  int code = (mt << 4) + (l & 15);
  int k = (ks << 5) + ((l >> 4) << 3) + j;
  float val = cb[(code << 6) + k];
  unsigned u = __float_as_uint(val);
  float rf = val - __uint_as_float(u & 0xFFFF0000u);
  hi[idx] = (ushort_t)(u >> 16);
  lo[idx] = (ushort_t)(__float_as_uint(rf) >> 16);
}

// ---- csq in C/D fragment order: csqF[(mt*64+l)*4+r] = |cb[code]|^2 --------
__global__ __launch_bounds__(256) void csqF_k(
    const float* __restrict__ cb, float* __restrict__ csqF) {
  int idx = blockIdx.x * 256 + threadIdx.x;        // 8192 total
  int r = idx & 3, l = (idx >> 2) & 63, mt = idx >> 8;
  int code = (mt << 4) + ((l >> 4) << 2) + r;
  const float* cp = cb + (code << 6);
  float s = 0.f;
#pragma unroll
  for (int d = 0; d < 64; ++d) s = fmaf(cp[d], cp[d], s);
  csqF[idx] = s;
}

// ---------------- conv1 (1->128, 4x4, s2, p1) + relu -> packed u32 ----------
__global__ __launch_bounds__(128) void conv1_k(
    const float* __restrict__ x, const float* __restrict__ w1,
    const float* __restrict__ b1, unsigned* __restrict__ hp) {
  int oy = blockIdx.x, b = blockIdx.y, ox = threadIdx.x;
  float xv[16];
#pragma unroll
  for (int ky = 0; ky < 4; ++ky) {
    int iy = 2 * oy - 1 + ky;
#pragma unroll
    for (int kx = 0; kx < 4; ++kx) {
      int ix = 2 * ox - 1 + kx;
      float v = 0.f;
      if (iy >= 0 && iy < 256 && ix >= 0 && ix < 256)
        v = x[(b * 256 + iy) * 256 + ix];
      xv[ky * 4 + kx] = v;
    }
  }
  for (int c = 0; c < 128; ++c) {
    const float* wp = w1 + c * 16;                 // wave-uniform -> s_load
    float acc = b1[c];
#pragma unroll
    for (int k = 0; k < 16; ++k) acc = fmaf(xv[k], wp[k], acc);
    hp[((b * 128 + c) * 128 + oy) * 128 + ox] = pack_hilo(fmaxf(acc, 0.f));
  }
}

// ---------------- conv2 (128->64, 4x4, s2, p1) + relu: bf16x3 MFMA ----------
#define C2RL 133
__global__ __launch_bounds__(256) void conv2_k(
    const unsigned* __restrict__ hp, const ushort_t* __restrict__ wCh,
    const ushort_t* __restrict__ wCl, const float* __restrict__ b2,
    float* __restrict__ z) {
  __shared__ unsigned hs[8][4][C2RL];              // 17 KB
  int y = blockIdx.x, b = blockIdx.y;
  int t = threadIdx.x, l = t & 63;
  int w = __builtin_amdgcn_readfirstlane(t >> 6);  // = mt
  int g = l >> 4;

  if (t < 64) hs[t >> 3][(t >> 1) & 3][(t & 1) ? 129 : 0] = 0u;

  int ci_l = t >> 5, l32 = t & 31;
  int iy[4];
  bool rowok[4];
#pragma unroll
  for (int r = 0; r < 4; ++r) {
    iy[r] = 2 * y - 1 + r;
    rowok[r] = iy[r] >= 0 && iy[r] < 128;
  }
  const unsigned* hbase = hp + (((long)b * 128) << 14);

  u32x4 pre[4];
#pragma unroll
  for (int r = 0; r < 4; ++r)
    pre[r] = rowok[r]
        ? *reinterpret_cast<const u32x4*>(
              hbase + (((long)ci_l << 14) + (iy[r] << 7)) + 4 * l32)
        : (u32x4)0u;

  f32x4 acc[4];
#pragma unroll
  for (int nt = 0; nt < 4; ++nt) acc[nt] = (f32x4)0.f;

  for (int rnd = 0; rnd < 16; ++rnd) {
    __syncthreads();                               // buffer consumed / halo done
#pragma unroll
    for (int r = 0; r < 4; ++r) {
      unsigned* dst = &hs[ci_l][r][1 + 4 * l32];
      dst[0] = pre[r][0]; dst[1] = pre[r][1];
      dst[2] = pre[r][2]; dst[3] = pre[r][3];
    }
    __syncthreads();                               // tile visible
    if (rnd < 15) {
      long cb8 = ((long)((rnd + 1) * 8 + ci_l)) << 14;
#pragma unroll
      for (int r = 0; r < 4; ++r)
        pre[r] = rowok[r]
            ? *reinterpret_cast<const u32x4*>(
                  hbase + cb8 + (iy[r] << 7) + 4 * l32)
            : (u32x4)0u;
    }
#pragma unroll
    for (int ky = 0; ky < 4; ++ky) {
      int ks = (rnd << 2) + ky;
      FragU ah, al_;
      long aoff = (((long)ks * 4 + w) * 64 + l) * 8;
      ah.u = *reinterpret_cast<const u32x4*>(wCh + aoff);
      al_.u = *reinterpret_cast<const u32x4*>(wCl + aoff);
#pragma unroll
      for (int nt = 0; nt < 4; ++nt) {
        const unsigned* pa = &hs[g * 2][ky][(nt << 5) + 2 * (l & 15)];
        const unsigned* pb = &hs[g * 2 + 1][ky][(nt << 5) + 2 * (l & 15)];
        unsigned a0 = pa[0], a1 = pa[1], a2 = pa[2], a3 = pa[3];
        unsigned b0 = pb[0], b1 = pb[1], b2_ = pb[2], b3 = pb[3];
        FragU bh, bl;
        bh.u[0] = __builtin_amdgcn_perm(a1, a0, 0x07060302u);
        bl.u[0] = __builtin_amdgcn_perm(a1, a0, 0x05040100u);
        bh.u[1] = __builtin_amdgcn_perm(a3, a2, 0x07060302u);
        bl.u[1] = __builtin_amdgcn_perm(a3, a2, 0x05040100u);
        bh.u[2] = __builtin_amdgcn_perm(b1, b0, 0x07060302u);
        bl.u[2] = __builtin_amdgcn_perm(b1, b0, 0x05040100u);
        bh.u[3] = __builtin_amdgcn_perm(b3, b2_, 0x07060302u);
        bl.u[3] = __builtin_amdgcn_perm(b3, b2_, 0x05040100u);
        acc[nt] = __builtin_amdgcn_mfma_f32_16x16x32_bf16(
            ah.h, bh.h, acc[nt], 0, 0, 0);
        acc[nt] = __builtin_amdgcn_mfma_f32_16x16x32_bf16(
            ah.h, bl.h, acc[nt], 0, 0, 0);
        acc[nt] = __builtin_amdgcn_mfma_f32_16x16x32_bf16(
            al_.h, bh.h, acc[nt], 0, 0, 0);
      }
    }
  }
#pragma unroll
  for (int nt = 0; nt < 4; ++nt) {
#pragma unroll
    for (int r = 0; r < 4; ++r) {
      int d = (w << 4) + (g << 2) + r;
      int x = (nt << 4) + (l & 15);
      float v = fmaxf(acc[nt][r] + b2[d], 0.f);
      z[((b * 64 + d) * 64 + y) * 64 + x] = v;
    }
  }
}

// ---------------- VQ: bf16x3 MFMA distances + fp32 argmin -------------------
// block = 64 points (one b,y row), 4 waves = n-tile (16 points, all 512 codes).
// zS: packed hi|lo z, stride 67 (<=2-way banks). Argmin: per-lane ascending
// code scan strict '<', shfl merge with (d,k) tie-break = np first-min.
__global__ __launch_bounds__(256) void vq_k(
    const float* z, const float* __restrict__ cb,
    const ushort_t* __restrict__ cbFh, const ushort_t* __restrict__ cbFl,
    const float* __restrict__ csqF, unsigned int* q_pk,
    float* __restrict__ out, int n0) {
  __shared__ unsigned zS[64 * 67];                 // 17.2 KB
  __shared__ int bk_arr[64];
  __shared__ float redl[4];
  int t = threadIdx.x, l = t & 63;
  int w = __builtin_amdgcn_readfirstlane(t >> 6);
  int nbase = blockIdx.x * 64;
  int b = nbase >> 12, y = (nbase >> 6) & 63;
  long zbase = (long)b * 262144 + y * 64;

  // Phase A: stage z packed. thread t: point l, dims [16w, 16w+16).
#pragma unroll
  for (int j = 0; j < 16; ++j) {
    float v = z[zbase + (long)((w << 4) + j) * 4096 + l];
    zS[l * 67 + (w << 4) + j] = pack_hilo(v);
  }
  __syncthreads();

  // Phase B: wave w covers points w*16..+15 x all 512 codes.
  f32x4 acc[32];
#pragma unroll
  for (int mt = 0; mt < 32; ++mt) acc[mt] = (f32x4)0.f;

  int pp = (w << 4) + (l & 15);                    // this lane's B point
#pragma unroll
  for (int ks = 0; ks < 2; ++ks) {
    const unsigned* zp = &zS[pp * 67 + (ks << 5) + ((l >> 4) << 3)];
    unsigned u0 = zp[0], u1 = zp[1], u2 = zp[2], u3 = zp[3];
    unsigned u4 = zp[4], u5 = zp[5], u6 = zp[6], u7 = zp[7];
    FragU bh, bl;
    bh.u[0] = __builtin_amdgcn_perm(u1, u0, 0x07060302u);
    bl.u[0] = __builtin_amdgcn_perm(u1, u0, 0x05040100u);
    bh.u[1] = __builtin_amdgcn_perm(u3, u2, 0x07060302u);
    bl.u[1] = __builtin_amdgcn_perm(u3, u2, 0x05040100u);
    bh.u[2] = __builtin_amdgcn_perm(u5, u4, 0x07060302u);
    bl.u[2] = __builtin_amdgcn_perm(u5, u4, 0x05040100u);
    bh.u[3] = __builtin_amdgcn_perm(u7, u6, 0x07060302u);
    bl.u[3] = __builtin_amdgcn_perm(u7, u6, 0x05040100u);
#pragma unroll
    for (int mt = 0; mt < 32; ++mt) {
      long aoff = (((long)(ks * 32 + mt) * 64) + l) * 8;
      FragU ah, al_;
      ah.u = *reinterpret_cast<const u32x4*>(cbFh + aoff);
      al_.u = *reinterpret_cast<const u32x4*>(cbFl + aoff);
      acc[mt] = __builtin_amdgcn_mfma_f32_16x16x32_bf16(
          ah.h, bh.h, acc[mt], 0, 0, 0);
      acc[mt] = __builtin_amdgcn_mfma_f32_16x16x32_bf16(
          ah.h, bl.h, acc[mt], 0, 0, 0);
      acc[mt] = __builtin_amdgcn_mfma_f32_16x16x32_bf16(
          al_.h, bh.h, acc[mt], 0, 0, 0);
    }
  }

  // Argmin epilogue: d = csqF - 2*dot, ascending code per lane.
  int g = l >> 4;
  float bd = 1e30f;
  int bk = 0;
#pragma unroll
  for (int mt = 0; mt < 32; ++mt) {
    f32x4 cq = *reinterpret_cast<const f32x4*>(csqF + ((mt << 6) + l) * 4);
#pragma unroll
    for (int r = 0; r < 4; ++r) {
      float d = fmaf(-2.f, acc[mt][r], cq[r]);
      if (d < bd) { bd = d; bk = (mt << 4) + (g << 2) + r; }
    }
  }
#pragma unroll
  for (int m = 16; m <= 32; m <<= 1) {
    float d2 = __shfl_xor(bd, m);
    int k2 = __shfl_xor(bk, m);
    if (d2 < bd || (d2 == bd && k2 < bk)) { bd = d2; bk = k2; }
  }
  if (l < 16) {
    bk_arr[(w << 4) + l] = bk;
    out[1 + n0 + nbase + (w << 4) + l] = (float)bk;
  }
  __syncthreads();

  // Phase C: thread t: point l, dims [16w,16w+16): loss + packed q write.
  int bkp = bk_arr[l];
  const float* cbest = cb + (bkp << 6) + (w << 4);
  float zv[16];
#pragma unroll
  for (int j = 0; j < 16; ++j)
    zv[j] = z[zbase + (long)((w << 4) + j) * 4096 + l];
  float ls = 0.f;
#pragma unroll
  for (int j = 0; j < 16; ++j) {
    float c = cbest[j];
    q_pk[zbase + (long)((w << 4) + j) * 4096 + l] = pack_hilo(c);
    float df = c - zv[j];
    ls = fmaf(df, df, ls);
  }
#pragma unroll
  for (int m = 32; m; m >>= 1) ls += __shfl_xor(ls, m);
  if (l == 0) redl[w] = ls;
  __syncthreads();
  if (t == 0)
    atomicAdd(out, (redl[0] + redl[1] + redl[2] + redl[3]) * (1.25f / 8388608.f));
}

// ---------------- convT2 (64->128, 4x4, s2, p1) + relu: bf16x3 MFMA ---------
__global__ __launch_bounds__(256) void dconv2_k(
    const unsigned int* __restrict__ q_pk, const ushort_t* __restrict__ wAh,
    const ushort_t* __restrict__ wAl, const float* __restrict__ db2,
    float* __restrict__ g) {
  __shared__ unsigned int rows[64][2][68];         // 34.8 KB packed hi|lo
  int Y = blockIdx.x, b = blockIdx.y;
  int t = threadIdx.x, l = t & 63;
  int w = __builtin_amdgcn_readfirstlane(t >> 6);
  int pX = w & 1, coh = w >> 1;
  int yA = (Y + 1) >> 1, yB = yA - 1;
  int v = ((Y & 1) << 1) | pX;

  for (int s = t; s < 64 * 2 * 68; s += 256) {
    int ci = s / 136, r2 = s - ci * 136;
    int r = r2 / 68, i = r2 - r * 68;
    int yy = r ? yB : yA, ix = i - 1;
    unsigned val = 0u;
    if (i < 66 && yy >= 0 && yy < 64 && ix >= 0 && ix < 64)
      val = q_pk[((b * 64 + ci) * 64 + yy) * 64 + ix];
    rows[ci][r][i] = val;
  }
  __syncthreads();

  f32x4 acc[4][4];
#pragma unroll
  for (int mt = 0; mt < 4; ++mt)
#pragma unroll
    for (int nt = 0; nt < 4; ++nt) acc[mt][nt] = (f32x4)0.f;

  for (int s8 = 0; s8 < 8; ++s8) {
    FragU ah[4], al[4];
#pragma unroll
    for (int mt = 0; mt < 4; ++mt) {
      long off = ((((long)(v * 8 + s8) * 8 + (coh * 4 + mt)) * 64 + l) * 8);
      ah[mt].u = *reinterpret_cast<const u32x4*>(wAh + off);
      al[mt].u = *reinterpret_cast<const u32x4*>(wAl + off);
    }
#pragma unroll
    for (int nt = 0; nt < 4; ++nt) {
      int p = nt * 16 + (l & 15) + pX;
      int cc0 = (s8 << 3) + ((l >> 4) << 1);
      unsigned u0 = rows[cc0][0][p], u1 = rows[cc0][0][p + 1];
      unsigned u2 = rows[cc0][1][p], u3 = rows[cc0][1][p + 1];
      unsigned u4 = rows[cc0 + 1][0][p], u5 = rows[cc0 + 1][0][p + 1];
      unsigned u6 = rows[cc0 + 1][1][p], u7 = rows[cc0 + 1][1][p + 1];
      FragU bh, bl;
      bh.u[0] = (u0 >> 16) | (u1 & 0xFFFF0000u);
      bl.u[0] = (u0 & 0xFFFFu) | (u1 << 16);
      bh.u[1] = (u2 >> 16) | (u3 & 0xFFFF0000u);
      bl.u[1] = (u2 & 0xFFFFu) | (u3 << 16);
      bh.u[2] = (u4 >> 16) | (u5 & 0xFFFF0000u);
      bl.u[2] = (u4 & 0xFFFFu) | (u5 << 16);
      bh.u[3] = (u6 >> 16) | (u7 & 0xFFFF0000u);
      bl.u[3] = (u6 & 0xFFFFu) | (u7 << 16);
#pragma unroll
      for (int mt = 0; mt < 4; ++mt) {
        acc[mt][nt] = __builtin_amdgcn_mfma_f32_16x16x32_bf16(
            ah[mt].h, bh.h, acc[mt][nt], 0, 0, 0);
        acc[mt][nt] = __builtin_amdgcn_mfma_f32_16x16x32_bf16(
            ah[mt].h, bl.h, acc[mt][nt], 0, 0, 0);
        acc[mt][nt] = __builtin_amdgcn_mfma_f32_16x16x32_bf16(
            al[mt].h, bh.h, acc[mt][nt], 0, 0, 0);
      }
    }
  }

#pragma unroll
  for (int mt = 0; mt < 4; ++mt) {
#pragma unroll
    for (int r = 0; r < 4; ++r) {
      int co = ((coh * 4 + mt) << 4) + ((l >> 4) << 2) + r;
      float bias = db2[co];
#pragma unroll
      for (int nt = 0; nt < 4; ++nt) {
        int X = ((nt << 4) + (l & 15)) * 2 + pX;
        float val = fmaxf(acc[mt][nt][r] + bias, 0.f);
        g[((b * 128 + co) * 128 + Y) * 128 + X] = val;
      }
    }
  }
}

// ---------------- convT1 (128->1, 4x4, s2, p1) + sigmoid --------------------
__global__ __launch_bounds__(256) void dconv1_k(
    const float* __restrict__ g, const float* __restrict__ wd1,
    const float* __restrict__ db1, float* __restrict__ rec) {
  int a2 = blockIdx.x, b = blockIdx.y;
  int t = threadIdx.x;
  int w = __builtin_amdgcn_readfirstlane(t >> 6);
  int l = t & 63;
  int xh = w >> 1, pX = w & 1;
  int L = xh * 64 + l;                       // X = 2L + pX
  int kxA = pX ? 0 : 1, kxB = kxA + 2;
  int ixH = L + pX, ixL = L + pX - 1;
  bool okH = ixH < 128, okL = ixL >= 0;
  int yy0 = 2 * a2 - 1;
  bool vy[4];
#pragma unroll
  for (int r = 0; r < 4; ++r) vy[r] = (yy0 + r) >= 0 && (yy0 + r) < 128;

  const float* gb = g + ((long)b * 128) * 16384 + (long)yy0 * 128;
  float acc[4] = {0.f, 0.f, 0.f, 0.f};

  for (int ci = 0; ci < 128; ci += 2) {
    const float* p0 = gb + (long)ci * 16384;
    const float* p1 = p0 + 16384;
    float hi0[4], lo0[4], hi1[4], lo1[4];
#pragma unroll
    for (int r = 0; r < 4; ++r) {
      const float* q0 = p0 + r * 128;
      const float* q1 = p1 + r * 128;
      hi0[r] = (vy[r] && okH) ? q0[ixH] : 0.f;
      lo0[r] = (vy[r] && okL) ? q0[ixL] : 0.f;
      hi1[r] = (vy[r] && okH) ? q1[ixH] : 0.f;
      lo1[r] = (vy[r] && okL) ? q1[ixL] : 0.f;
    }
    const float* wp0 = wd1 + ci * 16;        // wave-uniform -> s_load
    const float* wp1 = wp0 + 16;
#pragma unroll
    for (int j = 0; j < 4; ++j) {
      int kyA = (j + 1) & 1, kyB = kyA + 2;
      int rA = ((j + 1) >> 1) + 1;           // in [1,3]
      float v = acc[j];
      v = fmaf(wp0[kyA * 4 + kxA], hi0[rA], v);
      v = fmaf(wp0[kyA * 4 + kxB], lo0[rA], v);
      v = fmaf(wp0[kyB * 4 + kxA], hi0[rA - 1], v);
      v = fmaf(wp0[kyB * 4 + kxB], lo0[rA - 1], v);
      v = fmaf(wp1[kyA * 4 + kxA], hi1[rA], v);
      v = fmaf(wp1[kyA * 4 + kxB], lo1[rA], v);
      v = fmaf(wp1[kyB * 4 + kxA], hi1[rA - 1], v);
      v = fmaf(wp1[kyB * 4 + kxB], lo1[rA - 1], v);
      acc[j] = v;
    }
  }
  float bb = db1[0];
#pragma unroll
  for (int j = 0; j < 4; ++j) {
    float v = acc[j] + bb;
    v = 1.f / (1.f + __expf(-v));
    rec[((b * 256 + 4 * a2 + j) * 256) + 2 * L + pX] = v;
  }
}

// ---------------------------------------------------------------------------
extern "C" void kernel_launch(void* const* d_in, const int* in_sizes, int n_in,
                              void* d_out, int out_size, void* d_ws, size_t ws_size,
                              hipStream_t stream) {
  const float* x      = (const float*)d_in[0];
  const float* enc_w1 = (const float*)d_in[1];
  const float* enc_b1 = (const float*)d_in[2];
  const float* enc_w2 = (const float*)d_in[3];
  const float* enc_b2 = (const float*)d_in[4];
  const float* cb     = (const float*)d_in[5];
  const float* dec_w2 = (const float*)d_in[6];
  const float* dec_b2 = (const float*)d_in[7];
  const float* dec_w1 = (const float*)d_in[8];
  const float* dec_b1 = (const float*)d_in[9];

  float* out = (float*)d_out;
  float* ws  = (float*)d_ws;
  ushort_t* wCh  = (ushort_t*)ws;                   // 131072 ushort = 65536 f
  ushort_t* wCl  = (ushort_t*)(ws + 65536);
  ushort_t* wAh  = (ushort_t*)(ws + 131072);
  ushort_t* wAl  = (ushort_t*)(ws + 196608);
  ushort_t* cbFh = (ushort_t*)(ws + 262144);        // 32768 ushort = 16384 f
  ushort_t* cbFl = (ushort_t*)(ws + 278528);
  float* csqF = ws + 294912;                        // 8192 f
  float* dyn  = ws + 303104;                        // chunk buffers

  // Per-image: h_pk = 2,097,152 u32 (g f32 aliases), z/q_pk = 262,144.
  const size_t PER_IMG = 2097152 + 262144;                   // 2,359,296 elems
  size_t avail = (ws_size / 4 > 303104 + 64) ? ws_size / 4 - 303104 - 64 : 0;
  int CB = 32;
  while (CB > 1 && (size_t)CB * PER_IMG > avail) CB >>= 1;

  zero_loss_k<<<dim3(1), 64, 0, stream>>>(out);
  repackA2_k<<<dim3(512), 256, 0, stream>>>(enc_w2, wCh, wCl);
  repackA_k<<<dim3(512), 256, 0, stream>>>(dec_w2, wAh, wAl);
  repackCB_k<<<dim3(128), 256, 0, stream>>>(cb, cbFh, cbFl);
  csqF_k<<<dim3(32), 256, 0, stream>>>(cb, csqF);

  for (int b0 = 0; b0 < 32; b0 += CB) {
    unsigned* hp = (unsigned*)dyn;                    // CB*2097152 (g aliases)
    float* zq = dyn + (size_t)CB * 2097152;           // CB*262144 (q_pk aliases)
    conv1_k<<<dim3(128, CB), 128, 0, stream>>>(
        x + (size_t)b0 * 65536, enc_w1, enc_b1, hp);
    conv2_k<<<dim3(64, CB), 256, 0, stream>>>(hp, wCh, wCl, enc_b2, zq);
    vq_k<<<dim3(CB * 64), 256, 0, stream>>>(
        zq, cb, cbFh, cbFl, csqF, (unsigned int*)zq, out, b0 * 4096);
    dconv2_k<<<dim3(128, CB), 256, 0, stream>>>(
        (const unsigned int*)zq, wAh, wAl, dec_b2, (float*)dyn /*g*/);
    dconv1_k<<<dim3(64, CB), 256, 0, stream>>>(
        (float*)dyn /*g*/, dec_w1, dec_b1, out + REC_OFF + (size_t)b0 * 65536);
  }
}

// Round 10
// 603.787 us; speedup vs baseline: 3.4089x; 1.1514x over previous
//
#include <hip/hip_runtime.h>
#include <math.h>

// ---------------------------------------------------------------------------
// VQ-VAE forward, bf16x3-MFMA for conv2, convT2 AND VQ distances.
//  x (32,1,256,256) -> h_pk (32,128,128,128 u32 hi|lo) -> z (32,64,64,64 f32)
//  VQ: N=131072 x D=64 vs K=512 = M512/N64/K64 GEMM per 64-pt block
//  q packed bf16 hi/lo aliases z; g (f32, aliases h_pk) -> x_recon
// d_out: [0]=vq_loss, [1..131072]=idx (as float), [131073..]=x_recon
// ws: wCh|wCl|wAh|wAl 65536f ea | cbFh 16384f | cbFl 16384f | csqF 8192f | dyn
// Fragment conventions (HW-verified, absmax 0.0 rounds 4-9):
//   A/B: lane l holds k_local = 8*(l>>4)+j, m/n = l&15
//   C/D: row = (l>>4)*4 + reg, col = l&15
// Round 10: vq_k acc chunked 4x (codes 128/chunk) -> VGPR 132->~85, B-frags
// built once, z kept in regs for Phase C. Ascending scan = np first-min.
// ---------------------------------------------------------------------------

#define REC_OFF 131073

typedef unsigned short ushort_t;
typedef __attribute__((ext_vector_type(8))) short bf16x8;
typedef __attribute__((ext_vector_type(4))) float f32x4;
typedef __attribute__((ext_vector_type(4))) unsigned int u32x4;
union FragU { u32x4 u; bf16x8 h; };

__device__ __forceinline__ unsigned pack_hilo(float v) {
  unsigned u = __float_as_uint(v);
  unsigned htop = u & 0xFFFF0000u;
  float rf = v - __uint_as_float(htop);
  return htop | (__float_as_uint(rf) >> 16);
}

__global__ __launch_bounds__(64) void zero_loss_k(float* __restrict__ out) {
  if (threadIdx.x == 0) out[0] = 0.f;
}

// ---- conv2 A-table: [ks=ci0*4+ky][mt][lane][j] bf16 hi/lo -----------------
__global__ __launch_bounds__(256) void repackA2_k(
    const float* __restrict__ ew2,
    ushort_t* __restrict__ hi, ushort_t* __restrict__ lo) {
  int idx = blockIdx.x * 256 + threadIdx.x;        // 131072 total
  int j = idx & 7, l = (idx >> 3) & 63, mt = (idx >> 9) & 3, ks = idx >> 11;
  int ci = ((ks >> 2) << 3) + ((l >> 4) << 1) + (j >> 2);
  int ky = ks & 3, kx = j & 3, d = (mt << 4) + (l & 15);
  float val = ew2[((d << 7) + ci) * 16 + (ky << 2) + kx];
  unsigned u = __float_as_uint(val);
  float rf = val - __uint_as_float(u & 0xFFFF0000u);
  hi[idx] = (ushort_t)(u >> 16);
  lo[idx] = (ushort_t)(__float_as_uint(rf) >> 16);
}

// ---- dconv2 A-table (proven) ----------------------------------------------
__global__ __launch_bounds__(256) void repackA_k(
    const float* __restrict__ dw2,   // dec_w2 (ci=64, co=128, ky, kx)
    ushort_t* __restrict__ hi, ushort_t* __restrict__ lo) {
  int idx = blockIdx.x * 256 + threadIdx.x;        // 131072 total
  int j = idx & 7, l = (idx >> 3) & 63, mt = (idx >> 9) & 7;
  int s = (idx >> 12) & 7, v = idx >> 15;
  int co = (mt << 4) + (l & 15);
  int ci = (s << 3) + ((l >> 4) << 1) + (j >> 2);
  int tap = j & 3;
  int Yp = v >> 1, pX = v & 1;
  int kyA = 1 - Yp, kyB = kyA + 2;
  int kxA = pX ? 0 : 1, kxB = kxA + 2;
  int ky = (tap & 2) ? kyB : kyA;
  int kx = (tap & 1) ? kxA : kxB;
  float val = dw2[(((ci << 7) + co) << 4) + (ky << 2) + kx];
  unsigned u = __float_as_uint(val);
  float rf = val - __uint_as_float(u & 0xFFFF0000u);
  hi[idx] = (ushort_t)(u >> 16);
  lo[idx] = (ushort_t)(__float_as_uint(rf) >> 16);
}

// ---- VQ codebook A-table: [ks(2)][mt(32)][lane(64)][j(8)] bf16 hi/lo ------
__global__ __launch_bounds__(256) void repackCB_k(
    const float* __restrict__ cb,
    ushort_t* __restrict__ hi, ushort_t* __restrict__ lo) {
  int idx = blockIdx.x * 256 + threadIdx.x;        // 32768 total
  int j = idx & 7, l = (idx >> 3) & 63, mt = (idx >> 9) & 31, ks = idx >> 14;
  int code = (mt << 4) + (l & 15);
  int k = (ks << 5) + ((l >> 4) << 3) + j;
  float val = cb[(code << 6) + k];
  unsigned u = __float_as_uint(val);
  float rf = val - __uint_as_float(u & 0xFFFF0000u);
  hi[idx] = (ushort_t)(u >> 16);
  lo[idx] = (ushort_t)(__float_as_uint(rf) >> 16);
}

// ---- csq in C/D fragment order: csqF[(mt*64+l)*4+r] = |cb[code]|^2 --------
__global__ __launch_bounds__(256) void csqF_k(
    const float* __restrict__ cb, float* __restrict__ csqF) {
  int idx = blockIdx.x * 256 + threadIdx.x;        // 8192 total
  int r = idx & 3, l = (idx >> 2) & 63, mt = idx >> 8;
  int code = (mt << 4) + ((l >> 4) << 2) + r;
  const float* cp = cb + (code << 6);
  float s = 0.f;
#pragma unroll
  for (int d = 0; d < 64; ++d) s = fmaf(cp[d], cp[d], s);
  csqF[idx] = s;
}

// ---------------- conv1 (1->128, 4x4, s2, p1) + relu -> packed u32 ----------
__global__ __launch_bounds__(128) void conv1_k(
    const float* __restrict__ x, const float* __restrict__ w1,
    const float* __restrict__ b1, unsigned* __restrict__ hp) {
  int oy = blockIdx.x, b = blockIdx.y, ox = threadIdx.x;
  float xv[16];
#pragma unroll
  for (int ky = 0; ky < 4; ++ky) {
    int iy = 2 * oy - 1 + ky;
#pragma unroll
    for (int kx = 0; kx < 4; ++kx) {
      int ix = 2 * ox - 1 + kx;
      float v = 0.f;
      if (iy >= 0 && iy < 256 && ix >= 0 && ix < 256)
        v = x[(b * 256 + iy) * 256 + ix];
      xv[ky * 4 + kx] = v;
    }
  }
  for (int c = 0; c < 128; ++c) {
    const float* wp = w1 + c * 16;                 // wave-uniform -> s_load
    float acc = b1[c];
#pragma unroll
    for (int k = 0; k < 16; ++k) acc = fmaf(xv[k], wp[k], acc);
    hp[((b * 128 + c) * 128 + oy) * 128 + ox] = pack_hilo(fmaxf(acc, 0.f));
  }
}

// ---------------- conv2 (128->64, 4x4, s2, p1) + relu: bf16x3 MFMA ----------
#define C2RL 133
__global__ __launch_bounds__(256) void conv2_k(
    const unsigned* __restrict__ hp, const ushort_t* __restrict__ wCh,
    const ushort_t* __restrict__ wCl, const float* __restrict__ b2,
    float* __restrict__ z) {
  __shared__ unsigned hs[8][4][C2RL];              // 17 KB
  int y = blockIdx.x, b = blockIdx.y;
  int t = threadIdx.x, l = t & 63;
  int w = __builtin_amdgcn_readfirstlane(t >> 6);  // = mt
  int g = l >> 4;

  if (t < 64) hs[t >> 3][(t >> 1) & 3][(t & 1) ? 129 : 0] = 0u;

  int ci_l = t >> 5, l32 = t & 31;
  int iy[4];
  bool rowok[4];
#pragma unroll
  for (int r = 0; r < 4; ++r) {
    iy[r] = 2 * y - 1 + r;
    rowok[r] = iy[r] >= 0 && iy[r] < 128;
  }
  const unsigned* hbase = hp + (((long)b * 128) << 14);

  u32x4 pre[4];
#pragma unroll
  for (int r = 0; r < 4; ++r)
    pre[r] = rowok[r]
        ? *reinterpret_cast<const u32x4*>(
              hbase + (((long)ci_l << 14) + (iy[r] << 7)) + 4 * l32)
        : (u32x4)0u;

  f32x4 acc[4];
#pragma unroll
  for (int nt = 0; nt < 4; ++nt) acc[nt] = (f32x4)0.f;

  for (int rnd = 0; rnd < 16; ++rnd) {
    __syncthreads();                               // buffer consumed / halo done
#pragma unroll
    for (int r = 0; r < 4; ++r) {
      unsigned* dst = &hs[ci_l][r][1 + 4 * l32];
      dst[0] = pre[r][0]; dst[1] = pre[r][1];
      dst[2] = pre[r][2]; dst[3] = pre[r][3];
    }
    __syncthreads();                               // tile visible
    if (rnd < 15) {
      long cb8 = ((long)((rnd + 1) * 8 + ci_l)) << 14;
#pragma unroll
      for (int r = 0; r < 4; ++r)
        pre[r] = rowok[r]
            ? *reinterpret_cast<const u32x4*>(
                  hbase + cb8 + (iy[r] << 7) + 4 * l32)
            : (u32x4)0u;
    }
#pragma unroll
    for (int ky = 0; ky < 4; ++ky) {
      int ks = (rnd << 2) + ky;
      FragU ah, al_;
      long aoff = (((long)ks * 4 + w) * 64 + l) * 8;
      ah.u = *reinterpret_cast<const u32x4*>(wCh + aoff);
      al_.u = *reinterpret_cast<const u32x4*>(wCl + aoff);
#pragma unroll
      for (int nt = 0; nt < 4; ++nt) {
        const unsigned* pa = &hs[g * 2][ky][(nt << 5) + 2 * (l & 15)];
        const unsigned* pb = &hs[g * 2 + 1][ky][(nt << 5) + 2 * (l & 15)];
        unsigned a0 = pa[0], a1 = pa[1], a2 = pa[2], a3 = pa[3];
        unsigned b0 = pb[0], b1 = pb[1], b2_ = pb[2], b3 = pb[3];
        FragU bh, bl;
        bh.u[0] = __builtin_amdgcn_perm(a1, a0, 0x07060302u);
        bl.u[0] = __builtin_amdgcn_perm(a1, a0, 0x05040100u);
        bh.u[1] = __builtin_amdgcn_perm(a3, a2, 0x07060302u);
        bl.u[1] = __builtin_amdgcn_perm(a3, a2, 0x05040100u);
        bh.u[2] = __builtin_amdgcn_perm(b1, b0, 0x07060302u);
        bl.u[2] = __builtin_amdgcn_perm(b1, b0, 0x05040100u);
        bh.u[3] = __builtin_amdgcn_perm(b3, b2_, 0x07060302u);
        bl.u[3] = __builtin_amdgcn_perm(b3, b2_, 0x05040100u);
        acc[nt] = __builtin_amdgcn_mfma_f32_16x16x32_bf16(
            ah.h, bh.h, acc[nt], 0, 0, 0);
        acc[nt] = __builtin_amdgcn_mfma_f32_16x16x32_bf16(
            ah.h, bl.h, acc[nt], 0, 0, 0);
        acc[nt] = __builtin_amdgcn_mfma_f32_16x16x32_bf16(
            al_.h, bh.h, acc[nt], 0, 0, 0);
      }
    }
  }
#pragma unroll
  for (int nt = 0; nt < 4; ++nt) {
#pragma unroll
    for (int r = 0; r < 4; ++r) {
      int d = (w << 4) + (g << 2) + r;
      int x = (nt << 4) + (l & 15);
      float v = fmaxf(acc[nt][r] + b2[d], 0.f);
      z[((b * 64 + d) * 64 + y) * 64 + x] = v;
    }
  }
}

// ---------------- VQ: bf16x3 MFMA distances + fp32 argmin (chunked) ---------
// block = 64 points, 4 waves = n-tile (16 points each, all 512 codes).
// Codes processed in 4 chunks of 128: acc[8] (32 VGPR) reused per chunk,
// folded into running (bd,bk). Ascending (mc,mt8,r) + strict '<' and shfl
// (d,k) tie-break = np first-min. z kept in fp32 regs for Phase C.
__global__ __launch_bounds__(256) void vq_k(
    const float* z, const float* __restrict__ cb,
    const ushort_t* __restrict__ cbFh, const ushort_t* __restrict__ cbFl,
    const float* __restrict__ csqF, unsigned int* q_pk,
    float* __restrict__ out, int n0) {
  __shared__ unsigned zS[64 * 67];                 // 17.2 KB
  __shared__ int bk_arr[64];
  __shared__ float redl[4];
  int t = threadIdx.x, l = t & 63;
  int w = __builtin_amdgcn_readfirstlane(t >> 6);
  int nbase = blockIdx.x * 64;
  int b = nbase >> 12, y = (nbase >> 6) & 63;
  long zbase = (long)b * 262144 + y * 64;

  // Phase A: stage z packed; keep fp32 in regs (same mapping as Phase C).
  float zv[16];
#pragma unroll
  for (int j = 0; j < 16; ++j) {
    zv[j] = z[zbase + (long)((w << 4) + j) * 4096 + l];
    zS[l * 67 + (w << 4) + j] = pack_hilo(zv[j]);
  }
  __syncthreads();

  // Build B fragments once (lane's point pp, both k-halves).
  int pp = (w << 4) + (l & 15);
  FragU bh[2], bl[2];
#pragma unroll
  for (int ks = 0; ks < 2; ++ks) {
    const unsigned* zp = &zS[pp * 67 + (ks << 5) + ((l >> 4) << 3)];
    unsigned u0 = zp[0], u1 = zp[1], u2 = zp[2], u3 = zp[3];
    unsigned u4 = zp[4], u5 = zp[5], u6 = zp[6], u7 = zp[7];
    bh[ks].u[0] = __builtin_amdgcn_perm(u1, u0, 0x07060302u);
    bl[ks].u[0] = __builtin_amdgcn_perm(u1, u0, 0x05040100u);
    bh[ks].u[1] = __builtin_amdgcn_perm(u3, u2, 0x07060302u);
    bl[ks].u[1] = __builtin_amdgcn_perm(u3, u2, 0x05040100u);
    bh[ks].u[2] = __builtin_amdgcn_perm(u5, u4, 0x07060302u);
    bl[ks].u[2] = __builtin_amdgcn_perm(u5, u4, 0x05040100u);
    bh[ks].u[3] = __builtin_amdgcn_perm(u7, u6, 0x07060302u);
    bl[ks].u[3] = __builtin_amdgcn_perm(u7, u6, 0x05040100u);
  }

  int g = l >> 4;
  float bd = 1e30f;
  int bk = 0;
  for (int mc = 0; mc < 4; ++mc) {                 // 128 codes per chunk
    f32x4 acc[8];
#pragma unroll
    for (int m8 = 0; m8 < 8; ++m8) acc[m8] = (f32x4)0.f;
#pragma unroll
    for (int ks = 0; ks < 2; ++ks) {
#pragma unroll
      for (int m8 = 0; m8 < 8; ++m8) {
        long aoff = (((long)(ks * 32 + mc * 8 + m8) * 64) + l) * 8;
        FragU ah, al_;
        ah.u = *reinterpret_cast<const u32x4*>(cbFh + aoff);
        al_.u = *reinterpret_cast<const u32x4*>(cbFl + aoff);
        acc[m8] = __builtin_amdgcn_mfma_f32_16x16x32_bf16(
            ah.h, bh[ks].h, acc[m8], 0, 0, 0);
        acc[m8] = __builtin_amdgcn_mfma_f32_16x16x32_bf16(
            ah.h, bl[ks].h, acc[m8], 0, 0, 0);
        acc[m8] = __builtin_amdgcn_mfma_f32_16x16x32_bf16(
            al_.h, bh[ks].h, acc[m8], 0, 0, 0);
      }
    }
#pragma unroll
    for (int m8 = 0; m8 < 8; ++m8) {
      int mt = mc * 8 + m8;
      f32x4 cq = *reinterpret_cast<const f32x4*>(csqF + ((mt << 6) + l) * 4);
#pragma unroll
      for (int r = 0; r < 4; ++r) {
        float d = fmaf(-2.f, acc[m8][r], cq[r]);
        if (d < bd) { bd = d; bk = (mt << 4) + (g << 2) + r; }
      }
    }
  }
#pragma unroll
  for (int m = 16; m <= 32; m <<= 1) {
    float d2 = __shfl_xor(bd, m);
    int k2 = __shfl_xor(bk, m);
    if (d2 < bd || (d2 == bd && k2 < bk)) { bd = d2; bk = k2; }
  }
  if (l < 16) {
    bk_arr[(w << 4) + l] = bk;
    out[1 + n0 + nbase + (w << 4) + l] = (float)bk;
  }
  __syncthreads();

  // Phase C: thread t: point l, dims [16w,16w+16): loss + packed q write.
  int bkp = bk_arr[l];
  const float* cbest = cb + (bkp << 6) + (w << 4);
  float ls = 0.f;
#pragma unroll
  for (int j = 0; j < 16; ++j) {
    float c = cbest[j];
    q_pk[zbase + (long)((w << 4) + j) * 4096 + l] = pack_hilo(c);
    float df = c - zv[j];
    ls = fmaf(df, df, ls);
  }
#pragma unroll
  for (int m = 32; m; m >>= 1) ls += __shfl_xor(ls, m);
  if (l == 0) redl[w] = ls;
  __syncthreads();
  if (t == 0)
    atomicAdd(out, (redl[0] + redl[1] + redl[2] + redl[3]) * (1.25f / 8388608.f));
}

// ---------------- convT2 (64->128, 4x4, s2, p1) + relu: bf16x3 MFMA ---------
__global__ __launch_bounds__(256) void dconv2_k(
    const unsigned int* __restrict__ q_pk, const ushort_t* __restrict__ wAh,
    const ushort_t* __restrict__ wAl, const float* __restrict__ db2,
    float* __restrict__ g) {
  __shared__ unsigned int rows[64][2][68];         // 34.8 KB packed hi|lo
  int Y = blockIdx.x, b = blockIdx.y;
  int t = threadIdx.x, l = t & 63;
  int w = __builtin_amdgcn_readfirstlane(t >> 6);
  int pX = w & 1, coh = w >> 1;
  int yA = (Y + 1) >> 1, yB = yA - 1;
  int v = ((Y & 1) << 1) | pX;

  for (int s = t; s < 64 * 2 * 68; s += 256) {
    int ci = s / 136, r2 = s - ci * 136;
    int r = r2 / 68, i = r2 - r * 68;
    int yy = r ? yB : yA, ix = i - 1;
    unsigned val = 0u;
    if (i < 66 && yy >= 0 && yy < 64 && ix >= 0 && ix < 64)
      val = q_pk[((b * 64 + ci) * 64 + yy) * 64 + ix];
    rows[ci][r][i] = val;
  }
  __syncthreads();

  f32x4 acc[4][4];
#pragma unroll
  for (int mt = 0; mt < 4; ++mt)
#pragma unroll
    for (int nt = 0; nt < 4; ++nt) acc[mt][nt] = (f32x4)0.f;

  for (int s8 = 0; s8 < 8; ++s8) {
    FragU ah[4], al[4];
#pragma unroll
    for (int mt = 0; mt < 4; ++mt) {
      long off = ((((long)(v * 8 + s8) * 8 + (coh * 4 + mt)) * 64 + l) * 8);
      ah[mt].u = *reinterpret_cast<const u32x4*>(wAh + off);
      al[mt].u = *reinterpret_cast<const u32x4*>(wAl + off);
    }
#pragma unroll
    for (int nt = 0; nt < 4; ++nt) {
      int p = nt * 16 + (l & 15) + pX;
      int cc0 = (s8 << 3) + ((l >> 4) << 1);
      unsigned u0 = rows[cc0][0][p], u1 = rows[cc0][0][p + 1];
      unsigned u2 = rows[cc0][1][p], u3 = rows[cc0][1][p + 1];
      unsigned u4 = rows[cc0 + 1][0][p], u5 = rows[cc0 + 1][0][p + 1];
      unsigned u6 = rows[cc0 + 1][1][p], u7 = rows[cc0 + 1][1][p + 1];
      FragU bh, bl;
      bh.u[0] = (u0 >> 16) | (u1 & 0xFFFF0000u);
      bl.u[0] = (u0 & 0xFFFFu) | (u1 << 16);
      bh.u[1] = (u2 >> 16) | (u3 & 0xFFFF0000u);
      bl.u[1] = (u2 & 0xFFFFu) | (u3 << 16);
      bh.u[2] = (u4 >> 16) | (u5 & 0xFFFF0000u);
      bl.u[2] = (u4 & 0xFFFFu) | (u5 << 16);
      bh.u[3] = (u6 >> 16) | (u7 & 0xFFFF0000u);
      bl.u[3] = (u6 & 0xFFFFu) | (u7 << 16);
#pragma unroll
      for (int mt = 0; mt < 4; ++mt) {
        acc[mt][nt] = __builtin_amdgcn_mfma_f32_16x16x32_bf16(
            ah[mt].h, bh.h, acc[mt][nt], 0, 0, 0);
        acc[mt][nt] = __builtin_amdgcn_mfma_f32_16x16x32_bf16(
            ah[mt].h, bl.h, acc[mt][nt], 0, 0, 0);
        acc[mt][nt] = __builtin_amdgcn_mfma_f32_16x16x32_bf16(
            al[mt].h, bh.h, acc[mt][nt], 0, 0, 0);
      }
    }
  }

#pragma unroll
  for (int mt = 0; mt < 4; ++mt) {
#pragma unroll
    for (int r = 0; r < 4; ++r) {
      int co = ((coh * 4 + mt) << 4) + ((l >> 4) << 2) + r;
      float bias = db2[co];
#pragma unroll
      for (int nt = 0; nt < 4; ++nt) {
        int X = ((nt << 4) + (l & 15)) * 2 + pX;
        float val = fmaxf(acc[mt][nt][r] + bias, 0.f);
        g[((b * 128 + co) * 128 + Y) * 128 + X] = val;
      }
    }
  }
}

// ---------------- convT1 (128->1, 4x4, s2, p1) + sigmoid --------------------
__global__ __launch_bounds__(256) void dconv1_k(
    const float* __restrict__ g, const float* __restrict__ wd1,
    const float* __restrict__ db1, float* __restrict__ rec) {
  int a2 = blockIdx.x, b = blockIdx.y;
  int t = threadIdx.x;
  int w = __builtin_amdgcn_readfirstlane(t >> 6);
  int l = t & 63;
  int xh = w >> 1, pX = w & 1;
  int L = xh * 64 + l;                       // X = 2L + pX
  int kxA = pX ? 0 : 1, kxB = kxA + 2;
  int ixH = L + pX, ixL = L + pX - 1;
  bool okH = ixH < 128, okL = ixL >= 0;
  int yy0 = 2 * a2 - 1;
  bool vy[4];
#pragma unroll
  for (int r = 0; r < 4; ++r) vy[r] = (yy0 + r) >= 0 && (yy0 + r) < 128;

  const float* gb = g + ((long)b * 128) * 16384 + (long)yy0 * 128;
  float acc[4] = {0.f, 0.f, 0.f, 0.f};

  for (int ci = 0; ci < 128; ci += 2) {
    const float* p0 = gb + (long)ci * 16384;
    const float* p1 = p0 + 16384;
    float hi0[4], lo0[4], hi1[4], lo1[4];
#pragma unroll
    for (int r = 0; r < 4; ++r) {
      const float* q0 = p0 + r * 128;
      const float* q1 = p1 + r * 128;
      hi0[r] = (vy[r] && okH) ? q0[ixH] : 0.f;
      lo0[r] = (vy[r] && okL) ? q0[ixL] : 0.f;
      hi1[r] = (vy[r] && okH) ? q1[ixH] : 0.f;
      lo1[r] = (vy[r] && okL) ? q1[ixL] : 0.f;
    }
    const float* wp0 = wd1 + ci * 16;        // wave-uniform -> s_load
    const float* wp1 = wp0 + 16;
#pragma unroll
    for (int j = 0; j < 4; ++j) {
      int kyA = (j + 1) & 1, kyB = kyA + 2;
      int rA = ((j + 1) >> 1) + 1;           // in [1,3]
      float v = acc[j];
      v = fmaf(wp0[kyA * 4 + kxA], hi0[rA], v);
      v = fmaf(wp0[kyA * 4 + kxB], lo0[rA], v);
      v = fmaf(wp0[kyB * 4 + kxA], hi0[rA - 1], v);
      v = fmaf(wp0[kyB * 4 + kxB], lo0[rA - 1], v);
      v = fmaf(wp1[kyA * 4 + kxA], hi1[rA], v);
      v = fmaf(wp1[kyA * 4 + kxB], lo1[rA], v);
      v = fmaf(wp1[kyB * 4 + kxA], hi1[rA - 1], v);
      v = fmaf(wp1[kyB * 4 + kxB], lo1[rA - 1], v);
      acc[j] = v;
    }
  }
  float bb = db1[0];
#pragma unroll
  for (int j = 0; j < 4; ++j) {
    float v = acc[j] + bb;
    v = 1.f / (1.f + __expf(-v));
    rec[((b * 256 + 4 * a2 + j) * 256) + 2 * L + pX] = v;
  }
}

// ---------------------------------------------------------------------------
extern "C" void kernel_launch(void* const* d_in, const int* in_sizes, int n_in,
                              void* d_out, int out_size, void* d_ws, size_t ws_size,
                              hipStream_t stream) {
  const float* x      = (const float*)d_in[0];
  const float* enc_w1 = (const float*)d_in[1];
  const float* enc_b1 = (const float*)d_in[2];
  const float* enc_w2 = (const float*)d_in[3];
  const float* enc_b2 = (const float*)d_in[4];
  const float* cb     = (const float*)d_in[5];
  const float* dec_w2 = (const float*)d_in[6];
  const float* dec_b2 = (const float*)d_in[7];
  const float* dec_w1 = (const float*)d_in[8];
  const float* dec_b1 = (const float*)d_in[9];

  float* out = (float*)d_out;
  float* ws  = (float*)d_ws;
  ushort_t* wCh  = (ushort_t*)ws;                   // 131072 ushort = 65536 f
  ushort_t* wCl  = (ushort_t*)(ws + 65536);
  ushort_t* wAh  = (ushort_t*)(ws + 131072);
  ushort_t* wAl  = (ushort_t*)(ws + 196608);
  ushort_t* cbFh = (ushort_t*)(ws + 262144);        // 32768 ushort = 16384 f
  ushort_t* cbFl = (ushort_t*)(ws + 278528);
  float* csqF = ws + 294912;                        // 8192 f
  float* dyn  = ws + 303104;                        // chunk buffers

  // Per-image: h_pk = 2,097,152 u32 (g f32 aliases), z/q_pk = 262,144.
  const size_t PER_IMG = 2097152 + 262144;                   // 2,359,296 elems
  size_t avail = (ws_size / 4 > 303104 + 64) ? ws_size / 4 - 303104 - 64 : 0;
  int CB = 32;
  while (CB > 1 && (size_t)CB * PER_IMG > avail) CB >>= 1;

  zero_loss_k<<<dim3(1), 64, 0, stream>>>(out);
  repackA2_k<<<dim3(512), 256, 0, stream>>>(enc_w2, wCh, wCl);
  repackA_k<<<dim3(512), 256, 0, stream>>>(dec_w2, wAh, wAl);
  repackCB_k<<<dim3(128), 256, 0, stream>>>(cb, cbFh, cbFl);
  csqF_k<<<dim3(32), 256, 0, stream>>>(cb, csqF);

  for (int b0 = 0; b0 < 32; b0 += CB) {
    unsigned* hp = (unsigned*)dyn;                    // CB*2097152 (g aliases)
    float* zq = dyn + (size_t)CB * 2097152;           // CB*262144 (q_pk aliases)
    conv1_k<<<dim3(128, CB), 128, 0, stream>>>(
        x + (size_t)b0 * 65536, enc_w1, enc_b1, hp);
    conv2_k<<<dim3(64, CB), 256, 0, stream>>>(hp, wCh, wCl, enc_b2, zq);
    vq_k<<<dim3(CB * 64), 256, 0, stream>>>(
        zq, cb, cbFh, cbFl, csqF, (unsigned int*)zq, out, b0 * 4096);
    dconv2_k<<<dim3(128, CB), 256, 0, stream>>>(
        (const unsigned int*)zq, wAh, wAl, dec_b2, (float*)dyn /*g*/);
    dconv1_k<<<dim3(64, CB), 256, 0, stream>>>(
        (float*)dyn /*g*/, dec_w1, dec_b1, out + REC_OFF + (size_t)b0 * 65536);
  }
}